// Round 2
// baseline (4871.542 us; speedup 1.0000x reference)
//
#include <hip/hip_runtime.h>
#include <hip/hip_bf16.h>
#include <math.h>

#define BB 8
#define NN 2048
#define FF 64
#define DD 6
#define NSAMP 64
#define TOPK 16
#define NHEAD 8
#define HD 8
#define NLAYER 2
#define EPSF 1e-5f
#define R2 0.09f

// ---------------- transpose sortvec (B,1,F,N) -> x (B,N,F) ----------------
__global__ void k_transpose(const float* __restrict__ sv, float* __restrict__ x) {
  int i = blockIdx.x * 256 + threadIdx.x;
  if (i >= BB * NN * FF) return;
  int f = i % FF;
  int n = (i / FF) % NN;
  int b = i / (FF * NN);
  x[i] = sv[(b * FF + f) * NN + n];
}

// ---------------- qkv = x @ w_in^T + b_in : (B*N,192) ----------------
__global__ void k_qkv(const float* __restrict__ x, const float* __restrict__ win,
                      const float* __restrict__ bin, float* __restrict__ qkv) {
  __shared__ float xs[FF];
  int row = blockIdx.x;
  int t = threadIdx.x;  // 0..191
  if (t < FF) xs[t] = x[row * FF + t];
  __syncthreads();
  float s = bin[t];
  const float* w = win + t * FF;
  #pragma unroll 16
  for (int f = 0; f < FF; ++f) s += xs[f] * w[f];
  qkv[(size_t)row * 192 + t] = s;
}

// ---------------- attention: one thread per (b,h,n) query, online softmax ----
#define CHK 128
__global__ void k_attn(const float* __restrict__ qkv, float* __restrict__ a) {
  __shared__ float kv[CHK * 16];
  int n = blockIdx.x * 256 + threadIdx.x;
  int h = blockIdx.y, b = blockIdx.z;
  const float* qrow = qkv + ((size_t)(b * NN + n)) * 192 + h * HD;
  float q[HD];
  #pragma unroll
  for (int d = 0; d < HD; ++d) q[d] = qrow[d];
  float mrun = -1e30f, l = 0.f, acc[HD];
  #pragma unroll
  for (int d = 0; d < HD; ++d) acc[d] = 0.f;
  const float scale = 0.35355339059327373f;  // 1/sqrt(8)
  for (int base = 0; base < NN; base += CHK) {
    for (int i = threadIdx.x; i < CHK * 16; i += 256) {
      int m = i >> 4, d = i & 15;
      size_t off = ((size_t)(b * NN + base + m)) * 192;
      kv[i] = (d < 8) ? qkv[off + 64 + h * HD + d] : qkv[off + 128 + h * HD + (d - 8)];
    }
    __syncthreads();
    for (int m = 0; m < CHK; ++m) {
      const float* kk = kv + m * 16;
      float s = 0.f;
      #pragma unroll
      for (int d = 0; d < HD; ++d) s += q[d] * kk[d];
      s *= scale;
      float mnew = fmaxf(mrun, s);
      float corr = __expf(mrun - mnew);
      float p = __expf(s - mnew);
      l = l * corr + p;
      #pragma unroll
      for (int d = 0; d < HD; ++d) acc[d] = acc[d] * corr + p * kk[8 + d];
      mrun = mnew;
    }
    __syncthreads();
  }
  float inv = 1.f / l;
  float* out = a + ((size_t)(b * NN + n)) * FF + h * HD;
  #pragma unroll
  for (int d = 0; d < HD; ++d) out[d] = acc[d] * inv;
}

// ---------------- out-proj + residual + LayerNorm (block = 64 = one wave) ----
__global__ void k_proj_ln(const float* __restrict__ a, const float* __restrict__ wout,
                          const float* __restrict__ bout, const float* __restrict__ g,
                          const float* __restrict__ be, float* __restrict__ x) {
  __shared__ float as[FF];
  int row = blockIdx.x;
  int j = threadIdx.x;  // 64
  as[j] = a[row * FF + j];
  __syncthreads();
  float s = bout[j];
  const float* w = wout + j * FF;
  #pragma unroll 16
  for (int e = 0; e < FF; ++e) s += as[e] * w[e];
  float val = x[row * FF + j] + s;
  float m = val;
  for (int o = 32; o; o >>= 1) m += __shfl_xor(m, o);
  m *= (1.f / 64.f);
  float d = val - m;
  float v = d * d;
  for (int o = 32; o; o >>= 1) v += __shfl_xor(v, o);
  v *= (1.f / 64.f);
  x[row * FF + j] = d * rsqrtf(v + EPSF) * g[j] + be[j];
}

// ---------------- fused FFN + residual + LN, block=256 per row ----------------
__global__ void k_ffn(const float* __restrict__ w1, const float* __restrict__ b1,
                      const float* __restrict__ w2, const float* __restrict__ b2,
                      const float* __restrict__ g, const float* __restrict__ be,
                      float* __restrict__ x) {
  __shared__ float xs[FF];
  __shared__ float h1[2048];
  __shared__ float fp[256];
  int row = blockIdx.x;
  int t = threadIdx.x;  // 256
  if (t < FF) xs[t] = x[row * FF + t];
  __syncthreads();
  for (int i = 0; i < 8; ++i) {
    int k = t * 8 + i;
    float s = b1[k];
    const float* w = w1 + (size_t)k * FF;
    #pragma unroll 16
    for (int f = 0; f < FF; ++f) s += xs[f] * w[f];
    h1[k] = fmaxf(s, 0.f);
  }
  __syncthreads();
  int j = t & 63, part = t >> 6;
  {
    float s = 0.f;
    const float* w = w2 + (size_t)j * 2048 + part * 512;
    const float* hh = h1 + part * 512;
    for (int k = 0; k < 512; ++k) s += hh[k] * w[k];
    fp[part * 64 + j] = s;
  }
  __syncthreads();
  if (t < 64) {
    float val = xs[t] + b2[t] + fp[t] + fp[64 + t] + fp[128 + t] + fp[192 + t];
    float m = val;
    for (int o = 32; o; o >>= 1) m += __shfl_xor(m, o);
    m *= (1.f / 64.f);
    float d = val - m;
    float v = d * d;
    for (int o = 32; o; o >>= 1) v += __shfl_xor(v, o);
    v *= (1.f / 64.f);
    x[row * FF + t] = d * rsqrtf(v + EPSF) * g[t] + be[t];
  }
}

// ---------------- score head: 64->64->16->1 with BN+ReLU, block=64 per row ----
__global__ void k_fg(const float* __restrict__ x,
                     const float* __restrict__ w0, const float* __restrict__ b0, const float* __restrict__ bn0,
                     const float* __restrict__ w1, const float* __restrict__ b1, const float* __restrict__ bn1,
                     const float* __restrict__ w2, const float* __restrict__ b2, const float* __restrict__ bn2,
                     float* __restrict__ scores) {
  __shared__ float xs[FF];
  __shared__ float s0[64];
  __shared__ float s1[16];
  int row = blockIdx.x;
  int t = threadIdx.x;  // 64
  xs[t] = x[row * FF + t];
  __syncthreads();
  {
    float s = b0[t];
    const float* w = w0 + t * FF;
    #pragma unroll 16
    for (int f = 0; f < FF; ++f) s += xs[f] * w[f];
    float sc = bn0[t] * rsqrtf(bn0[192 + t] + EPSF);
    s = (s - bn0[128 + t]) * sc + bn0[64 + t];
    s0[t] = fmaxf(s, 0.f);
  }
  __syncthreads();
  if (t < 16) {
    float s = b1[t];
    const float* w = w1 + t * 64;
    for (int o = 0; o < 64; ++o) s += s0[o] * w[o];
    float sc = bn1[t] * rsqrtf(bn1[48 + t] + EPSF);
    s = (s - bn1[32 + t]) * sc + bn1[16 + t];
    s1[t] = fmaxf(s, 0.f);
  }
  __syncthreads();
  if (t == 0) {
    float s = b2[0];
    for (int o = 0; o < 16; ++o) s += s1[o] * w2[o];
    float sc = bn2[0] * rsqrtf(bn2[3] + EPSF);
    s = (s - bn2[2]) * sc + bn2[1];
    scores[row] = fmaxf(s, 0.f);
  }
}

// ---------------- top-k (k=16) per batch, iterative argmax, tie->lowest idx ----
__global__ void k_topk(const float* __restrict__ scores, int* __restrict__ idx,
                       float* __restrict__ out_idx) {
  __shared__ float vals[NN];
  __shared__ float rv[256];
  __shared__ int ri[256];
  int b = blockIdx.x, t = threadIdx.x;
  for (int i = t; i < NN; i += 256) vals[i] = scores[b * NN + i];
  __syncthreads();
  for (int r = 0; r < TOPK; ++r) {
    float best = -1e30f;
    int bi = NN;
    for (int i = t; i < NN; i += 256) {
      float v = vals[i];
      if (v > best || (v == best && i < bi)) { best = v; bi = i; }
    }
    rv[t] = best; ri[t] = bi;
    __syncthreads();
    for (int s = 128; s > 0; s >>= 1) {
      if (t < s) {
        if (rv[t + s] > rv[t] || (rv[t + s] == rv[t] && ri[t + s] < ri[t])) {
          rv[t] = rv[t + s]; ri[t] = ri[t + s];
        }
      }
      __syncthreads();
    }
    if (t == 0) {
      int w = ri[0];
      idx[b * TOPK + r] = w;
      out_idx[b * TOPK + r] = (float)w;
      vals[w] = -1e30f;
    }
    __syncthreads();
  }
}

// ---------------- ball query + 3 conv stages, block = 64 per (b,k) ----------------
__global__ void k_group(const float* __restrict__ inp, const int* __restrict__ idx,
                        const float* __restrict__ w0, const float* __restrict__ b0, const float* __restrict__ bn0,
                        const float* __restrict__ w1, const float* __restrict__ b1, const float* __restrict__ bn1,
                        const float* __restrict__ w2, const float* __restrict__ b2, const float* __restrict__ bn2,
                        float* __restrict__ r2g) {
  __shared__ int gidx[NSAMP];
  __shared__ float gsh[65 * DD];
  __shared__ float r0[128];
  __shared__ float r1[256];
  int k = blockIdx.x, b = blockIdx.y;
  int lane = threadIdx.x;  // 64
  int qn = idx[b * TOPK + k];
  const float* px = inp + (size_t)b * DD * NN;  // [d*N + n]
  float qx = px[qn], qy = px[NN + qn], qz = px[2 * NN + qn];
  int cnt = 0;
  for (int base = 0; base < NN && cnt < NSAMP; base += 64) {
    int n = base + lane;
    float dx = px[n] - qx, dy = px[NN + n] - qy, dz = px[2 * NN + n] - qz;
    float d2 = dx * dx + dy * dy + dz * dz;
    bool flag = (d2 <= R2);
    unsigned long long m = __ballot(flag);
    int pos = cnt + __popcll(m & ((1ull << lane) - 1ull));
    if (flag && pos < NSAMP) gidx[pos] = n;
    cnt += (int)__popcll(m);
  }
  __syncthreads();
  int total = cnt < NSAMP ? cnt : NSAMP;
  if (lane >= total) gidx[lane] = gidx[0];
  __syncthreads();
  for (int i = lane; i < 65 * DD; i += 64) {
    int p = i / DD, d = i - p * DD;
    int n = (p == 0) ? qn : gidx[p - 1];
    gsh[i] = px[d * NN + n];
  }
  __syncthreads();
  for (int c = lane; c < 128; c += 64) {
    float s = b0[c];
    const float* w = w0 + c * 390;
    for (int i = 0; i < 390; ++i) s += gsh[i] * w[i];
    float sc = bn0[c] * rsqrtf(bn0[384 + c] + EPSF);
    s = (s - bn0[256 + c]) * sc + bn0[128 + c];
    r0[c] = fmaxf(s, 0.f);
  }
  __syncthreads();
  for (int c = lane; c < 256; c += 64) {
    float s = b1[c];
    const float* w = w1 + c * 128;
    for (int o = 0; o < 128; ++o) s += r0[o] * w[o];
    float sc = bn1[c] * rsqrtf(bn1[768 + c] + EPSF);
    s = (s - bn1[512 + c]) * sc + bn1[256 + c];
    r1[c] = fmaxf(s, 0.f);
  }
  __syncthreads();
  for (int c = lane; c < 512; c += 64) {
    float s = b2[c];
    const float* w = w2 + c * 256;
    for (int o = 0; o < 256; ++o) s += r1[o] * w[o];
    float sc = bn2[c] * rsqrtf(bn2[1536 + c] + EPSF);
    s = (s - bn2[1024 + c]) * sc + bn2[512 + c];
    r2g[b * 8192 + c * TOPK + k] = fmaxf(s, 0.f);
  }
}

// ---------------- FC + BN + ReLU (wave-reduced dot), block=64 ----------------
__global__ void k_fl(const float* __restrict__ hin, const float* __restrict__ w,
                     const float* __restrict__ bias, const float* __restrict__ bn,
                     float* __restrict__ hout, int IN, int OUT) {
  int blk = blockIdx.x;
  int b = blk / OUT, j = blk % OUT;
  int lane = threadIdx.x;
  const float* hr = hin + (size_t)b * IN;
  const float* wr = w + (size_t)j * IN;
  float s = 0.f;
  for (int i = lane; i < IN; i += 64) s += hr[i] * wr[i];
  for (int o = 32; o; o >>= 1) s += __shfl_xor(s, o);
  if (lane == 0) {
    s += bias[j];
    float sc = bn[j] * rsqrtf(bn[3 * OUT + j] + EPSF);
    s = (s - bn[2 * OUT + j]) * sc + bn[OUT + j];
    hout[b * OUT + j] = fmaxf(s, 0.f);
  }
}

extern "C" void kernel_launch(void* const* d_in, const int* in_sizes, int n_in,
                              void* d_out, int out_size, void* d_ws, size_t ws_size,
                              hipStream_t stream) {
  const float* sv      = (const float*)d_in[0];
  const float* inp     = (const float*)d_in[1];
  const float* tl_win  = (const float*)d_in[2];
  const float* tl_bin  = (const float*)d_in[3];
  const float* tl_wout = (const float*)d_in[4];
  const float* tl_bout = (const float*)d_in[5];
  const float* tl_w1   = (const float*)d_in[6];
  const float* tl_b1   = (const float*)d_in[7];
  const float* tl_w2   = (const float*)d_in[8];
  const float* tl_b2   = (const float*)d_in[9];
  const float* tl_ln1g = (const float*)d_in[10];
  const float* tl_ln1b = (const float*)d_in[11];
  const float* tl_ln2g = (const float*)d_in[12];
  const float* tl_ln2b = (const float*)d_in[13];
  const float* fg_w0   = (const float*)d_in[14];
  const float* fg_b0   = (const float*)d_in[15];
  const float* fg_w1   = (const float*)d_in[16];
  const float* fg_b1   = (const float*)d_in[17];
  const float* fg_w2   = (const float*)d_in[18];
  const float* fg_b2   = (const float*)d_in[19];
  const float* fbn0    = (const float*)d_in[20];
  const float* fbn1    = (const float*)d_in[21];
  const float* fbn2    = (const float*)d_in[22];
  const float* rc_w0   = (const float*)d_in[23];
  const float* rc_b0   = (const float*)d_in[24];
  const float* rc_w1   = (const float*)d_in[25];
  const float* rc_b1   = (const float*)d_in[26];
  const float* rc_w2   = (const float*)d_in[27];
  const float* rc_b2   = (const float*)d_in[28];
  const float* rbn0    = (const float*)d_in[29];
  const float* rbn1    = (const float*)d_in[30];
  const float* rbn2    = (const float*)d_in[31];
  const float* fl_w0   = (const float*)d_in[32];
  const float* fl_b0   = (const float*)d_in[33];
  const float* fl_w1   = (const float*)d_in[34];
  const float* fl_b1   = (const float*)d_in[35];
  const float* lbn0    = (const float*)d_in[36];
  const float* lbn1    = (const float*)d_in[37];
  (void)in_sizes; (void)n_in; (void)out_size; (void)ws_size;

  float* ws = (float*)d_ws;
  float* x      = ws;                         // B*N*F      = 1048576
  float* qkv    = x + BB * NN * FF;           // B*N*192    = 3145728
  float* a      = qkv + BB * NN * 192;        // B*N*F      = 1048576
  float* scores = a + BB * NN * FF;           // B*N        = 16384
  int*   idxb   = (int*)(scores + BB * NN);   // B*TOPK     = 128
  float* r2g    = (float*)(idxb + BB * TOPK); // B*8192     = 65536
  float* h1g    = r2g + BB * 8192;            // B*1024     = 8192

  float* out = (float*)d_out;  // fp32: h at [0,4096), idx-as-float at [4096,4224)

  k_transpose<<<(BB * NN * FF) / 256, 256, 0, stream>>>(sv, x);

  for (int l = 0; l < NLAYER; ++l) {
    k_qkv<<<BB * NN, 192, 0, stream>>>(x, tl_win + l * 192 * FF, tl_bin + l * 192, qkv);
    k_attn<<<dim3(NN / 256, NHEAD, BB), 256, 0, stream>>>(qkv, a);
    k_proj_ln<<<BB * NN, 64, 0, stream>>>(a, tl_wout + l * FF * FF, tl_bout + l * FF,
                                          tl_ln1g + l * FF, tl_ln1b + l * FF, x);
    k_ffn<<<BB * NN, 256, 0, stream>>>(tl_w1 + l * 2048 * FF, tl_b1 + l * 2048,
                                       tl_w2 + l * FF * 2048, tl_b2 + l * FF,
                                       tl_ln2g + l * FF, tl_ln2b + l * FF, x);
  }

  k_fg<<<BB * NN, 64, 0, stream>>>(x, fg_w0, fg_b0, fbn0, fg_w1, fg_b1, fbn1,
                                   fg_w2, fg_b2, fbn2, scores);
  k_topk<<<BB, 256, 0, stream>>>(scores, idxb, out + BB * 512);
  k_group<<<dim3(TOPK, BB), 64, 0, stream>>>(inp, idxb, rc_w0, rc_b0, rbn0,
                                             rc_w1, rc_b1, rbn1, rc_w2, rc_b2, rbn2, r2g);
  k_fl<<<BB * 1024, 64, 0, stream>>>(r2g, fl_w0, fl_b0, lbn0, h1g, 8192, 1024);
  k_fl<<<BB * 512, 64, 0, stream>>>(h1g, fl_w1, fl_b1, lbn1, out, 1024, 512);
}

// Round 3
// 1578.585 us; speedup vs baseline: 3.0860x; 3.0860x over previous
//
#include <hip/hip_runtime.h>
#include <hip/hip_bf16.h>
#include <math.h>

#define BB 8
#define NN 2048
#define FF 64
#define DD 6
#define NSAMP 64
#define TOPK 16
#define NHEAD 8
#define HD 8
#define NLAYER 2
#define EPSF 1e-5f
#define R2 0.09f

// ---------------- transpose sortvec (B,1,F,N) -> x (B,N,F) ----------------
__global__ void k_transpose(const float* __restrict__ sv, float* __restrict__ x) {
  int i = blockIdx.x * 256 + threadIdx.x;
  if (i >= BB * NN * FF) return;
  int f = i % FF;
  int n = (i / FF) % NN;
  int b = i / (FF * NN);
  x[i] = sv[(b * FF + f) * NN + n];
}

// ---------------- tiled GEMM: qkv[row][192] = x[row][64] @ win^T + bin ----------
// grid (256 row-tiles, 3 col-tiles), block 256. LDS-staged, 4x4 microtile.
__global__ void k_qkv2(const float* __restrict__ x, const float* __restrict__ win,
                       const float* __restrict__ bin, float* __restrict__ qkv) {
  __shared__ float xs[64 * 64];
  __shared__ float ws[64 * 68];
  int row0 = blockIdx.x * 64, col0 = blockIdx.y * 64;
  int t = threadIdx.x;
  #pragma unroll
  for (int i = 0; i < 4; ++i) {
    int q = t + i * 256, r = q >> 4, c = (q & 15) * 4;
    *(float4*)(xs + r * 64 + c) = *(const float4*)(x + (size_t)(row0 + r) * 64 + c);
    *(float4*)(ws + r * 68 + c) = *(const float4*)(win + (size_t)(col0 + r) * 64 + c);
  }
  __syncthreads();
  int tx = t & 15, ty = t >> 4;
  float acc[4][4] = {};
  for (int f = 0; f < 64; f += 4) {
    float4 xv[4], wv[4];
    #pragma unroll
    for (int ri = 0; ri < 4; ++ri) xv[ri] = *(const float4*)(xs + (ty + 16 * ri) * 64 + f);
    #pragma unroll
    for (int ci = 0; ci < 4; ++ci) wv[ci] = *(const float4*)(ws + (tx + 16 * ci) * 68 + f);
    #pragma unroll
    for (int ri = 0; ri < 4; ++ri)
      #pragma unroll
      for (int ci = 0; ci < 4; ++ci)
        acc[ri][ci] += xv[ri].x * wv[ci].x + xv[ri].y * wv[ci].y +
                       xv[ri].z * wv[ci].z + xv[ri].w * wv[ci].w;
  }
  #pragma unroll
  for (int ri = 0; ri < 4; ++ri)
    #pragma unroll
    for (int ci = 0; ci < 4; ++ci) {
      int r = row0 + ty + 16 * ri, c = col0 + tx + 16 * ci;
      qkv[(size_t)r * 192 + c] = acc[ri][ci] + bin[c];
    }
}

// ---------------- attention: one thread per (b,h,n) query, online softmax ----
#define CHK 128
__global__ void k_attn(const float* __restrict__ qkv, float* __restrict__ a) {
  __shared__ float kv[CHK * 16];
  int n = blockIdx.x * 256 + threadIdx.x;
  int h = blockIdx.y, b = blockIdx.z;
  const float* qrow = qkv + ((size_t)(b * NN + n)) * 192 + h * HD;
  float q[HD];
  #pragma unroll
  for (int d = 0; d < HD; ++d) q[d] = qrow[d];
  float mrun = -1e30f, l = 0.f, acc[HD];
  #pragma unroll
  for (int d = 0; d < HD; ++d) acc[d] = 0.f;
  const float scale = 0.35355339059327373f;  // 1/sqrt(8)
  for (int base = 0; base < NN; base += CHK) {
    for (int i = threadIdx.x; i < CHK * 16; i += 256) {
      int m = i >> 4, d = i & 15;
      size_t off = ((size_t)(b * NN + base + m)) * 192;
      kv[i] = (d < 8) ? qkv[off + 64 + h * HD + d] : qkv[off + 128 + h * HD + (d - 8)];
    }
    __syncthreads();
    for (int m = 0; m < CHK; ++m) {
      const float* kk = kv + m * 16;
      float s = 0.f;
      #pragma unroll
      for (int d = 0; d < HD; ++d) s += q[d] * kk[d];
      s *= scale;
      float mnew = fmaxf(mrun, s);
      float corr = __expf(mrun - mnew);
      float p = __expf(s - mnew);
      l = l * corr + p;
      #pragma unroll
      for (int d = 0; d < HD; ++d) acc[d] = acc[d] * corr + p * kk[8 + d];
      mrun = mnew;
    }
    __syncthreads();
  }
  float inv = 1.f / l;
  float* out = a + ((size_t)(b * NN + n)) * FF + h * HD;
  #pragma unroll
  for (int d = 0; d < HD; ++d) out[d] = acc[d] * inv;
}

// ------- proj + residual + LN, tiled GEMM, grid 256 blocks of 64 rows ---------
__global__ void k_proj2(const float* __restrict__ a, const float* __restrict__ wout,
                        const float* __restrict__ bout, const float* __restrict__ g,
                        const float* __restrict__ be, float* __restrict__ x) {
  __shared__ float xs[64 * 64];
  __shared__ float ws[64 * 68];
  int row0 = blockIdx.x * 64;
  int t = threadIdx.x;
  #pragma unroll
  for (int i = 0; i < 4; ++i) {
    int q = t + i * 256, r = q >> 4, c = (q & 15) * 4;
    *(float4*)(xs + r * 64 + c) = *(const float4*)(a + (size_t)(row0 + r) * 64 + c);
    *(float4*)(ws + r * 68 + c) = *(const float4*)(wout + r * 64 + c);
  }
  __syncthreads();
  int tx = t & 15, ty = t >> 4;
  float acc[4][4] = {};
  for (int f = 0; f < 64; f += 4) {
    float4 xv[4], wv[4];
    #pragma unroll
    for (int ri = 0; ri < 4; ++ri) xv[ri] = *(const float4*)(xs + (ty + 16 * ri) * 64 + f);
    #pragma unroll
    for (int ci = 0; ci < 4; ++ci) wv[ci] = *(const float4*)(ws + (tx + 16 * ci) * 68 + f);
    #pragma unroll
    for (int ri = 0; ri < 4; ++ri)
      #pragma unroll
      for (int ci = 0; ci < 4; ++ci)
        acc[ri][ci] += xv[ri].x * wv[ci].x + xv[ri].y * wv[ci].y +
                       xv[ri].z * wv[ci].z + xv[ri].w * wv[ci].w;
  }
  // epilogue: val = x + proj; LN over 64 cols (cols spread over tx lanes + ci regs)
  #pragma unroll
  for (int ri = 0; ri < 4; ++ri) {
    int rl = ty + 16 * ri;
    float val[4], s = 0.f, sq = 0.f;
    #pragma unroll
    for (int ci = 0; ci < 4; ++ci) {
      int c = tx + 16 * ci;
      val[ci] = x[(size_t)(row0 + rl) * 64 + c] + bout[c] + acc[ri][ci];
      s += val[ci]; sq += val[ci] * val[ci];
    }
    #pragma unroll
    for (int off = 1; off < 16; off <<= 1) { s += __shfl_xor(s, off); sq += __shfl_xor(sq, off); }
    float mean = s * (1.f / 64.f);
    float var = sq * (1.f / 64.f) - mean * mean;
    float rstd = rsqrtf(var + EPSF);
    #pragma unroll
    for (int ci = 0; ci < 4; ++ci) {
      int c = tx + 16 * ci;
      x[(size_t)(row0 + rl) * 64 + c] = (val[ci] - mean) * rstd * g[c] + be[c];
    }
  }
}

// ------- fused FFN (64->2048->64) + residual + LN, chunked hidden, grid 256 ----
__global__ void k_ffn2(const float* __restrict__ w1, const float* __restrict__ b1,
                       const float* __restrict__ w2, const float* __restrict__ b2,
                       const float* __restrict__ g, const float* __restrict__ be,
                       float* __restrict__ x) {
  __shared__ float xs[64 * 64];   // input tile (stationary, broadcast reads)
  __shared__ float ws[64 * 68];   // shared w1-chunk / w2-chunk buffer (strided reads)
  __shared__ float hs[64 * 64];   // relu(h) chunk (broadcast reads)
  __shared__ float b1s[64];
  int row0 = blockIdx.x * 64;
  int t = threadIdx.x;
  int tx = t & 15, ty = t >> 4;
  #pragma unroll
  for (int i = 0; i < 4; ++i) {
    int q = t + i * 256, r = q >> 4, c = (q & 15) * 4;
    *(float4*)(xs + r * 64 + c) = *(const float4*)(x + (size_t)(row0 + r) * 64 + c);
  }
  float acc[4][4] = {};
  for (int ch = 0; ch < 32; ++ch) {
    int kc = ch * 64;
    // stage w1 chunk rows [kc,kc+64) + b1 chunk into regs (global, coalesced)
    float4 rw[4], rb;
    #pragma unroll
    for (int i = 0; i < 4; ++i) {
      int q = t + i * 256, r = q >> 4, c = (q & 15) * 4;
      rw[i] = *(const float4*)(w1 + (size_t)(kc + r) * 64 + c);
    }
    if (t < 16) rb = *(const float4*)(b1 + kc + t * 4);
    __syncthreads();  // (A) prev phase2 done reading ws/hs
    #pragma unroll
    for (int i = 0; i < 4; ++i) {
      int q = t + i * 256, r = q >> 4, c = (q & 15) * 4;
      *(float4*)(ws + r * 68 + c) = rw[i];
    }
    if (t < 16) *(float4*)(b1s + t * 4) = rb;
    __syncthreads();  // (B) w1 chunk ready
    // phase 1: h[r][k] = relu(x[r]·w1[kc+k] + b1)
    float a1[4][4] = {};
    for (int f = 0; f < 64; f += 4) {
      float4 xv[4], wv[4];
      #pragma unroll
      for (int ri = 0; ri < 4; ++ri) xv[ri] = *(const float4*)(xs + (ty + 16 * ri) * 64 + f);
      #pragma unroll
      for (int ki = 0; ki < 4; ++ki) wv[ki] = *(const float4*)(ws + (tx + 16 * ki) * 68 + f);
      #pragma unroll
      for (int ri = 0; ri < 4; ++ri)
        #pragma unroll
        for (int ki = 0; ki < 4; ++ki)
          a1[ri][ki] += xv[ri].x * wv[ki].x + xv[ri].y * wv[ki].y +
                        xv[ri].z * wv[ki].z + xv[ri].w * wv[ki].w;
    }
    #pragma unroll
    for (int ri = 0; ri < 4; ++ri)
      #pragma unroll
      for (int ki = 0; ki < 4; ++ki) {
        int k = tx + 16 * ki;
        hs[(ty + 16 * ri) * 64 + k] = fmaxf(a1[ri][ki] + b1s[k], 0.f);
      }
    // stage w2 chunk cols [kc,kc+64) for all 64 out-ch (global, coalesced)
    #pragma unroll
    for (int i = 0; i < 4; ++i) {
      int q = t + i * 256, j = q >> 4, c = (q & 15) * 4;
      rw[i] = *(const float4*)(w2 + (size_t)j * 2048 + kc + c);
    }
    __syncthreads();  // (C) phase1 done reading ws, hs written
    #pragma unroll
    for (int i = 0; i < 4; ++i) {
      int q = t + i * 256, j = q >> 4, c = (q & 15) * 4;
      *(float4*)(ws + j * 68 + c) = rw[i];
    }
    __syncthreads();  // (D) w2 chunk ready
    // phase 2: out[r][j] += h[r][k]·w2[j][kc+k]
    for (int k = 0; k < 64; k += 4) {
      float4 hv[4], wv[4];
      #pragma unroll
      for (int ri = 0; ri < 4; ++ri) hv[ri] = *(const float4*)(hs + (ty + 16 * ri) * 64 + k);
      #pragma unroll
      for (int ji = 0; ji < 4; ++ji) wv[ji] = *(const float4*)(ws + (tx + 16 * ji) * 68 + k);
      #pragma unroll
      for (int ri = 0; ri < 4; ++ri)
        #pragma unroll
        for (int ji = 0; ji < 4; ++ji)
          acc[ri][ji] += hv[ri].x * wv[ji].x + hv[ri].y * wv[ji].y +
                         hv[ri].z * wv[ji].z + hv[ri].w * wv[ji].w;
    }
  }
  // epilogue: residual (from xs) + b2, LN over 64 cols
  #pragma unroll
  for (int ri = 0; ri < 4; ++ri) {
    int rl = ty + 16 * ri;
    float val[4], s = 0.f, sq = 0.f;
    #pragma unroll
    for (int ci = 0; ci < 4; ++ci) {
      int c = tx + 16 * ci;
      val[ci] = xs[rl * 64 + c] + b2[c] + acc[ri][ci];
      s += val[ci]; sq += val[ci] * val[ci];
    }
    #pragma unroll
    for (int off = 1; off < 16; off <<= 1) { s += __shfl_xor(s, off); sq += __shfl_xor(sq, off); }
    float mean = s * (1.f / 64.f);
    float var = sq * (1.f / 64.f) - mean * mean;
    float rstd = rsqrtf(var + EPSF);
    #pragma unroll
    for (int ci = 0; ci < 4; ++ci) {
      int c = tx + 16 * ci;
      x[(size_t)(row0 + rl) * 64 + c] = (val[ci] - mean) * rstd * g[c] + be[c];
    }
  }
}

// ------- score head tiled: 64 rows/block; 64->64 GEMM then 16 then 1 ----------
__global__ void k_fg2(const float* __restrict__ x,
                      const float* __restrict__ w0, const float* __restrict__ b0, const float* __restrict__ bn0,
                      const float* __restrict__ w1, const float* __restrict__ b1, const float* __restrict__ bn1,
                      const float* __restrict__ w2, const float* __restrict__ b2, const float* __restrict__ bn2,
                      float* __restrict__ scores) {
  __shared__ float xs[64 * 64];
  __shared__ float ws[64 * 68];
  __shared__ float s0s[64 * 68];
  __shared__ float s1s[64 * 20];
  int row0 = blockIdx.x * 64;
  int t = threadIdx.x;
  #pragma unroll
  for (int i = 0; i < 4; ++i) {
    int q = t + i * 256, r = q >> 4, c = (q & 15) * 4;
    *(float4*)(xs + r * 64 + c) = *(const float4*)(x + (size_t)(row0 + r) * 64 + c);
    *(float4*)(ws + r * 68 + c) = *(const float4*)(w0 + r * 64 + c);
  }
  __syncthreads();
  int tx = t & 15, ty = t >> 4;
  float acc[4][4] = {};
  for (int f = 0; f < 64; f += 4) {
    float4 xv[4], wv[4];
    #pragma unroll
    for (int ri = 0; ri < 4; ++ri) xv[ri] = *(const float4*)(xs + (ty + 16 * ri) * 64 + f);
    #pragma unroll
    for (int ci = 0; ci < 4; ++ci) wv[ci] = *(const float4*)(ws + (tx + 16 * ci) * 68 + f);
    #pragma unroll
    for (int ri = 0; ri < 4; ++ri)
      #pragma unroll
      for (int ci = 0; ci < 4; ++ci)
        acc[ri][ci] += xv[ri].x * wv[ci].x + xv[ri].y * wv[ci].y +
                       xv[ri].z * wv[ci].z + xv[ri].w * wv[ci].w;
  }
  #pragma unroll
  for (int ri = 0; ri < 4; ++ri)
    #pragma unroll
    for (int ci = 0; ci < 4; ++ci) {
      int c = tx + 16 * ci;
      float sc = bn0[c] * rsqrtf(bn0[192 + c] + EPSF);
      float v = (acc[ri][ci] + b0[c] - bn0[128 + c]) * sc + bn0[64 + c];
      s0s[(ty + 16 * ri) * 68 + c] = fmaxf(v, 0.f);
    }
  __syncthreads();
  {  // stage 2: 64 -> 16, each thread 4 (row,j) pairs
    int rl = t & 63, j0 = t >> 6;
    #pragma unroll
    for (int i = 0; i < 4; ++i) {
      int j = j0 + 4 * i;
      float s = b1[j];
      const float* wr = w1 + j * 64;
      #pragma unroll 16
      for (int c = 0; c < 64; ++c) s += s0s[rl * 68 + c] * wr[c];
      float sc = bn1[j] * rsqrtf(bn1[48 + j] + EPSF);
      s = (s - bn1[32 + j]) * sc + bn1[16 + j];
      s1s[rl * 20 + j] = fmaxf(s, 0.f);
    }
  }
  __syncthreads();
  if (t < 64) {
    float s = b2[0];
    #pragma unroll
    for (int o = 0; o < 16; ++o) s += s1s[t * 20 + o] * w2[o];
    float sc = bn2[0] * rsqrtf(bn2[3] + EPSF);
    s = (s - bn2[2]) * sc + bn2[1];
    scores[row0 + t] = fmaxf(s, 0.f);
  }
}

// ---------------- top-k (k=16) per batch, iterative argmax, tie->lowest idx ----
__global__ void k_topk(const float* __restrict__ scores, int* __restrict__ idx,
                       float* __restrict__ out_idx) {
  __shared__ float vals[NN];
  __shared__ float rv[256];
  __shared__ int ri[256];
  int b = blockIdx.x, t = threadIdx.x;
  for (int i = t; i < NN; i += 256) vals[i] = scores[b * NN + i];
  __syncthreads();
  for (int r = 0; r < TOPK; ++r) {
    float best = -1e30f;
    int bi = NN;
    for (int i = t; i < NN; i += 256) {
      float v = vals[i];
      if (v > best || (v == best && i < bi)) { best = v; bi = i; }
    }
    rv[t] = best; ri[t] = bi;
    __syncthreads();
    for (int s = 128; s > 0; s >>= 1) {
      if (t < s) {
        if (rv[t + s] > rv[t] || (rv[t + s] == rv[t] && ri[t + s] < ri[t])) {
          rv[t] = rv[t + s]; ri[t] = ri[t + s];
        }
      }
      __syncthreads();
    }
    if (t == 0) {
      int w = ri[0];
      idx[b * TOPK + r] = w;
      out_idx[b * TOPK + r] = (float)w;
      vals[w] = -1e30f;
    }
    __syncthreads();
  }
}

// ---------------- ball query + 3 conv stages, block = 64 per (b,k) ----------------
__global__ void k_group(const float* __restrict__ inp, const int* __restrict__ idx,
                        const float* __restrict__ w0, const float* __restrict__ b0, const float* __restrict__ bn0,
                        const float* __restrict__ w1, const float* __restrict__ b1, const float* __restrict__ bn1,
                        const float* __restrict__ w2, const float* __restrict__ b2, const float* __restrict__ bn2,
                        float* __restrict__ r2g) {
  __shared__ int gidx[NSAMP];
  __shared__ float gsh[65 * DD];
  __shared__ float r0[128];
  __shared__ float r1[256];
  int k = blockIdx.x, b = blockIdx.y;
  int lane = threadIdx.x;  // 64
  int qn = idx[b * TOPK + k];
  const float* px = inp + (size_t)b * DD * NN;  // [d*N + n]
  float qx = px[qn], qy = px[NN + qn], qz = px[2 * NN + qn];
  int cnt = 0;
  for (int base = 0; base < NN && cnt < NSAMP; base += 64) {
    int n = base + lane;
    float dx = px[n] - qx, dy = px[NN + n] - qy, dz = px[2 * NN + n] - qz;
    float d2 = dx * dx + dy * dy + dz * dz;
    bool flag = (d2 <= R2);
    unsigned long long m = __ballot(flag);
    int pos = cnt + __popcll(m & ((1ull << lane) - 1ull));
    if (flag && pos < NSAMP) gidx[pos] = n;
    cnt += (int)__popcll(m);
  }
  __syncthreads();
  int total = cnt < NSAMP ? cnt : NSAMP;
  if (lane >= total) gidx[lane] = gidx[0];
  __syncthreads();
  for (int i = lane; i < 65 * DD; i += 64) {
    int p = i / DD, d = i - p * DD;
    int n = (p == 0) ? qn : gidx[p - 1];
    gsh[i] = px[d * NN + n];
  }
  __syncthreads();
  for (int c = lane; c < 128; c += 64) {
    float s = b0[c];
    const float* w = w0 + c * 390;
    for (int i = 0; i < 390; ++i) s += gsh[i] * w[i];
    float sc = bn0[c] * rsqrtf(bn0[384 + c] + EPSF);
    s = (s - bn0[256 + c]) * sc + bn0[128 + c];
    r0[c] = fmaxf(s, 0.f);
  }
  __syncthreads();
  for (int c = lane; c < 256; c += 64) {
    float s = b1[c];
    const float* w = w1 + c * 128;
    for (int o = 0; o < 128; ++o) s += r0[o] * w[o];
    float sc = bn1[c] * rsqrtf(bn1[768 + c] + EPSF);
    s = (s - bn1[512 + c]) * sc + bn1[256 + c];
    r1[c] = fmaxf(s, 0.f);
  }
  __syncthreads();
  for (int c = lane; c < 512; c += 64) {
    float s = b2[c];
    const float* w = w2 + c * 256;
    for (int o = 0; o < 256; ++o) s += r1[o] * w[o];
    float sc = bn2[c] * rsqrtf(bn2[1536 + c] + EPSF);
    s = (s - bn2[1024 + c]) * sc + bn2[512 + c];
    r2g[b * 8192 + c * TOPK + k] = fmaxf(s, 0.f);
  }
}

// ---------------- FC + BN + ReLU (wave-reduced dot), block=64 ----------------
__global__ void k_fl(const float* __restrict__ hin, const float* __restrict__ w,
                     const float* __restrict__ bias, const float* __restrict__ bn,
                     float* __restrict__ hout, int IN, int OUT) {
  int blk = blockIdx.x;
  int b = blk / OUT, j = blk % OUT;
  int lane = threadIdx.x;
  const float* hr = hin + (size_t)b * IN;
  const float* wr = w + (size_t)j * IN;
  float s = 0.f;
  for (int i = lane; i < IN; i += 64) s += hr[i] * wr[i];
  for (int o = 32; o; o >>= 1) s += __shfl_xor(s, o);
  if (lane == 0) {
    s += bias[j];
    float sc = bn[j] * rsqrtf(bn[3 * OUT + j] + EPSF);
    s = (s - bn[2 * OUT + j]) * sc + bn[OUT + j];
    hout[b * OUT + j] = fmaxf(s, 0.f);
  }
}

extern "C" void kernel_launch(void* const* d_in, const int* in_sizes, int n_in,
                              void* d_out, int out_size, void* d_ws, size_t ws_size,
                              hipStream_t stream) {
  const float* sv      = (const float*)d_in[0];
  const float* inp     = (const float*)d_in[1];
  const float* tl_win  = (const float*)d_in[2];
  const float* tl_bin  = (const float*)d_in[3];
  const float* tl_wout = (const float*)d_in[4];
  const float* tl_bout = (const float*)d_in[5];
  const float* tl_w1   = (const float*)d_in[6];
  const float* tl_b1   = (const float*)d_in[7];
  const float* tl_w2   = (const float*)d_in[8];
  const float* tl_b2   = (const float*)d_in[9];
  const float* tl_ln1g = (const float*)d_in[10];
  const float* tl_ln1b = (const float*)d_in[11];
  const float* tl_ln2g = (const float*)d_in[12];
  const float* tl_ln2b = (const float*)d_in[13];
  const float* fg_w0   = (const float*)d_in[14];
  const float* fg_b0   = (const float*)d_in[15];
  const float* fg_w1   = (const float*)d_in[16];
  const float* fg_b1   = (const float*)d_in[17];
  const float* fg_w2   = (const float*)d_in[18];
  const float* fg_b2   = (const float*)d_in[19];
  const float* fbn0    = (const float*)d_in[20];
  const float* fbn1    = (const float*)d_in[21];
  const float* fbn2    = (const float*)d_in[22];
  const float* rc_w0   = (const float*)d_in[23];
  const float* rc_b0   = (const float*)d_in[24];
  const float* rc_w1   = (const float*)d_in[25];
  const float* rc_b1   = (const float*)d_in[26];
  const float* rc_w2   = (const float*)d_in[27];
  const float* rc_b2   = (const float*)d_in[28];
  const float* rbn0    = (const float*)d_in[29];
  const float* rbn1    = (const float*)d_in[30];
  const float* rbn2    = (const float*)d_in[31];
  const float* fl_w0   = (const float*)d_in[32];
  const float* fl_b0   = (const float*)d_in[33];
  const float* fl_w1   = (const float*)d_in[34];
  const float* fl_b1   = (const float*)d_in[35];
  const float* lbn0    = (const float*)d_in[36];
  const float* lbn1    = (const float*)d_in[37];
  (void)in_sizes; (void)n_in; (void)out_size; (void)ws_size;

  float* ws = (float*)d_ws;
  float* x      = ws;                         // B*N*F      = 1048576
  float* qkv    = x + BB * NN * FF;           // B*N*192    = 3145728
  float* a      = qkv + BB * NN * 192;        // B*N*F      = 1048576
  float* scores = a + BB * NN * FF;           // B*N        = 16384
  int*   idxb   = (int*)(scores + BB * NN);   // B*TOPK     = 128
  float* r2g    = (float*)(idxb + BB * TOPK); // B*8192     = 65536
  float* h1g    = r2g + BB * 8192;            // B*1024     = 8192

  float* out = (float*)d_out;  // fp32: h at [0,4096), idx-as-float at [4096,4224)

  k_transpose<<<(BB * NN * FF) / 256, 256, 0, stream>>>(sv, x);

  for (int l = 0; l < NLAYER; ++l) {
    k_qkv2<<<dim3(BB * NN / 64, 3), 256, 0, stream>>>(x, tl_win + l * 192 * FF,
                                                      tl_bin + l * 192, qkv);
    k_attn<<<dim3(NN / 256, NHEAD, BB), 256, 0, stream>>>(qkv, a);
    k_proj2<<<BB * NN / 64, 256, 0, stream>>>(a, tl_wout + l * FF * FF, tl_bout + l * FF,
                                              tl_ln1g + l * FF, tl_ln1b + l * FF, x);
    k_ffn2<<<BB * NN / 64, 256, 0, stream>>>(tl_w1 + l * 2048 * FF, tl_b1 + l * 2048,
                                             tl_w2 + l * FF * 2048, tl_b2 + l * FF,
                                             tl_ln2g + l * FF, tl_ln2b + l * FF, x);
  }

  k_fg2<<<BB * NN / 64, 256, 0, stream>>>(x, fg_w0, fg_b0, fbn0, fg_w1, fg_b1, fbn1,
                                          fg_w2, fg_b2, fbn2, scores);
  k_topk<<<BB, 256, 0, stream>>>(scores, idxb, out + BB * 512);
  k_group<<<dim3(TOPK, BB), 64, 0, stream>>>(inp, idxb, rc_w0, rc_b0, rbn0,
                                             rc_w1, rc_b1, rbn1, rc_w2, rc_b2, rbn2, r2g);
  k_fl<<<BB * 1024, 64, 0, stream>>>(r2g, fl_w0, fl_b0, lbn0, h1g, 8192, 1024);
  k_fl<<<BB * 512, 64, 0, stream>>>(h1g, fl_w1, fl_b1, lbn1, out, 1024, 512);
}

// Round 4
// 1176.659 us; speedup vs baseline: 4.1401x; 1.3416x over previous
//
#include <hip/hip_runtime.h>
#include <hip/hip_bf16.h>
#include <math.h>

#define BB 8
#define NN 2048
#define FF 64
#define DD 6
#define NSAMP 64
#define TOPK 16
#define NHEAD 8
#define HD 8
#define NLAYER 2
#define EPSF 1e-5f
#define R2 0.09f

// ---------------- transpose sortvec (B,1,F,N) -> x (B,N,F) ----------------
__global__ void k_transpose(const float* __restrict__ sv, float* __restrict__ x) {
  int i = blockIdx.x * 256 + threadIdx.x;
  if (i >= BB * NN * FF) return;
  int f = i % FF;
  int n = (i / FF) % NN;
  int b = i / (FF * NN);
  x[i] = sv[(b * FF + f) * NN + n];
}

// ---------------- tiled GEMM: qkv[row][192] = x[row][64] @ win^T + bin ----------
// grid (256 row-tiles, 3 col-tiles), block 256. rows ty*4+ri, xs stride 68.
__global__ void k_qkv2(const float* __restrict__ x, const float* __restrict__ win,
                       const float* __restrict__ bin, float* __restrict__ qkv) {
  __shared__ float xs[64 * 68];
  __shared__ float ws[64 * 68];
  int row0 = blockIdx.x * 64, col0 = blockIdx.y * 64;
  int t = threadIdx.x;
  #pragma unroll
  for (int i = 0; i < 4; ++i) {
    int q = t + i * 256, r = q >> 4, c = (q & 15) * 4;
    *(float4*)(xs + r * 68 + c) = *(const float4*)(x + (size_t)(row0 + r) * 64 + c);
    *(float4*)(ws + r * 68 + c) = *(const float4*)(win + (size_t)(col0 + r) * 64 + c);
  }
  __syncthreads();
  int tx = t & 15, ty = t >> 4;
  float acc[4][4] = {};
  for (int f = 0; f < 64; f += 4) {
    float4 xv[4], wv[4];
    #pragma unroll
    for (int ri = 0; ri < 4; ++ri) xv[ri] = *(const float4*)(xs + (ty * 4 + ri) * 68 + f);
    #pragma unroll
    for (int ci = 0; ci < 4; ++ci) wv[ci] = *(const float4*)(ws + (tx + 16 * ci) * 68 + f);
    #pragma unroll
    for (int ri = 0; ri < 4; ++ri)
      #pragma unroll
      for (int ci = 0; ci < 4; ++ci)
        acc[ri][ci] += xv[ri].x * wv[ci].x + xv[ri].y * wv[ci].y +
                       xv[ri].z * wv[ci].z + xv[ri].w * wv[ci].w;
  }
  #pragma unroll
  for (int ri = 0; ri < 4; ++ri)
    #pragma unroll
    for (int ci = 0; ci < 4; ++ci) {
      int r = row0 + ty * 4 + ri, c = col0 + tx + 16 * ci;
      qkv[(size_t)r * 192 + c] = acc[ri][ci] + bin[c];
    }
}

// ---------------- attention v2: no running max (scores tiny), float4 kv ----
#define CHK 128
__global__ void k_attn2(const float* __restrict__ qkv, float* __restrict__ a) {
  __shared__ float kv[CHK * 16];
  int n = blockIdx.x * 256 + threadIdx.x;
  int h = blockIdx.y, b = blockIdx.z;
  const float* qrow = qkv + ((size_t)(b * NN + n)) * 192 + h * HD;
  float4 q0 = *(const float4*)(qrow);
  float4 q1 = *(const float4*)(qrow + 4);
  float l = 0.f;
  float4 a0 = {0, 0, 0, 0}, a1 = {0, 0, 0, 0};
  const float scale = 0.35355339059327373f;  // 1/sqrt(8)
  for (int base = 0; base < NN; base += CHK) {
    for (int i = threadIdx.x; i < CHK * 16; i += 256) {
      int m = i >> 4, d = i & 15;
      size_t off = ((size_t)(b * NN + base + m)) * 192;
      kv[i] = (d < 8) ? qkv[off + 64 + h * HD + d] : qkv[off + 128 + h * HD + (d - 8)];
    }
    __syncthreads();
    #pragma unroll 2
    for (int m = 0; m < CHK; ++m) {
      const float4 k0 = *(const float4*)(kv + m * 16);
      const float4 k1 = *(const float4*)(kv + m * 16 + 4);
      float s = q0.x * k0.x + q0.y * k0.y + q0.z * k0.z + q0.w * k0.w +
                q1.x * k1.x + q1.y * k1.y + q1.z * k1.z + q1.w * k1.w;
      float p = __expf(s * scale);
      l += p;
      const float4 v0 = *(const float4*)(kv + m * 16 + 8);
      const float4 v1 = *(const float4*)(kv + m * 16 + 12);
      a0.x += p * v0.x; a0.y += p * v0.y; a0.z += p * v0.z; a0.w += p * v0.w;
      a1.x += p * v1.x; a1.y += p * v1.y; a1.z += p * v1.z; a1.w += p * v1.w;
    }
    __syncthreads();
  }
  float inv = 1.f / l;
  float* out = a + ((size_t)(b * NN + n)) * FF + h * HD;
  float4 o0 = {a0.x * inv, a0.y * inv, a0.z * inv, a0.w * inv};
  float4 o1 = {a1.x * inv, a1.y * inv, a1.z * inv, a1.w * inv};
  *(float4*)(out) = o0;
  *(float4*)(out + 4) = o1;
}

// ------- proj + residual + LN, tiled GEMM, rows ty*4+ri, xs stride 68 ---------
__global__ void k_proj2(const float* __restrict__ a, const float* __restrict__ wout,
                        const float* __restrict__ bout, const float* __restrict__ g,
                        const float* __restrict__ be, float* __restrict__ x) {
  __shared__ float xs[64 * 68];
  __shared__ float ws[64 * 68];
  int row0 = blockIdx.x * 64;
  int t = threadIdx.x;
  #pragma unroll
  for (int i = 0; i < 4; ++i) {
    int q = t + i * 256, r = q >> 4, c = (q & 15) * 4;
    *(float4*)(xs + r * 68 + c) = *(const float4*)(a + (size_t)(row0 + r) * 64 + c);
    *(float4*)(ws + r * 68 + c) = *(const float4*)(wout + r * 64 + c);
  }
  __syncthreads();
  int tx = t & 15, ty = t >> 4;
  float acc[4][4] = {};
  for (int f = 0; f < 64; f += 4) {
    float4 xv[4], wv[4];
    #pragma unroll
    for (int ri = 0; ri < 4; ++ri) xv[ri] = *(const float4*)(xs + (ty * 4 + ri) * 68 + f);
    #pragma unroll
    for (int ci = 0; ci < 4; ++ci) wv[ci] = *(const float4*)(ws + (tx + 16 * ci) * 68 + f);
    #pragma unroll
    for (int ri = 0; ri < 4; ++ri)
      #pragma unroll
      for (int ci = 0; ci < 4; ++ci)
        acc[ri][ci] += xv[ri].x * wv[ci].x + xv[ri].y * wv[ci].y +
                       xv[ri].z * wv[ci].z + xv[ri].w * wv[ci].w;
  }
  #pragma unroll
  for (int ri = 0; ri < 4; ++ri) {
    int rl = ty * 4 + ri;
    float val[4], s = 0.f, sq = 0.f;
    #pragma unroll
    for (int ci = 0; ci < 4; ++ci) {
      int c = tx + 16 * ci;
      val[ci] = x[(size_t)(row0 + rl) * 64 + c] + bout[c] + acc[ri][ci];
      s += val[ci]; sq += val[ci] * val[ci];
    }
    #pragma unroll
    for (int off = 1; off < 16; off <<= 1) { s += __shfl_xor(s, off); sq += __shfl_xor(sq, off); }
    float mean = s * (1.f / 64.f);
    float var = sq * (1.f / 64.f) - mean * mean;
    float rstd = rsqrtf(var + EPSF);
    #pragma unroll
    for (int ci = 0; ci < 4; ++ci) {
      int c = tx + 16 * ci;
      x[(size_t)(row0 + rl) * 64 + c] = (val[ci] - mean) * rstd * g[c] + be[c];
    }
  }
}

// ------- FFN split-K: grid (256 row-tiles, 4 k-splits). Each block does 8
// hidden-chunks of 64 and writes a partial (no residual/LN). ----------------
__global__ void k_ffn3(const float* __restrict__ x,
                       const float* __restrict__ w1, const float* __restrict__ b1,
                       const float* __restrict__ w2, float* __restrict__ part) {
  __shared__ float xs[64 * 68];
  __shared__ float ws[64 * 68];
  __shared__ float hs[64 * 68];
  __shared__ float b1s[64];
  int row0 = blockIdx.x * 64;
  int ks = blockIdx.y;
  int t = threadIdx.x;
  int tx = t & 15, ty = t >> 4;
  #pragma unroll
  for (int i = 0; i < 4; ++i) {
    int q = t + i * 256, r = q >> 4, c = (q & 15) * 4;
    *(float4*)(xs + r * 68 + c) = *(const float4*)(x + (size_t)(row0 + r) * 64 + c);
  }
  float acc[4][4] = {};
  for (int ch = 0; ch < 8; ++ch) {
    int kc = (ks * 8 + ch) * 64;
    float4 rw[4], rb;
    #pragma unroll
    for (int i = 0; i < 4; ++i) {
      int q = t + i * 256, r = q >> 4, c = (q & 15) * 4;
      rw[i] = *(const float4*)(w1 + (size_t)(kc + r) * 64 + c);
    }
    if (t < 16) rb = *(const float4*)(b1 + kc + t * 4);
    __syncthreads();  // (A) prev phase2 done with ws/hs; xs ready on ch==0
    #pragma unroll
    for (int i = 0; i < 4; ++i) {
      int q = t + i * 256, r = q >> 4, c = (q & 15) * 4;
      *(float4*)(ws + r * 68 + c) = rw[i];
    }
    if (t < 16) *(float4*)(b1s + t * 4) = rb;
    __syncthreads();  // (B) w1 chunk ready
    float a1[4][4] = {};
    for (int f = 0; f < 64; f += 4) {
      float4 xv[4], wv[4];
      #pragma unroll
      for (int ri = 0; ri < 4; ++ri) xv[ri] = *(const float4*)(xs + (ty * 4 + ri) * 68 + f);
      #pragma unroll
      for (int ki = 0; ki < 4; ++ki) wv[ki] = *(const float4*)(ws + (tx + 16 * ki) * 68 + f);
      #pragma unroll
      for (int ri = 0; ri < 4; ++ri)
        #pragma unroll
        for (int ki = 0; ki < 4; ++ki)
          a1[ri][ki] += xv[ri].x * wv[ki].x + xv[ri].y * wv[ki].y +
                        xv[ri].z * wv[ki].z + xv[ri].w * wv[ki].w;
    }
    #pragma unroll
    for (int ri = 0; ri < 4; ++ri)
      #pragma unroll
      for (int ki = 0; ki < 4; ++ki) {
        int k = tx + 16 * ki;
        hs[(ty * 4 + ri) * 68 + k] = fmaxf(a1[ri][ki] + b1s[k], 0.f);
      }
    #pragma unroll
    for (int i = 0; i < 4; ++i) {
      int q = t + i * 256, j = q >> 4, c = (q & 15) * 4;
      rw[i] = *(const float4*)(w2 + (size_t)j * 2048 + kc + c);
    }
    __syncthreads();  // (C) phase1 done with ws; hs written
    #pragma unroll
    for (int i = 0; i < 4; ++i) {
      int q = t + i * 256, j = q >> 4, c = (q & 15) * 4;
      *(float4*)(ws + j * 68 + c) = rw[i];
    }
    __syncthreads();  // (D) w2 chunk ready
    for (int k = 0; k < 64; k += 4) {
      float4 hv[4], wv[4];
      #pragma unroll
      for (int ri = 0; ri < 4; ++ri) hv[ri] = *(const float4*)(hs + (ty * 4 + ri) * 68 + k);
      #pragma unroll
      for (int ji = 0; ji < 4; ++ji) wv[ji] = *(const float4*)(ws + (tx + 16 * ji) * 68 + k);
      #pragma unroll
      for (int ri = 0; ri < 4; ++ri)
        #pragma unroll
        for (int ji = 0; ji < 4; ++ji)
          acc[ri][ji] += hv[ri].x * wv[ji].x + hv[ri].y * wv[ji].y +
                         hv[ri].z * wv[ji].z + hv[ri].w * wv[ji].w;
    }
  }
  float* pb = part + (size_t)ks * (BB * NN * 64);
  #pragma unroll
  for (int ri = 0; ri < 4; ++ri)
    #pragma unroll
    for (int ji = 0; ji < 4; ++ji)
      pb[(size_t)(row0 + ty * 4 + ri) * 64 + tx + 16 * ji] = acc[ri][ji];
}

// ------- combine 4 partials + residual + b2 + LN; one wave per row ---------
__global__ void k_ffn_ln(const float* __restrict__ part, const float* __restrict__ b2,
                         const float* __restrict__ g, const float* __restrict__ be,
                         float* __restrict__ x) {
  int row = blockIdx.x * 4 + (threadIdx.x >> 6);
  int j = threadIdx.x & 63;
  size_t o = (size_t)row * 64 + j;
  const size_t S = (size_t)BB * NN * 64;
  float val = x[o] + b2[j] + ((part[o] + part[o + S]) + (part[o + 2 * S] + part[o + 3 * S]));
  float s = val;
  for (int off = 32; off; off >>= 1) s += __shfl_xor(s, off);
  s *= (1.f / 64.f);
  float d = val - s;
  float v = d * d;
  for (int off = 32; off; off >>= 1) v += __shfl_xor(v, off);
  v *= (1.f / 64.f);
  x[o] = d * rsqrtf(v + EPSF) * g[j] + be[j];
}

// ------- score head tiled: 64 rows/block; 64->64 GEMM then 16 then 1 ----------
__global__ void k_fg2(const float* __restrict__ x,
                      const float* __restrict__ w0, const float* __restrict__ b0, const float* __restrict__ bn0,
                      const float* __restrict__ w1, const float* __restrict__ b1, const float* __restrict__ bn1,
                      const float* __restrict__ w2, const float* __restrict__ b2, const float* __restrict__ bn2,
                      float* __restrict__ scores) {
  __shared__ float xs[64 * 68];
  __shared__ float ws[64 * 68];
  __shared__ float s0s[64 * 68];
  __shared__ float s1s[64 * 20];
  int row0 = blockIdx.x * 64;
  int t = threadIdx.x;
  #pragma unroll
  for (int i = 0; i < 4; ++i) {
    int q = t + i * 256, r = q >> 4, c = (q & 15) * 4;
    *(float4*)(xs + r * 68 + c) = *(const float4*)(x + (size_t)(row0 + r) * 64 + c);
    *(float4*)(ws + r * 68 + c) = *(const float4*)(w0 + r * 64 + c);
  }
  __syncthreads();
  int tx = t & 15, ty = t >> 4;
  float acc[4][4] = {};
  for (int f = 0; f < 64; f += 4) {
    float4 xv[4], wv[4];
    #pragma unroll
    for (int ri = 0; ri < 4; ++ri) xv[ri] = *(const float4*)(xs + (ty * 4 + ri) * 68 + f);
    #pragma unroll
    for (int ci = 0; ci < 4; ++ci) wv[ci] = *(const float4*)(ws + (tx + 16 * ci) * 68 + f);
    #pragma unroll
    for (int ri = 0; ri < 4; ++ri)
      #pragma unroll
      for (int ci = 0; ci < 4; ++ci)
        acc[ri][ci] += xv[ri].x * wv[ci].x + xv[ri].y * wv[ci].y +
                       xv[ri].z * wv[ci].z + xv[ri].w * wv[ci].w;
  }
  #pragma unroll
  for (int ri = 0; ri < 4; ++ri)
    #pragma unroll
    for (int ci = 0; ci < 4; ++ci) {
      int c = tx + 16 * ci;
      float sc = bn0[c] * rsqrtf(bn0[192 + c] + EPSF);
      float v = (acc[ri][ci] + b0[c] - bn0[128 + c]) * sc + bn0[64 + c];
      s0s[(ty * 4 + ri) * 68 + c] = fmaxf(v, 0.f);
    }
  __syncthreads();
  {  // stage 2: 64 -> 16, each thread 4 (row,j) pairs
    int rl = t & 63, j0 = t >> 6;
    #pragma unroll
    for (int i = 0; i < 4; ++i) {
      int j = j0 + 4 * i;
      float s = b1[j];
      const float* wr = w1 + j * 64;
      #pragma unroll 16
      for (int c = 0; c < 64; ++c) s += s0s[rl * 68 + c] * wr[c];
      float sc = bn1[j] * rsqrtf(bn1[48 + j] + EPSF);
      s = (s - bn1[32 + j]) * sc + bn1[16 + j];
      s1s[rl * 20 + j] = fmaxf(s, 0.f);
    }
  }
  __syncthreads();
  if (t < 64) {
    float s = b2[0];
    #pragma unroll
    for (int o = 0; o < 16; ++o) s += s1s[t * 20 + o] * w2[o];
    float sc = bn2[0] * rsqrtf(bn2[3] + EPSF);
    s = (s - bn2[2]) * sc + bn2[1];
    scores[row0 + t] = fmaxf(s, 0.f);
  }
}

// ---- top-k (k=16): register-resident vals, wave shuffle reduce, tie->lowest --
__global__ void k_topk2(const float* __restrict__ scores, int* __restrict__ idx,
                        float* __restrict__ out_idx) {
  int b = blockIdx.x, t = threadIdx.x;
  float v[8];
  int base = b * NN;
  #pragma unroll
  for (int u = 0; u < 8; ++u) v[u] = scores[base + t + 256 * u];
  __shared__ float wvs[4];
  __shared__ int wis[4];
  __shared__ int winner;
  unsigned taken = 0;
  for (int r = 0; r < TOPK; ++r) {
    float best = -1e30f; int bi = 1 << 30;
    #pragma unroll
    for (int u = 0; u < 8; ++u) {
      if (!((taken >> u) & 1)) {
        float vv = v[u]; int ii = t + 256 * u;
        if (vv > best || (vv == best && ii < bi)) { best = vv; bi = ii; }
      }
    }
    for (int off = 32; off; off >>= 1) {
      float ov = __shfl_xor(best, off);
      int oi = __shfl_xor(bi, off);
      if (ov > best || (ov == best && oi < bi)) { best = ov; bi = oi; }
    }
    if ((t & 63) == 0) { wvs[t >> 6] = best; wis[t >> 6] = bi; }
    __syncthreads();
    if (t == 0) {
      float B = wvs[0]; int I = wis[0];
      #pragma unroll
      for (int q = 1; q < 4; ++q)
        if (wvs[q] > B || (wvs[q] == B && wis[q] < I)) { B = wvs[q]; I = wis[q]; }
      winner = I;
      idx[b * TOPK + r] = I;
      out_idx[b * TOPK + r] = (float)I;
    }
    __syncthreads();
    int w = winner;
    if ((w & 255) == t) taken |= 1u << (w >> 8);
  }
}

// ---------------- ball query + 3 conv stages, block = 64 per (b,k) ----------------
__global__ void k_group(const float* __restrict__ inp, const int* __restrict__ idx,
                        const float* __restrict__ w0, const float* __restrict__ b0, const float* __restrict__ bn0,
                        const float* __restrict__ w1, const float* __restrict__ b1, const float* __restrict__ bn1,
                        const float* __restrict__ w2, const float* __restrict__ b2, const float* __restrict__ bn2,
                        float* __restrict__ r2g) {
  __shared__ int gidx[NSAMP];
  __shared__ float gsh[65 * DD];
  __shared__ float r0[128];
  __shared__ float r1[256];
  int k = blockIdx.x, b = blockIdx.y;
  int lane = threadIdx.x;  // 64
  int qn = idx[b * TOPK + k];
  const float* px = inp + (size_t)b * DD * NN;  // [d*N + n]
  float qx = px[qn], qy = px[NN + qn], qz = px[2 * NN + qn];
  int cnt = 0;
  for (int base = 0; base < NN && cnt < NSAMP; base += 64) {
    int n = base + lane;
    float dx = px[n] - qx, dy = px[NN + n] - qy, dz = px[2 * NN + n] - qz;
    float d2 = dx * dx + dy * dy + dz * dz;
    bool flag = (d2 <= R2);
    unsigned long long m = __ballot(flag);
    int pos = cnt + __popcll(m & ((1ull << lane) - 1ull));
    if (flag && pos < NSAMP) gidx[pos] = n;
    cnt += (int)__popcll(m);
  }
  __syncthreads();
  int total = cnt < NSAMP ? cnt : NSAMP;
  if (lane >= total) gidx[lane] = gidx[0];
  __syncthreads();
  for (int i = lane; i < 65 * DD; i += 64) {
    int p = i / DD, d = i - p * DD;
    int n = (p == 0) ? qn : gidx[p - 1];
    gsh[i] = px[d * NN + n];
  }
  __syncthreads();
  for (int c = lane; c < 128; c += 64) {
    float s = b0[c];
    const float* w = w0 + c * 390;
    for (int i = 0; i < 390; ++i) s += gsh[i] * w[i];
    float sc = bn0[c] * rsqrtf(bn0[384 + c] + EPSF);
    s = (s - bn0[256 + c]) * sc + bn0[128 + c];
    r0[c] = fmaxf(s, 0.f);
  }
  __syncthreads();
  for (int c = lane; c < 256; c += 64) {
    float s = b1[c];
    const float* w = w1 + c * 128;
    for (int o = 0; o < 128; ++o) s += r0[o] * w[o];
    float sc = bn1[c] * rsqrtf(bn1[768 + c] + EPSF);
    s = (s - bn1[512 + c]) * sc + bn1[256 + c];
    r1[c] = fmaxf(s, 0.f);
  }
  __syncthreads();
  for (int c = lane; c < 512; c += 64) {
    float s = b2[c];
    const float* w = w2 + c * 256;
    for (int o = 0; o < 256; ++o) s += r1[o] * w[o];
    float sc = bn2[c] * rsqrtf(bn2[1536 + c] + EPSF);
    s = (s - bn2[1024 + c]) * sc + bn2[512 + c];
    r2g[b * 8192 + c * TOPK + k] = fmaxf(s, 0.f);
  }
}

// ---------------- FC + BN + ReLU (wave-reduced dot), block=64 ----------------
__global__ void k_fl(const float* __restrict__ hin, const float* __restrict__ w,
                     const float* __restrict__ bias, const float* __restrict__ bn,
                     float* __restrict__ hout, int IN, int OUT) {
  int blk = blockIdx.x;
  int b = blk / OUT, j = blk % OUT;
  int lane = threadIdx.x;
  const float* hr = hin + (size_t)b * IN;
  const float* wr = w + (size_t)j * IN;
  float s = 0.f;
  for (int i = lane; i < IN; i += 64) s += hr[i] * wr[i];
  for (int o = 32; o; o >>= 1) s += __shfl_xor(s, o);
  if (lane == 0) {
    s += bias[j];
    float sc = bn[j] * rsqrtf(bn[3 * OUT + j] + EPSF);
    s = (s - bn[2 * OUT + j]) * sc + bn[OUT + j];
    hout[b * OUT + j] = fmaxf(s, 0.f);
  }
}

extern "C" void kernel_launch(void* const* d_in, const int* in_sizes, int n_in,
                              void* d_out, int out_size, void* d_ws, size_t ws_size,
                              hipStream_t stream) {
  const float* sv      = (const float*)d_in[0];
  const float* inp     = (const float*)d_in[1];
  const float* tl_win  = (const float*)d_in[2];
  const float* tl_bin  = (const float*)d_in[3];
  const float* tl_wout = (const float*)d_in[4];
  const float* tl_bout = (const float*)d_in[5];
  const float* tl_w1   = (const float*)d_in[6];
  const float* tl_b1   = (const float*)d_in[7];
  const float* tl_w2   = (const float*)d_in[8];
  const float* tl_b2   = (const float*)d_in[9];
  const float* tl_ln1g = (const float*)d_in[10];
  const float* tl_ln1b = (const float*)d_in[11];
  const float* tl_ln2g = (const float*)d_in[12];
  const float* tl_ln2b = (const float*)d_in[13];
  const float* fg_w0   = (const float*)d_in[14];
  const float* fg_b0   = (const float*)d_in[15];
  const float* fg_w1   = (const float*)d_in[16];
  const float* fg_b1   = (const float*)d_in[17];
  const float* fg_w2   = (const float*)d_in[18];
  const float* fg_b2   = (const float*)d_in[19];
  const float* fbn0    = (const float*)d_in[20];
  const float* fbn1    = (const float*)d_in[21];
  const float* fbn2    = (const float*)d_in[22];
  const float* rc_w0   = (const float*)d_in[23];
  const float* rc_b0   = (const float*)d_in[24];
  const float* rc_w1   = (const float*)d_in[25];
  const float* rc_b1   = (const float*)d_in[26];
  const float* rc_w2   = (const float*)d_in[27];
  const float* rc_b2   = (const float*)d_in[28];
  const float* rbn0    = (const float*)d_in[29];
  const float* rbn1    = (const float*)d_in[30];
  const float* rbn2    = (const float*)d_in[31];
  const float* fl_w0   = (const float*)d_in[32];
  const float* fl_b0   = (const float*)d_in[33];
  const float* fl_w1   = (const float*)d_in[34];
  const float* fl_b1   = (const float*)d_in[35];
  const float* lbn0    = (const float*)d_in[36];
  const float* lbn1    = (const float*)d_in[37];
  (void)in_sizes; (void)n_in; (void)out_size; (void)ws_size;

  float* ws = (float*)d_ws;
  float* x      = ws;                         // B*N*F      = 1048576
  float* qkv    = x + BB * NN * FF;           // B*N*192    = 3145728
  float* a      = qkv + BB * NN * 192;        // B*N*F      = 1048576
  float* scores = a + BB * NN * FF;           // B*N        = 16384
  int*   idxb   = (int*)(scores + BB * NN);   // B*TOPK     = 128
  float* r2g    = (float*)(idxb + BB * TOPK); // B*8192     = 65536
  float* h1g    = r2g + BB * 8192;            // B*1024     = 8192
  // FFN split-K partials reuse qkv+a (exactly 4*16384*64 floats, dead then)
  float* part   = qkv;

  float* out = (float*)d_out;  // fp32: h at [0,4096), idx-as-float at [4096,4224)

  k_transpose<<<(BB * NN * FF) / 256, 256, 0, stream>>>(sv, x);

  for (int l = 0; l < NLAYER; ++l) {
    k_qkv2<<<dim3(BB * NN / 64, 3), 256, 0, stream>>>(x, tl_win + l * 192 * FF,
                                                      tl_bin + l * 192, qkv);
    k_attn2<<<dim3(NN / 256, NHEAD, BB), 256, 0, stream>>>(qkv, a);
    k_proj2<<<BB * NN / 64, 256, 0, stream>>>(a, tl_wout + l * FF * FF, tl_bout + l * FF,
                                              tl_ln1g + l * FF, tl_ln1b + l * FF, x);
    k_ffn3<<<dim3(BB * NN / 64, 4), 256, 0, stream>>>(x, tl_w1 + l * 2048 * FF,
                                                      tl_b1 + l * 2048,
                                                      tl_w2 + l * FF * 2048, part);
    k_ffn_ln<<<BB * NN / 4, 256, 0, stream>>>(part, tl_b2 + l * FF,
                                              tl_ln2g + l * FF, tl_ln2b + l * FF, x);
  }

  k_fg2<<<BB * NN / 64, 256, 0, stream>>>(x, fg_w0, fg_b0, fbn0, fg_w1, fg_b1, fbn1,
                                          fg_w2, fg_b2, fbn2, scores);
  k_topk2<<<BB, 256, 0, stream>>>(scores, idxb, out + BB * 512);
  k_group<<<dim3(TOPK, BB), 64, 0, stream>>>(inp, idxb, rc_w0, rc_b0, rbn0,
                                             rc_w1, rc_b1, rbn1, rc_w2, rc_b2, rbn2, r2g);
  k_fl<<<BB * 1024, 64, 0, stream>>>(r2g, fl_w0, fl_b0, lbn0, h1g, 8192, 1024);
  k_fl<<<BB * 512, 64, 0, stream>>>(h1g, fl_w1, fl_b1, lbn1, out, 1024, 512);
}

// Round 5
// 1047.878 us; speedup vs baseline: 4.6490x; 1.1229x over previous
//
#include <hip/hip_runtime.h>
#include <hip/hip_bf16.h>
#include <math.h>

#define BB 8
#define NN 2048
#define FF 64
#define DD 6
#define NSAMP 64
#define TOPK 16
#define NHEAD 8
#define HD 8
#define NLAYER 2
#define EPSF 1e-5f
#define R2 0.09f

// ---------------- transpose sortvec (B,1,F,N) -> x (B,N,F) ----------------
__global__ void k_transpose(const float* __restrict__ sv, float* __restrict__ x) {
  int i = blockIdx.x * 256 + threadIdx.x;
  if (i >= BB * NN * FF) return;
  int f = i % FF;
  int n = (i / FF) % NN;
  int b = i / (FF * NN);
  x[i] = sv[(b * FF + f) * NN + n];
}

// ---------------- tiled GEMM: qkv[row][192] = x[row][64] @ win^T + bin ----------
__global__ void k_qkv2(const float* __restrict__ x, const float* __restrict__ win,
                       const float* __restrict__ bin, float* __restrict__ qkv) {
  __shared__ float xs[64 * 68];
  __shared__ float ws[64 * 68];
  int row0 = blockIdx.x * 64, col0 = blockIdx.y * 64;
  int t = threadIdx.x;
  #pragma unroll
  for (int i = 0; i < 4; ++i) {
    int q = t + i * 256, r = q >> 4, c = (q & 15) * 4;
    *(float4*)(xs + r * 68 + c) = *(const float4*)(x + (size_t)(row0 + r) * 64 + c);
    *(float4*)(ws + r * 68 + c) = *(const float4*)(win + (size_t)(col0 + r) * 64 + c);
  }
  __syncthreads();
  int tx = t & 15, ty = t >> 4;
  float acc[4][4] = {};
  for (int f = 0; f < 64; f += 4) {
    float4 xv[4], wv[4];
    #pragma unroll
    for (int ri = 0; ri < 4; ++ri) xv[ri] = *(const float4*)(xs + (ty * 4 + ri) * 68 + f);
    #pragma unroll
    for (int ci = 0; ci < 4; ++ci) wv[ci] = *(const float4*)(ws + (tx + 16 * ci) * 68 + f);
    #pragma unroll
    for (int ri = 0; ri < 4; ++ri)
      #pragma unroll
      for (int ci = 0; ci < 4; ++ci)
        acc[ri][ci] += xv[ri].x * wv[ci].x + xv[ri].y * wv[ci].y +
                       xv[ri].z * wv[ci].z + xv[ri].w * wv[ci].w;
  }
  #pragma unroll
  for (int ri = 0; ri < 4; ++ri)
    #pragma unroll
    for (int ci = 0; ci < 4; ++ci) {
      int r = row0 + ty * 4 + ri, c = col0 + tx + 16 * ci;
      qkv[(size_t)r * 192 + c] = acc[ri][ci] + bin[c];
    }
}

// ---- attention v3: 1024-thread block, 4 key-splits resident, max occupancy ----
// block covers 256 queries (lt = t&255) x all 2048 keys (ksp = t>>8 owns 512).
// Partials combined via LDS tree (deterministic order).
#define ACHK 128
__global__ void __launch_bounds__(1024, 8)
k_attn3(const float* __restrict__ qkv, float* __restrict__ a) {
  __shared__ float kv[4 * ACHK * 16];   // 32 KB: per-split chunk
  __shared__ float cbuf[2 * 256 * 9];   // 18.4 KB: combine buffer, stride 9
  int t = threadIdx.x;
  int ksp = t >> 8, lt = t & 255;
  int n = blockIdx.x * 256 + lt;
  int h = blockIdx.y, b = blockIdx.z;
  const float* qrow = qkv + ((size_t)(b * NN + n)) * 192 + h * HD;
  float4 q0 = *(const float4*)(qrow);
  float4 q1 = *(const float4*)(qrow + 4);
  float l = 0.f;
  float4 a0 = {0, 0, 0, 0}, a1 = {0, 0, 0, 0};
  const float scale = 0.35355339059327373f;  // 1/sqrt(8)
  const float* my_kv = kv + ksp * (ACHK * 16);
  for (int c = 0; c < 512 / ACHK; ++c) {
    // all 1024 threads stage all 4 splits' chunks
    #pragma unroll
    for (int u = 0; u < 8; ++u) {
      int i = t + u * 1024;                 // < 8192
      int g = i >> 11, j = i & 2047;
      int m = j >> 4, d = j & 15;
      int key = g * 512 + c * ACHK + m;
      size_t off = ((size_t)(b * NN + key)) * 192;
      kv[i] = (d < 8) ? qkv[off + 64 + h * HD + d] : qkv[off + 128 + h * HD + (d - 8)];
    }
    __syncthreads();
    #pragma unroll 2
    for (int m = 0; m < ACHK; ++m) {
      const float4 k0 = *(const float4*)(my_kv + m * 16);
      const float4 k1 = *(const float4*)(my_kv + m * 16 + 4);
      float s = q0.x * k0.x + q0.y * k0.y + q0.z * k0.z + q0.w * k0.w +
                q1.x * k1.x + q1.y * k1.y + q1.z * k1.z + q1.w * k1.w;
      float p = __expf(s * scale);
      l += p;
      const float4 v0 = *(const float4*)(my_kv + m * 16 + 8);
      const float4 v1 = *(const float4*)(my_kv + m * 16 + 12);
      a0.x += p * v0.x; a0.y += p * v0.y; a0.z += p * v0.z; a0.w += p * v0.w;
      a1.x += p * v1.x; a1.y += p * v1.y; a1.z += p * v1.z; a1.w += p * v1.w;
    }
    __syncthreads();
  }
  // combine: (0<-2, 1<-3), then (0<-1). Fixed order => deterministic.
  if (ksp >= 2) {
    float* cb = cbuf + (ksp - 2) * (256 * 9) + lt * 9;
    cb[0] = l;
    cb[1] = a0.x; cb[2] = a0.y; cb[3] = a0.z; cb[4] = a0.w;
    cb[5] = a1.x; cb[6] = a1.y; cb[7] = a1.z; cb[8] = a1.w;
  }
  __syncthreads();
  if (ksp < 2) {
    const float* cb = cbuf + ksp * (256 * 9) + lt * 9;
    l += cb[0];
    a0.x += cb[1]; a0.y += cb[2]; a0.z += cb[3]; a0.w += cb[4];
    a1.x += cb[5]; a1.y += cb[6]; a1.z += cb[7]; a1.w += cb[8];
  }
  __syncthreads();
  if (ksp == 1) {
    float* cb = cbuf + lt * 9;
    cb[0] = l;
    cb[1] = a0.x; cb[2] = a0.y; cb[3] = a0.z; cb[4] = a0.w;
    cb[5] = a1.x; cb[6] = a1.y; cb[7] = a1.z; cb[8] = a1.w;
  }
  __syncthreads();
  if (ksp == 0) {
    const float* cb = cbuf + lt * 9;
    l += cb[0];
    a0.x += cb[1]; a0.y += cb[2]; a0.z += cb[3]; a0.w += cb[4];
    a1.x += cb[5]; a1.y += cb[6]; a1.z += cb[7]; a1.w += cb[8];
    float inv = 1.f / l;
    float* out = a + ((size_t)(b * NN + n)) * FF + h * HD;
    float4 o0 = {a0.x * inv, a0.y * inv, a0.z * inv, a0.w * inv};
    float4 o1 = {a1.x * inv, a1.y * inv, a1.z * inv, a1.w * inv};
    *(float4*)(out) = o0;
    *(float4*)(out + 4) = o1;
  }
}

// ------- proj + residual + LN, tiled GEMM, rows ty*4+ri, xs stride 68 ---------
__global__ void k_proj2(const float* __restrict__ a, const float* __restrict__ wout,
                        const float* __restrict__ bout, const float* __restrict__ g,
                        const float* __restrict__ be, float* __restrict__ x) {
  __shared__ float xs[64 * 68];
  __shared__ float ws[64 * 68];
  int row0 = blockIdx.x * 64;
  int t = threadIdx.x;
  #pragma unroll
  for (int i = 0; i < 4; ++i) {
    int q = t + i * 256, r = q >> 4, c = (q & 15) * 4;
    *(float4*)(xs + r * 68 + c) = *(const float4*)(a + (size_t)(row0 + r) * 64 + c);
    *(float4*)(ws + r * 68 + c) = *(const float4*)(wout + r * 64 + c);
  }
  __syncthreads();
  int tx = t & 15, ty = t >> 4;
  float acc[4][4] = {};
  for (int f = 0; f < 64; f += 4) {
    float4 xv[4], wv[4];
    #pragma unroll
    for (int ri = 0; ri < 4; ++ri) xv[ri] = *(const float4*)(xs + (ty * 4 + ri) * 68 + f);
    #pragma unroll
    for (int ci = 0; ci < 4; ++ci) wv[ci] = *(const float4*)(ws + (tx + 16 * ci) * 68 + f);
    #pragma unroll
    for (int ri = 0; ri < 4; ++ri)
      #pragma unroll
      for (int ci = 0; ci < 4; ++ci)
        acc[ri][ci] += xv[ri].x * wv[ci].x + xv[ri].y * wv[ci].y +
                       xv[ri].z * wv[ci].z + xv[ri].w * wv[ci].w;
  }
  #pragma unroll
  for (int ri = 0; ri < 4; ++ri) {
    int rl = ty * 4 + ri;
    float val[4], s = 0.f, sq = 0.f;
    #pragma unroll
    for (int ci = 0; ci < 4; ++ci) {
      int c = tx + 16 * ci;
      val[ci] = x[(size_t)(row0 + rl) * 64 + c] + bout[c] + acc[ri][ci];
      s += val[ci]; sq += val[ci] * val[ci];
    }
    #pragma unroll
    for (int off = 1; off < 16; off <<= 1) { s += __shfl_xor(s, off); sq += __shfl_xor(sq, off); }
    float mean = s * (1.f / 64.f);
    float var = sq * (1.f / 64.f) - mean * mean;
    float rstd = rsqrtf(var + EPSF);
    #pragma unroll
    for (int ci = 0; ci < 4; ++ci) {
      int c = tx + 16 * ci;
      x[(size_t)(row0 + rl) * 64 + c] = (val[ci] - mean) * rstd * g[c] + be[c];
    }
  }
}

// ------- FFN split-K: grid (256 row-tiles, 4 k-splits) ----------------
__global__ void k_ffn3(const float* __restrict__ x,
                       const float* __restrict__ w1, const float* __restrict__ b1,
                       const float* __restrict__ w2, float* __restrict__ part) {
  __shared__ float xs[64 * 68];
  __shared__ float ws[64 * 68];
  __shared__ float hs[64 * 68];
  __shared__ float b1s[64];
  int row0 = blockIdx.x * 64;
  int ks = blockIdx.y;
  int t = threadIdx.x;
  int tx = t & 15, ty = t >> 4;
  #pragma unroll
  for (int i = 0; i < 4; ++i) {
    int q = t + i * 256, r = q >> 4, c = (q & 15) * 4;
    *(float4*)(xs + r * 68 + c) = *(const float4*)(x + (size_t)(row0 + r) * 64 + c);
  }
  float acc[4][4] = {};
  for (int ch = 0; ch < 8; ++ch) {
    int kc = (ks * 8 + ch) * 64;
    float4 rw[4], rb;
    #pragma unroll
    for (int i = 0; i < 4; ++i) {
      int q = t + i * 256, r = q >> 4, c = (q & 15) * 4;
      rw[i] = *(const float4*)(w1 + (size_t)(kc + r) * 64 + c);
    }
    if (t < 16) rb = *(const float4*)(b1 + kc + t * 4);
    __syncthreads();  // (A)
    #pragma unroll
    for (int i = 0; i < 4; ++i) {
      int q = t + i * 256, r = q >> 4, c = (q & 15) * 4;
      *(float4*)(ws + r * 68 + c) = rw[i];
    }
    if (t < 16) *(float4*)(b1s + t * 4) = rb;
    __syncthreads();  // (B)
    float a1[4][4] = {};
    for (int f = 0; f < 64; f += 4) {
      float4 xv[4], wv[4];
      #pragma unroll
      for (int ri = 0; ri < 4; ++ri) xv[ri] = *(const float4*)(xs + (ty * 4 + ri) * 68 + f);
      #pragma unroll
      for (int ki = 0; ki < 4; ++ki) wv[ki] = *(const float4*)(ws + (tx + 16 * ki) * 68 + f);
      #pragma unroll
      for (int ri = 0; ri < 4; ++ri)
        #pragma unroll
        for (int ki = 0; ki < 4; ++ki)
          a1[ri][ki] += xv[ri].x * wv[ki].x + xv[ri].y * wv[ki].y +
                        xv[ri].z * wv[ki].z + xv[ri].w * wv[ki].w;
    }
    #pragma unroll
    for (int ri = 0; ri < 4; ++ri)
      #pragma unroll
      for (int ki = 0; ki < 4; ++ki) {
        int k = tx + 16 * ki;
        hs[(ty * 4 + ri) * 68 + k] = fmaxf(a1[ri][ki] + b1s[k], 0.f);
      }
    #pragma unroll
    for (int i = 0; i < 4; ++i) {
      int q = t + i * 256, j = q >> 4, c = (q & 15) * 4;
      rw[i] = *(const float4*)(w2 + (size_t)j * 2048 + kc + c);
    }
    __syncthreads();  // (C)
    #pragma unroll
    for (int i = 0; i < 4; ++i) {
      int q = t + i * 256, j = q >> 4, c = (q & 15) * 4;
      *(float4*)(ws + j * 68 + c) = rw[i];
    }
    __syncthreads();  // (D)
    for (int k = 0; k < 64; k += 4) {
      float4 hv[4], wv[4];
      #pragma unroll
      for (int ri = 0; ri < 4; ++ri) hv[ri] = *(const float4*)(hs + (ty * 4 + ri) * 68 + k);
      #pragma unroll
      for (int ji = 0; ji < 4; ++ji) wv[ji] = *(const float4*)(ws + (tx + 16 * ji) * 68 + k);
      #pragma unroll
      for (int ri = 0; ri < 4; ++ri)
        #pragma unroll
        for (int ji = 0; ji < 4; ++ji)
          acc[ri][ji] += hv[ri].x * wv[ji].x + hv[ri].y * wv[ji].y +
                         hv[ri].z * wv[ji].z + hv[ri].w * wv[ji].w;
    }
  }
  float* pb = part + (size_t)ks * (BB * NN * 64);
  #pragma unroll
  for (int ri = 0; ri < 4; ++ri)
    #pragma unroll
    for (int ji = 0; ji < 4; ++ji)
      pb[(size_t)(row0 + ty * 4 + ri) * 64 + tx + 16 * ji] = acc[ri][ji];
}

// ------- combine 4 partials + residual + b2 + LN; one wave per row ---------
__global__ void k_ffn_ln(const float* __restrict__ part, const float* __restrict__ b2,
                         const float* __restrict__ g, const float* __restrict__ be,
                         float* __restrict__ x) {
  int row = blockIdx.x * 4 + (threadIdx.x >> 6);
  int j = threadIdx.x & 63;
  size_t o = (size_t)row * 64 + j;
  const size_t S = (size_t)BB * NN * 64;
  float val = x[o] + b2[j] + ((part[o] + part[o + S]) + (part[o + 2 * S] + part[o + 3 * S]));
  float s = val;
  for (int off = 32; off; off >>= 1) s += __shfl_xor(s, off);
  s *= (1.f / 64.f);
  float d = val - s;
  float v = d * d;
  for (int off = 32; off; off >>= 1) v += __shfl_xor(v, off);
  v *= (1.f / 64.f);
  x[o] = d * rsqrtf(v + EPSF) * g[j] + be[j];
}

// ------- score head tiled: 64 rows/block; 64->64 GEMM then 16 then 1 ----------
__global__ void k_fg2(const float* __restrict__ x,
                      const float* __restrict__ w0, const float* __restrict__ b0, const float* __restrict__ bn0,
                      const float* __restrict__ w1, const float* __restrict__ b1, const float* __restrict__ bn1,
                      const float* __restrict__ w2, const float* __restrict__ b2, const float* __restrict__ bn2,
                      float* __restrict__ scores) {
  __shared__ float xs[64 * 68];
  __shared__ float ws[64 * 68];
  __shared__ float s0s[64 * 68];
  __shared__ float s1s[64 * 20];
  int row0 = blockIdx.x * 64;
  int t = threadIdx.x;
  #pragma unroll
  for (int i = 0; i < 4; ++i) {
    int q = t + i * 256, r = q >> 4, c = (q & 15) * 4;
    *(float4*)(xs + r * 68 + c) = *(const float4*)(x + (size_t)(row0 + r) * 64 + c);
    *(float4*)(ws + r * 68 + c) = *(const float4*)(w0 + r * 64 + c);
  }
  __syncthreads();
  int tx = t & 15, ty = t >> 4;
  float acc[4][4] = {};
  for (int f = 0; f < 64; f += 4) {
    float4 xv[4], wv[4];
    #pragma unroll
    for (int ri = 0; ri < 4; ++ri) xv[ri] = *(const float4*)(xs + (ty * 4 + ri) * 68 + f);
    #pragma unroll
    for (int ci = 0; ci < 4; ++ci) wv[ci] = *(const float4*)(ws + (tx + 16 * ci) * 68 + f);
    #pragma unroll
    for (int ri = 0; ri < 4; ++ri)
      #pragma unroll
      for (int ci = 0; ci < 4; ++ci)
        acc[ri][ci] += xv[ri].x * wv[ci].x + xv[ri].y * wv[ci].y +
                       xv[ri].z * wv[ci].z + xv[ri].w * wv[ci].w;
  }
  #pragma unroll
  for (int ri = 0; ri < 4; ++ri)
    #pragma unroll
    for (int ci = 0; ci < 4; ++ci) {
      int c = tx + 16 * ci;
      float sc = bn0[c] * rsqrtf(bn0[192 + c] + EPSF);
      float v = (acc[ri][ci] + b0[c] - bn0[128 + c]) * sc + bn0[64 + c];
      s0s[(ty * 4 + ri) * 68 + c] = fmaxf(v, 0.f);
    }
  __syncthreads();
  {
    int rl = t & 63, j0 = t >> 6;
    #pragma unroll
    for (int i = 0; i < 4; ++i) {
      int j = j0 + 4 * i;
      float s = b1[j];
      const float* wr = w1 + j * 64;
      #pragma unroll 16
      for (int c = 0; c < 64; ++c) s += s0s[rl * 68 + c] * wr[c];
      float sc = bn1[j] * rsqrtf(bn1[48 + j] + EPSF);
      s = (s - bn1[32 + j]) * sc + bn1[16 + j];
      s1s[rl * 20 + j] = fmaxf(s, 0.f);
    }
  }
  __syncthreads();
  if (t < 64) {
    float s = b2[0];
    #pragma unroll
    for (int o = 0; o < 16; ++o) s += s1s[t * 20 + o] * w2[o];
    float sc = bn2[0] * rsqrtf(bn2[3] + EPSF);
    s = (s - bn2[2]) * sc + bn2[1];
    scores[row0 + t] = fmaxf(s, 0.f);
  }
}

// ---- top-k (k=16): register-resident vals, wave shuffle reduce, tie->lowest --
__global__ void k_topk2(const float* __restrict__ scores, int* __restrict__ idx,
                        float* __restrict__ out_idx) {
  int b = blockIdx.x, t = threadIdx.x;
  float v[8];
  int base = b * NN;
  #pragma unroll
  for (int u = 0; u < 8; ++u) v[u] = scores[base + t + 256 * u];
  __shared__ float wvs[4];
  __shared__ int wis[4];
  __shared__ int winner;
  unsigned taken = 0;
  for (int r = 0; r < TOPK; ++r) {
    float best = -1e30f; int bi = 1 << 30;
    #pragma unroll
    for (int u = 0; u < 8; ++u) {
      if (!((taken >> u) & 1)) {
        float vv = v[u]; int ii = t + 256 * u;
        if (vv > best || (vv == best && ii < bi)) { best = vv; bi = ii; }
      }
    }
    for (int off = 32; off; off >>= 1) {
      float ov = __shfl_xor(best, off);
      int oi = __shfl_xor(bi, off);
      if (ov > best || (ov == best && oi < bi)) { best = ov; bi = oi; }
    }
    if ((t & 63) == 0) { wvs[t >> 6] = best; wis[t >> 6] = bi; }
    __syncthreads();
    if (t == 0) {
      float B = wvs[0]; int I = wis[0];
      #pragma unroll
      for (int q = 1; q < 4; ++q)
        if (wvs[q] > B || (wvs[q] == B && wis[q] < I)) { B = wvs[q]; I = wis[q]; }
      winner = I;
      idx[b * TOPK + r] = I;
      out_idx[b * TOPK + r] = (float)I;
    }
    __syncthreads();
    int w = winner;
    if ((w & 255) == t) taken |= 1u << (w >> 8);
  }
}

// ---------------- ball query + 3 conv stages, block = 64 per (b,k) ----------------
__global__ void k_group(const float* __restrict__ inp, const int* __restrict__ idx,
                        const float* __restrict__ w0, const float* __restrict__ b0, const float* __restrict__ bn0,
                        const float* __restrict__ w1, const float* __restrict__ b1, const float* __restrict__ bn1,
                        const float* __restrict__ w2, const float* __restrict__ b2, const float* __restrict__ bn2,
                        float* __restrict__ r2g) {
  __shared__ int gidx[NSAMP];
  __shared__ float gsh[65 * DD];
  __shared__ float r0[128];
  __shared__ float r1[256];
  int k = blockIdx.x, b = blockIdx.y;
  int lane = threadIdx.x;  // 64
  int qn = idx[b * TOPK + k];
  const float* px = inp + (size_t)b * DD * NN;  // [d*N + n]
  float qx = px[qn], qy = px[NN + qn], qz = px[2 * NN + qn];
  int cnt = 0;
  for (int base = 0; base < NN && cnt < NSAMP; base += 64) {
    int n = base + lane;
    float dx = px[n] - qx, dy = px[NN + n] - qy, dz = px[2 * NN + n] - qz;
    float d2 = dx * dx + dy * dy + dz * dz;
    bool flag = (d2 <= R2);
    unsigned long long m = __ballot(flag);
    int pos = cnt + __popcll(m & ((1ull << lane) - 1ull));
    if (flag && pos < NSAMP) gidx[pos] = n;
    cnt += (int)__popcll(m);
  }
  __syncthreads();
  int total = cnt < NSAMP ? cnt : NSAMP;
  if (lane >= total) gidx[lane] = gidx[0];
  __syncthreads();
  for (int i = lane; i < 65 * DD; i += 64) {
    int p = i / DD, d = i - p * DD;
    int n = (p == 0) ? qn : gidx[p - 1];
    gsh[i] = px[d * NN + n];
  }
  __syncthreads();
  for (int c = lane; c < 128; c += 64) {
    float s = b0[c];
    const float* w = w0 + c * 390;
    for (int i = 0; i < 390; ++i) s += gsh[i] * w[i];
    float sc = bn0[c] * rsqrtf(bn0[384 + c] + EPSF);
    s = (s - bn0[256 + c]) * sc + bn0[128 + c];
    r0[c] = fmaxf(s, 0.f);
  }
  __syncthreads();
  for (int c = lane; c < 256; c += 64) {
    float s = b1[c];
    const float* w = w1 + c * 128;
    for (int o = 0; o < 128; ++o) s += r0[o] * w[o];
    float sc = bn1[c] * rsqrtf(bn1[768 + c] + EPSF);
    s = (s - bn1[512 + c]) * sc + bn1[256 + c];
    r1[c] = fmaxf(s, 0.f);
  }
  __syncthreads();
  for (int c = lane; c < 512; c += 64) {
    float s = b2[c];
    const float* w = w2 + c * 256;
    for (int o = 0; o < 256; ++o) s += r1[o] * w[o];
    float sc = bn2[c] * rsqrtf(bn2[1536 + c] + EPSF);
    s = (s - bn2[1024 + c]) * sc + bn2[512 + c];
    r2g[b * 8192 + c * TOPK + k] = fmaxf(s, 0.f);
  }
}

// ---------------- FC + BN + ReLU (wave-reduced dot), block=64 ----------------
__global__ void k_fl(const float* __restrict__ hin, const float* __restrict__ w,
                     const float* __restrict__ bias, const float* __restrict__ bn,
                     float* __restrict__ hout, int IN, int OUT) {
  int blk = blockIdx.x;
  int b = blk / OUT, j = blk % OUT;
  int lane = threadIdx.x;
  const float* hr = hin + (size_t)b * IN;
  const float* wr = w + (size_t)j * IN;
  float s = 0.f;
  for (int i = lane; i < IN; i += 64) s += hr[i] * wr[i];
  for (int o = 32; o; o >>= 1) s += __shfl_xor(s, o);
  if (lane == 0) {
    s += bias[j];
    float sc = bn[j] * rsqrtf(bn[3 * OUT + j] + EPSF);
    s = (s - bn[2 * OUT + j]) * sc + bn[OUT + j];
    hout[b * OUT + j] = fmaxf(s, 0.f);
  }
}

extern "C" void kernel_launch(void* const* d_in, const int* in_sizes, int n_in,
                              void* d_out, int out_size, void* d_ws, size_t ws_size,
                              hipStream_t stream) {
  const float* sv      = (const float*)d_in[0];
  const float* inp     = (const float*)d_in[1];
  const float* tl_win  = (const float*)d_in[2];
  const float* tl_bin  = (const float*)d_in[3];
  const float* tl_wout = (const float*)d_in[4];
  const float* tl_bout = (const float*)d_in[5];
  const float* tl_w1   = (const float*)d_in[6];
  const float* tl_b1   = (const float*)d_in[7];
  const float* tl_w2   = (const float*)d_in[8];
  const float* tl_b2   = (const float*)d_in[9];
  const float* tl_ln1g = (const float*)d_in[10];
  const float* tl_ln1b = (const float*)d_in[11];
  const float* tl_ln2g = (const float*)d_in[12];
  const float* tl_ln2b = (const float*)d_in[13];
  const float* fg_w0   = (const float*)d_in[14];
  const float* fg_b0   = (const float*)d_in[15];
  const float* fg_w1   = (const float*)d_in[16];
  const float* fg_b1   = (const float*)d_in[17];
  const float* fg_w2   = (const float*)d_in[18];
  const float* fg_b2   = (const float*)d_in[19];
  const float* fbn0    = (const float*)d_in[20];
  const float* fbn1    = (const float*)d_in[21];
  const float* fbn2    = (const float*)d_in[22];
  const float* rc_w0   = (const float*)d_in[23];
  const float* rc_b0   = (const float*)d_in[24];
  const float* rc_w1   = (const float*)d_in[25];
  const float* rc_b1   = (const float*)d_in[26];
  const float* rc_w2   = (const float*)d_in[27];
  const float* rc_b2   = (const float*)d_in[28];
  const float* rbn0    = (const float*)d_in[29];
  const float* rbn1    = (const float*)d_in[30];
  const float* rbn2    = (const float*)d_in[31];
  const float* fl_w0   = (const float*)d_in[32];
  const float* fl_b0   = (const float*)d_in[33];
  const float* fl_w1   = (const float*)d_in[34];
  const float* fl_b1   = (const float*)d_in[35];
  const float* lbn0    = (const float*)d_in[36];
  const float* lbn1    = (const float*)d_in[37];
  (void)in_sizes; (void)n_in; (void)out_size; (void)ws_size;

  float* ws = (float*)d_ws;
  float* x      = ws;                         // B*N*F      = 1048576
  float* qkv    = x + BB * NN * FF;           // B*N*192    = 3145728
  float* a      = qkv + BB * NN * 192;        // B*N*F      = 1048576
  float* scores = a + BB * NN * FF;           // B*N        = 16384
  int*   idxb   = (int*)(scores + BB * NN);   // B*TOPK     = 128
  float* r2g    = (float*)(idxb + BB * TOPK); // B*8192     = 65536
  float* h1g    = r2g + BB * 8192;            // B*1024     = 8192
  // FFN split-K partials reuse qkv+a (exactly 4*16384*64 floats, dead then)
  float* part   = qkv;

  float* out = (float*)d_out;  // fp32: h at [0,4096), idx-as-float at [4096,4224)

  k_transpose<<<(BB * NN * FF) / 256, 256, 0, stream>>>(sv, x);

  for (int l = 0; l < NLAYER; ++l) {
    k_qkv2<<<dim3(BB * NN / 64, 3), 256, 0, stream>>>(x, tl_win + l * 192 * FF,
                                                      tl_bin + l * 192, qkv);
    k_attn3<<<dim3(NN / 256, NHEAD, BB), 1024, 0, stream>>>(qkv, a);
    k_proj2<<<BB * NN / 64, 256, 0, stream>>>(a, tl_wout + l * FF * FF, tl_bout + l * FF,
                                              tl_ln1g + l * FF, tl_ln1b + l * FF, x);
    k_ffn3<<<dim3(BB * NN / 64, 4), 256, 0, stream>>>(x, tl_w1 + l * 2048 * FF,
                                                      tl_b1 + l * 2048,
                                                      tl_w2 + l * FF * 2048, part);
    k_ffn_ln<<<BB * NN / 4, 256, 0, stream>>>(part, tl_b2 + l * FF,
                                              tl_ln2g + l * FF, tl_ln2b + l * FF, x);
  }

  k_fg2<<<BB * NN / 64, 256, 0, stream>>>(x, fg_w0, fg_b0, fbn0, fg_w1, fg_b1, fbn1,
                                          fg_w2, fg_b2, fbn2, scores);
  k_topk2<<<BB, 256, 0, stream>>>(scores, idxb, out + BB * 512);
  k_group<<<dim3(TOPK, BB), 64, 0, stream>>>(inp, idxb, rc_w0, rc_b0, rbn0,
                                             rc_w1, rc_b1, rbn1, rc_w2, rc_b2, rbn2, r2g);
  k_fl<<<BB * 1024, 64, 0, stream>>>(r2g, fl_w0, fl_b0, lbn0, h1g, 8192, 1024);
  k_fl<<<BB * 512, 64, 0, stream>>>(h1g, fl_w1, fl_b1, lbn1, out, 1024, 512);
}

// Round 6
// 945.214 us; speedup vs baseline: 5.1539x; 1.1086x over previous
//
#include <hip/hip_runtime.h>
#include <hip/hip_bf16.h>
#include <math.h>

#define BB 8
#define NN 2048
#define FF 64
#define DD 6
#define NSAMP 64
#define TOPK 16
#define NHEAD 8
#define HD 8
#define NLAYER 2
#define EPSF 1e-5f
#define R2 0.09f

typedef short short8 __attribute__((ext_vector_type(8)));
typedef float f32x4 __attribute__((ext_vector_type(4)));

// split-pack: u32 = (bf16_hi << 16) | bf16_lo, both RNE. x ≈ hi + lo, err ~2^-16 rel.
__device__ inline unsigned pk2(float x) {
  unsigned b = __float_as_uint(x);
  unsigned hi = (b + 0x7fffu + ((b >> 16) & 1u)) >> 16;
  float r = x - __uint_as_float(hi << 16);
  unsigned c = __float_as_uint(r);
  unsigned lo = (c + 0x7fffu + ((c >> 16) & 1u)) >> 16;
  return (hi << 16) | lo;
}

__device__ inline void unpk(const unsigned* p, short8& hi, short8& lo) {
  #pragma unroll
  for (int i = 0; i < 8; ++i) {
    hi[i] = (short)(p[i] >> 16);
    lo[i] = (short)(p[i] & 0xffffu);
  }
}

// ---------------- transpose sortvec (B,1,F,N) -> x (B,N,F) ----------------
__global__ void k_transpose(const float* __restrict__ sv, float* __restrict__ x) {
  int i = blockIdx.x * 256 + threadIdx.x;
  if (i >= BB * NN * FF) return;
  int f = i % FF;
  int n = (i / FF) % NN;
  int b = i / (FF * NN);
  x[i] = sv[(b * FF + f) * NN + n];
}

// ---------------- pack fp32 weights -> split-bf16 u32 ----------------
__global__ void k_wpack(const float* __restrict__ w, unsigned* __restrict__ o, int n) {
  int i = blockIdx.x * 256 + threadIdx.x;
  if (i < n) o[i] = pk2(w[i]);
}

// ---------------- tiled GEMM: qkv[row][192] = x[row][64] @ win^T + bin ----------
__global__ void k_qkv2(const float* __restrict__ x, const float* __restrict__ win,
                       const float* __restrict__ bin, float* __restrict__ qkv) {
  __shared__ float xs[64 * 68];
  __shared__ float ws[64 * 68];
  int row0 = blockIdx.x * 64, col0 = blockIdx.y * 64;
  int t = threadIdx.x;
  #pragma unroll
  for (int i = 0; i < 4; ++i) {
    int q = t + i * 256, r = q >> 4, c = (q & 15) * 4;
    *(float4*)(xs + r * 68 + c) = *(const float4*)(x + (size_t)(row0 + r) * 64 + c);
    *(float4*)(ws + r * 68 + c) = *(const float4*)(win + (size_t)(col0 + r) * 64 + c);
  }
  __syncthreads();
  int tx = t & 15, ty = t >> 4;
  float acc[4][4] = {};
  for (int f = 0; f < 64; f += 4) {
    float4 xv[4], wv[4];
    #pragma unroll
    for (int ri = 0; ri < 4; ++ri) xv[ri] = *(const float4*)(xs + (ty * 4 + ri) * 68 + f);
    #pragma unroll
    for (int ci = 0; ci < 4; ++ci) wv[ci] = *(const float4*)(ws + (tx + 16 * ci) * 68 + f);
    #pragma unroll
    for (int ri = 0; ri < 4; ++ri)
      #pragma unroll
      for (int ci = 0; ci < 4; ++ci)
        acc[ri][ci] += xv[ri].x * wv[ci].x + xv[ri].y * wv[ci].y +
                       xv[ri].z * wv[ci].z + xv[ri].w * wv[ci].w;
  }
  #pragma unroll
  for (int ri = 0; ri < 4; ++ri)
    #pragma unroll
    for (int ci = 0; ci < 4; ++ci) {
      int r = row0 + ty * 4 + ri, c = col0 + tx + 16 * ci;
      qkv[(size_t)r * 192 + c] = acc[ri][ci] + bin[c];
    }
}

// ---- attention v3: 1024-thread block, 4 key-splits resident ----
#define ACHK 128
__global__ void __launch_bounds__(1024, 8)
k_attn3(const float* __restrict__ qkv, float* __restrict__ a) {
  __shared__ float kv[4 * ACHK * 16];
  __shared__ float cbuf[2 * 256 * 9];
  int t = threadIdx.x;
  int ksp = t >> 8, lt = t & 255;
  int n = blockIdx.x * 256 + lt;
  int h = blockIdx.y, b = blockIdx.z;
  const float* qrow = qkv + ((size_t)(b * NN + n)) * 192 + h * HD;
  float4 q0 = *(const float4*)(qrow);
  float4 q1 = *(const float4*)(qrow + 4);
  // pre-fold softmax scale * log2(e) into q; use exp2 (v_exp_f32 is base-2)
  const float kf = 0.35355339059327373f * 1.4426950408889634f;
  q0.x *= kf; q0.y *= kf; q0.z *= kf; q0.w *= kf;
  q1.x *= kf; q1.y *= kf; q1.z *= kf; q1.w *= kf;
  float l = 0.f;
  float4 a0 = {0, 0, 0, 0}, a1 = {0, 0, 0, 0};
  const float* my_kv = kv + ksp * (ACHK * 16);
  for (int c = 0; c < 512 / ACHK; ++c) {
    #pragma unroll
    for (int u = 0; u < 8; ++u) {
      int i = t + u * 1024;
      int g = i >> 11, j = i & 2047;
      int m = j >> 4, d = j & 15;
      int key = g * 512 + c * ACHK + m;
      size_t off = ((size_t)(b * NN + key)) * 192;
      kv[i] = (d < 8) ? qkv[off + 64 + h * HD + d] : qkv[off + 128 + h * HD + (d - 8)];
    }
    __syncthreads();
    #pragma unroll 2
    for (int m = 0; m < ACHK; ++m) {
      const float4 k0 = *(const float4*)(my_kv + m * 16);
      const float4 k1 = *(const float4*)(my_kv + m * 16 + 4);
      float s = q0.x * k0.x + q0.y * k0.y + q0.z * k0.z + q0.w * k0.w +
                q1.x * k1.x + q1.y * k1.y + q1.z * k1.z + q1.w * k1.w;
      float p = exp2f(s);
      l += p;
      const float4 v0 = *(const float4*)(my_kv + m * 16 + 8);
      const float4 v1 = *(const float4*)(my_kv + m * 16 + 12);
      a0.x += p * v0.x; a0.y += p * v0.y; a0.z += p * v0.z; a0.w += p * v0.w;
      a1.x += p * v1.x; a1.y += p * v1.y; a1.z += p * v1.z; a1.w += p * v1.w;
    }
    __syncthreads();
  }
  if (ksp >= 2) {
    float* cb = cbuf + (ksp - 2) * (256 * 9) + lt * 9;
    cb[0] = l;
    cb[1] = a0.x; cb[2] = a0.y; cb[3] = a0.z; cb[4] = a0.w;
    cb[5] = a1.x; cb[6] = a1.y; cb[7] = a1.z; cb[8] = a1.w;
  }
  __syncthreads();
  if (ksp < 2) {
    const float* cb = cbuf + ksp * (256 * 9) + lt * 9;
    l += cb[0];
    a0.x += cb[1]; a0.y += cb[2]; a0.z += cb[3]; a0.w += cb[4];
    a1.x += cb[5]; a1.y += cb[6]; a1.z += cb[7]; a1.w += cb[8];
  }
  __syncthreads();
  if (ksp == 1) {
    float* cb = cbuf + lt * 9;
    cb[0] = l;
    cb[1] = a0.x; cb[2] = a0.y; cb[3] = a0.z; cb[4] = a0.w;
    cb[5] = a1.x; cb[6] = a1.y; cb[7] = a1.z; cb[8] = a1.w;
  }
  __syncthreads();
  if (ksp == 0) {
    const float* cb = cbuf + lt * 9;
    l += cb[0];
    a0.x += cb[1]; a0.y += cb[2]; a0.z += cb[3]; a0.w += cb[4];
    a1.x += cb[5]; a1.y += cb[6]; a1.z += cb[7]; a1.w += cb[8];
    float inv = 1.f / l;
    float* out = a + ((size_t)(b * NN + n)) * FF + h * HD;
    float4 o0 = {a0.x * inv, a0.y * inv, a0.z * inv, a0.w * inv};
    float4 o1 = {a1.x * inv, a1.y * inv, a1.z * inv, a1.w * inv};
    *(float4*)(out) = o0;
    *(float4*)(out + 4) = o1;
  }
}

// ------- proj + residual + LN, tiled GEMM ---------
__global__ void k_proj2(const float* __restrict__ a, const float* __restrict__ wout,
                        const float* __restrict__ bout, const float* __restrict__ g,
                        const float* __restrict__ be, float* __restrict__ x) {
  __shared__ float xs[64 * 68];
  __shared__ float ws[64 * 68];
  int row0 = blockIdx.x * 64;
  int t = threadIdx.x;
  #pragma unroll
  for (int i = 0; i < 4; ++i) {
    int q = t + i * 256, r = q >> 4, c = (q & 15) * 4;
    *(float4*)(xs + r * 68 + c) = *(const float4*)(a + (size_t)(row0 + r) * 64 + c);
    *(float4*)(ws + r * 68 + c) = *(const float4*)(wout + r * 64 + c);
  }
  __syncthreads();
  int tx = t & 15, ty = t >> 4;
  float acc[4][4] = {};
  for (int f = 0; f < 64; f += 4) {
    float4 xv[4], wv[4];
    #pragma unroll
    for (int ri = 0; ri < 4; ++ri) xv[ri] = *(const float4*)(xs + (ty * 4 + ri) * 68 + f);
    #pragma unroll
    for (int ci = 0; ci < 4; ++ci) wv[ci] = *(const float4*)(ws + (tx + 16 * ci) * 68 + f);
    #pragma unroll
    for (int ri = 0; ri < 4; ++ri)
      #pragma unroll
      for (int ci = 0; ci < 4; ++ci)
        acc[ri][ci] += xv[ri].x * wv[ci].x + xv[ri].y * wv[ci].y +
                       xv[ri].z * wv[ci].z + xv[ri].w * wv[ci].w;
  }
  #pragma unroll
  for (int ri = 0; ri < 4; ++ri) {
    int rl = ty * 4 + ri;
    float val[4], s = 0.f, sq = 0.f;
    #pragma unroll
    for (int ci = 0; ci < 4; ++ci) {
      int c = tx + 16 * ci;
      val[ci] = x[(size_t)(row0 + rl) * 64 + c] + bout[c] + acc[ri][ci];
      s += val[ci]; sq += val[ci] * val[ci];
    }
    #pragma unroll
    for (int off = 1; off < 16; off <<= 1) { s += __shfl_xor(s, off); sq += __shfl_xor(sq, off); }
    float mean = s * (1.f / 64.f);
    float var = sq * (1.f / 64.f) - mean * mean;
    float rstd = rsqrtf(var + EPSF);
    #pragma unroll
    for (int ci = 0; ci < 4; ++ci) {
      int c = tx + 16 * ci;
      x[(size_t)(row0 + rl) * 64 + c] = (val[ci] - mean) * rstd * g[c] + be[c];
    }
  }
}

// ------- FFN v4: MFMA split-bf16 (hi*hi + hi*lo + lo*hi), split-K grid (256,4) ----
// 256 threads = 4 waves; wave w owns rows [w*16, w*16+16) of the 64-row tile.
// A-frag: A[m=lane&15][k=quad*8+j]; B-frag: B[k=quad*8+j][n=lane&15] from
// n-major packed arrays; C/D: col=lane&15, row=quad*4+reg.
__global__ void __launch_bounds__(256, 4)
k_ffn4(const float* __restrict__ x, const unsigned* __restrict__ w1p,
       const float* __restrict__ b1, const unsigned* __restrict__ w2p,
       float* __restrict__ part) {
  __shared__ unsigned xs[64 * 68];
  __shared__ unsigned ws[64 * 68];
  __shared__ unsigned hs[64 * 68];
  __shared__ float b1s[64];
  int row0 = blockIdx.x * 64;
  int ks = blockIdx.y;
  int t = threadIdx.x;
  int lane = t & 63, wv = t >> 6;
  int lm = lane & 15, lq = lane >> 4;
  // pack x tile -> split-bf16 u32
  #pragma unroll
  for (int i = 0; i < 4; ++i) {
    int q = t + i * 256, r = q >> 4, c = (q & 15) * 4;
    float4 v = *(const float4*)(x + (size_t)(row0 + r) * 64 + c);
    xs[r * 68 + c]     = pk2(v.x);
    xs[r * 68 + c + 1] = pk2(v.y);
    xs[r * 68 + c + 2] = pk2(v.z);
    xs[r * 68 + c + 3] = pk2(v.w);
  }
  f32x4 acc[4];
  #pragma unroll
  for (int tn = 0; tn < 4; ++tn) acc[tn] = (f32x4){0.f, 0.f, 0.f, 0.f};

  for (int ch = 0; ch < 8; ++ch) {
    int kc = (ks * 8 + ch) * 64;
    // stage w1 chunk (packed) + b1 into regs
    uint4 rw[4];
    #pragma unroll
    for (int i = 0; i < 4; ++i) {
      int q = t + i * 256, r = q >> 4, c = (q & 15) * 4;
      rw[i] = *(const uint4*)(w1p + (size_t)(kc + r) * 64 + c);
    }
    float rbv = 0.f;
    if (t < 64) rbv = b1[kc + t];
    __syncthreads();  // (A) prev phase2 done reading ws/hs
    #pragma unroll
    for (int i = 0; i < 4; ++i) {
      int q = t + i * 256, r = q >> 4, c = (q & 15) * 4;
      *(uint4*)(ws + r * 68 + c) = rw[i];
    }
    if (t < 64) b1s[t] = rbv;
    __syncthreads();  // (B) w1 chunk ready
    // phase 1: h[strip rows][64 hid] via MFMA
    f32x4 h4[4];
    #pragma unroll
    for (int tn = 0; tn < 4; ++tn) h4[tn] = (f32x4){0.f, 0.f, 0.f, 0.f};
    #pragma unroll
    for (int kb = 0; kb < 64; kb += 32) {
      unsigned ap[8];
      const unsigned* abase = xs + (wv * 16 + lm) * 68 + kb + lq * 8;
      *(uint4*)(ap)     = *(const uint4*)(abase);
      *(uint4*)(ap + 4) = *(const uint4*)(abase + 4);
      short8 ahi, alo; unpk(ap, ahi, alo);
      #pragma unroll
      for (int tn = 0; tn < 4; ++tn) {
        unsigned bp[8];
        const unsigned* bbase = ws + (tn * 16 + lm) * 68 + kb + lq * 8;
        *(uint4*)(bp)     = *(const uint4*)(bbase);
        *(uint4*)(bp + 4) = *(const uint4*)(bbase + 4);
        short8 bhi, blo; unpk(bp, bhi, blo);
        h4[tn] = __builtin_amdgcn_mfma_f32_16x16x32_bf16(ahi, bhi, h4[tn], 0, 0, 0);
        h4[tn] = __builtin_amdgcn_mfma_f32_16x16x32_bf16(ahi, blo, h4[tn], 0, 0, 0);
        h4[tn] = __builtin_amdgcn_mfma_f32_16x16x32_bf16(alo, bhi, h4[tn], 0, 0, 0);
      }
    }
    // h epilogue: bias + relu + split-pack into hs (intra-wave strip)
    #pragma unroll
    for (int tn = 0; tn < 4; ++tn)
      #pragma unroll
      for (int r = 0; r < 4; ++r) {
        float hv = fmaxf(h4[tn][r] + b1s[tn * 16 + lm], 0.f);
        hs[(wv * 16 + lq * 4 + r) * 68 + tn * 16 + lm] = pk2(hv);
      }
    // stage w2 chunk (packed)
    #pragma unroll
    for (int i = 0; i < 4; ++i) {
      int q = t + i * 256, j = q >> 4, c = (q & 15) * 4;
      rw[i] = *(const uint4*)(w2p + (size_t)j * 2048 + kc + c);
    }
    __syncthreads();  // (C) phase1 done reading ws; hs written
    #pragma unroll
    for (int i = 0; i < 4; ++i) {
      int q = t + i * 256, j = q >> 4, c = (q & 15) * 4;
      *(uint4*)(ws + j * 68 + c) = rw[i];
    }
    __syncthreads();  // (D) w2 chunk ready
    // phase 2: acc += h @ w2^T via MFMA
    #pragma unroll
    for (int kb = 0; kb < 64; kb += 32) {
      unsigned ap[8];
      const unsigned* abase = hs + (wv * 16 + lm) * 68 + kb + lq * 8;
      *(uint4*)(ap)     = *(const uint4*)(abase);
      *(uint4*)(ap + 4) = *(const uint4*)(abase + 4);
      short8 ahi, alo; unpk(ap, ahi, alo);
      #pragma unroll
      for (int tn = 0; tn < 4; ++tn) {
        unsigned bp[8];
        const unsigned* bbase = ws + (tn * 16 + lm) * 68 + kb + lq * 8;
        *(uint4*)(bp)     = *(const uint4*)(bbase);
        *(uint4*)(bp + 4) = *(const uint4*)(bbase + 4);
        short8 bhi, blo; unpk(bp, bhi, blo);
        acc[tn] = __builtin_amdgcn_mfma_f32_16x16x32_bf16(ahi, bhi, acc[tn], 0, 0, 0);
        acc[tn] = __builtin_amdgcn_mfma_f32_16x16x32_bf16(ahi, blo, acc[tn], 0, 0, 0);
        acc[tn] = __builtin_amdgcn_mfma_f32_16x16x32_bf16(alo, bhi, acc[tn], 0, 0, 0);
      }
    }
  }
  float* pb = part + (size_t)ks * (BB * NN * 64);
  #pragma unroll
  for (int tn = 0; tn < 4; ++tn)
    #pragma unroll
    for (int r = 0; r < 4; ++r)
      pb[(size_t)(row0 + wv * 16 + lq * 4 + r) * 64 + tn * 16 + lm] = acc[tn][r];
}

// ------- combine 4 partials + residual + b2 + LN; one wave per row ---------
__global__ void k_ffn_ln(const float* __restrict__ part, const float* __restrict__ b2,
                         const float* __restrict__ g, const float* __restrict__ be,
                         float* __restrict__ x) {
  int row = blockIdx.x * 4 + (threadIdx.x >> 6);
  int j = threadIdx.x & 63;
  size_t o = (size_t)row * 64 + j;
  const size_t S = (size_t)BB * NN * 64;
  float val = x[o] + b2[j] + ((part[o] + part[o + S]) + (part[o + 2 * S] + part[o + 3 * S]));
  float s = val;
  for (int off = 32; off; off >>= 1) s += __shfl_xor(s, off);
  s *= (1.f / 64.f);
  float d = val - s;
  float v = d * d;
  for (int off = 32; off; off >>= 1) v += __shfl_xor(v, off);
  v *= (1.f / 64.f);
  x[o] = d * rsqrtf(v + EPSF) * g[j] + be[j];
}

// ------- score head tiled ----------
__global__ void k_fg2(const float* __restrict__ x,
                      const float* __restrict__ w0, const float* __restrict__ b0, const float* __restrict__ bn0,
                      const float* __restrict__ w1, const float* __restrict__ b1, const float* __restrict__ bn1,
                      const float* __restrict__ w2, const float* __restrict__ b2, const float* __restrict__ bn2,
                      float* __restrict__ scores) {
  __shared__ float xs[64 * 68];
  __shared__ float ws[64 * 68];
  __shared__ float s0s[64 * 68];
  __shared__ float s1s[64 * 20];
  int row0 = blockIdx.x * 64;
  int t = threadIdx.x;
  #pragma unroll
  for (int i = 0; i < 4; ++i) {
    int q = t + i * 256, r = q >> 4, c = (q & 15) * 4;
    *(float4*)(xs + r * 68 + c) = *(const float4*)(x + (size_t)(row0 + r) * 64 + c);
    *(float4*)(ws + r * 68 + c) = *(const float4*)(w0 + r * 64 + c);
  }
  __syncthreads();
  int tx = t & 15, ty = t >> 4;
  float acc[4][4] = {};
  for (int f = 0; f < 64; f += 4) {
    float4 xv[4], wv[4];
    #pragma unroll
    for (int ri = 0; ri < 4; ++ri) xv[ri] = *(const float4*)(xs + (ty * 4 + ri) * 68 + f);
    #pragma unroll
    for (int ci = 0; ci < 4; ++ci) wv[ci] = *(const float4*)(ws + (tx + 16 * ci) * 68 + f);
    #pragma unroll
    for (int ri = 0; ri < 4; ++ri)
      #pragma unroll
      for (int ci = 0; ci < 4; ++ci)
        acc[ri][ci] += xv[ri].x * wv[ci].x + xv[ri].y * wv[ci].y +
                       xv[ri].z * wv[ci].z + xv[ri].w * wv[ci].w;
  }
  #pragma unroll
  for (int ri = 0; ri < 4; ++ri)
    #pragma unroll
    for (int ci = 0; ci < 4; ++ci) {
      int c = tx + 16 * ci;
      float sc = bn0[c] * rsqrtf(bn0[192 + c] + EPSF);
      float v = (acc[ri][ci] + b0[c] - bn0[128 + c]) * sc + bn0[64 + c];
      s0s[(ty * 4 + ri) * 68 + c] = fmaxf(v, 0.f);
    }
  __syncthreads();
  {
    int rl = t & 63, j0 = t >> 6;
    #pragma unroll
    for (int i = 0; i < 4; ++i) {
      int j = j0 + 4 * i;
      float s = b1[j];
      const float* wr = w1 + j * 64;
      #pragma unroll 16
      for (int c = 0; c < 64; ++c) s += s0s[rl * 68 + c] * wr[c];
      float sc = bn1[j] * rsqrtf(bn1[48 + j] + EPSF);
      s = (s - bn1[32 + j]) * sc + bn1[16 + j];
      s1s[rl * 20 + j] = fmaxf(s, 0.f);
    }
  }
  __syncthreads();
  if (t < 64) {
    float s = b2[0];
    #pragma unroll
    for (int o = 0; o < 16; ++o) s += s1s[t * 20 + o] * w2[o];
    float sc = bn2[0] * rsqrtf(bn2[3] + EPSF);
    s = (s - bn2[2]) * sc + bn2[1];
    scores[row0 + t] = fmaxf(s, 0.f);
  }
}

// ---- top-k (k=16) ----
__global__ void k_topk2(const float* __restrict__ scores, int* __restrict__ idx,
                        float* __restrict__ out_idx) {
  int b = blockIdx.x, t = threadIdx.x;
  float v[8];
  int base = b * NN;
  #pragma unroll
  for (int u = 0; u < 8; ++u) v[u] = scores[base + t + 256 * u];
  __shared__ float wvs[4];
  __shared__ int wis[4];
  __shared__ int winner;
  unsigned taken = 0;
  for (int r = 0; r < TOPK; ++r) {
    float best = -1e30f; int bi = 1 << 30;
    #pragma unroll
    for (int u = 0; u < 8; ++u) {
      if (!((taken >> u) & 1)) {
        float vv = v[u]; int ii = t + 256 * u;
        if (vv > best || (vv == best && ii < bi)) { best = vv; bi = ii; }
      }
    }
    for (int off = 32; off; off >>= 1) {
      float ov = __shfl_xor(best, off);
      int oi = __shfl_xor(bi, off);
      if (ov > best || (ov == best && oi < bi)) { best = ov; bi = oi; }
    }
    if ((t & 63) == 0) { wvs[t >> 6] = best; wis[t >> 6] = bi; }
    __syncthreads();
    if (t == 0) {
      float B = wvs[0]; int I = wis[0];
      #pragma unroll
      for (int q = 1; q < 4; ++q)
        if (wvs[q] > B || (wvs[q] == B && wis[q] < I)) { B = wvs[q]; I = wis[q]; }
      winner = I;
      idx[b * TOPK + r] = I;
      out_idx[b * TOPK + r] = (float)I;
    }
    __syncthreads();
    int w = winner;
    if ((w & 255) == t) taken |= 1u << (w >> 8);
  }
}

// ---------------- ball query + 3 conv stages, block = 64 per (b,k) ----------------
__global__ void k_group(const float* __restrict__ inp, const int* __restrict__ idx,
                        const float* __restrict__ w0, const float* __restrict__ b0, const float* __restrict__ bn0,
                        const float* __restrict__ w1, const float* __restrict__ b1, const float* __restrict__ bn1,
                        const float* __restrict__ w2, const float* __restrict__ b2, const float* __restrict__ bn2,
                        float* __restrict__ r2g) {
  __shared__ int gidx[NSAMP];
  __shared__ float gsh[65 * DD];
  __shared__ float r0[128];
  __shared__ float r1[256];
  int k = blockIdx.x, b = blockIdx.y;
  int lane = threadIdx.x;
  int qn = idx[b * TOPK + k];
  const float* px = inp + (size_t)b * DD * NN;
  float qx = px[qn], qy = px[NN + qn], qz = px[2 * NN + qn];
  int cnt = 0;
  for (int base = 0; base < NN && cnt < NSAMP; base += 64) {
    int n = base + lane;
    float dx = px[n] - qx, dy = px[NN + n] - qy, dz = px[2 * NN + n] - qz;
    float d2 = dx * dx + dy * dy + dz * dz;
    bool flag = (d2 <= R2);
    unsigned long long m = __ballot(flag);
    int pos = cnt + __popcll(m & ((1ull << lane) - 1ull));
    if (flag && pos < NSAMP) gidx[pos] = n;
    cnt += (int)__popcll(m);
  }
  __syncthreads();
  int total = cnt < NSAMP ? cnt : NSAMP;
  if (lane >= total) gidx[lane] = gidx[0];
  __syncthreads();
  for (int i = lane; i < 65 * DD; i += 64) {
    int p = i / DD, d = i - p * DD;
    int n = (p == 0) ? qn : gidx[p - 1];
    gsh[i] = px[d * NN + n];
  }
  __syncthreads();
  for (int c = lane; c < 128; c += 64) {
    float s = b0[c];
    const float* w = w0 + c * 390;
    for (int i = 0; i < 390; ++i) s += gsh[i] * w[i];
    float sc = bn0[c] * rsqrtf(bn0[384 + c] + EPSF);
    s = (s - bn0[256 + c]) * sc + bn0[128 + c];
    r0[c] = fmaxf(s, 0.f);
  }
  __syncthreads();
  for (int c = lane; c < 256; c += 64) {
    float s = b1[c];
    const float* w = w1 + c * 128;
    for (int o = 0; o < 128; ++o) s += r0[o] * w[o];
    float sc = bn1[c] * rsqrtf(bn1[768 + c] + EPSF);
    s = (s - bn1[512 + c]) * sc + bn1[256 + c];
    r1[c] = fmaxf(s, 0.f);
  }
  __syncthreads();
  for (int c = lane; c < 512; c += 64) {
    float s = b2[c];
    const float* w = w2 + c * 256;
    for (int o = 0; o < 256; ++o) s += r1[o] * w[o];
    float sc = bn2[c] * rsqrtf(bn2[1536 + c] + EPSF);
    s = (s - bn2[1024 + c]) * sc + bn2[512 + c];
    r2g[b * 8192 + c * TOPK + k] = fmaxf(s, 0.f);
  }
}

// ---------------- FC + BN + ReLU (wave-reduced dot), block=64 ----------------
__global__ void k_fl(const float* __restrict__ hin, const float* __restrict__ w,
                     const float* __restrict__ bias, const float* __restrict__ bn,
                     float* __restrict__ hout, int IN, int OUT) {
  int blk = blockIdx.x;
  int b = blk / OUT, j = blk % OUT;
  int lane = threadIdx.x;
  const float* hr = hin + (size_t)b * IN;
  const float* wr = w + (size_t)j * IN;
  float s = 0.f;
  for (int i = lane; i < IN; i += 64) s += hr[i] * wr[i];
  for (int o = 32; o; o >>= 1) s += __shfl_xor(s, o);
  if (lane == 0) {
    s += bias[j];
    float sc = bn[j] * rsqrtf(bn[3 * OUT + j] + EPSF);
    s = (s - bn[2 * OUT + j]) * sc + bn[OUT + j];
    hout[b * OUT + j] = fmaxf(s, 0.f);
  }
}

extern "C" void kernel_launch(void* const* d_in, const int* in_sizes, int n_in,
                              void* d_out, int out_size, void* d_ws, size_t ws_size,
                              hipStream_t stream) {
  const float* sv      = (const float*)d_in[0];
  const float* inp     = (const float*)d_in[1];
  const float* tl_win  = (const float*)d_in[2];
  const float* tl_bin  = (const float*)d_in[3];
  const float* tl_wout = (const float*)d_in[4];
  const float* tl_bout = (const float*)d_in[5];
  const float* tl_w1   = (const float*)d_in[6];
  const float* tl_b1   = (const float*)d_in[7];
  const float* tl_w2   = (const float*)d_in[8];
  const float* tl_b2   = (const float*)d_in[9];
  const float* tl_ln1g = (const float*)d_in[10];
  const float* tl_ln1b = (const float*)d_in[11];
  const float* tl_ln2g = (const float*)d_in[12];
  const float* tl_ln2b = (const float*)d_in[13];
  const float* fg_w0   = (const float*)d_in[14];
  const float* fg_b0   = (const float*)d_in[15];
  const float* fg_w1   = (const float*)d_in[16];
  const float* fg_b1   = (const float*)d_in[17];
  const float* fg_w2   = (const float*)d_in[18];
  const float* fg_b2   = (const float*)d_in[19];
  const float* fbn0    = (const float*)d_in[20];
  const float* fbn1    = (const float*)d_in[21];
  const float* fbn2    = (const float*)d_in[22];
  const float* rc_w0   = (const float*)d_in[23];
  const float* rc_b0   = (const float*)d_in[24];
  const float* rc_w1   = (const float*)d_in[25];
  const float* rc_b1   = (const float*)d_in[26];
  const float* rc_w2   = (const float*)d_in[27];
  const float* rc_b2   = (const float*)d_in[28];
  const float* rbn0    = (const float*)d_in[29];
  const float* rbn1    = (const float*)d_in[30];
  const float* rbn2    = (const float*)d_in[31];
  const float* fl_w0   = (const float*)d_in[32];
  const float* fl_b0   = (const float*)d_in[33];
  const float* fl_w1   = (const float*)d_in[34];
  const float* fl_b1   = (const float*)d_in[35];
  const float* lbn0    = (const float*)d_in[36];
  const float* lbn1    = (const float*)d_in[37];
  (void)in_sizes; (void)n_in; (void)out_size; (void)ws_size;

  float* wsp = (float*)d_ws;
  float* x      = wsp;                        // B*N*F      = 1048576
  float* qkv    = x + BB * NN * FF;           // B*N*192    = 3145728
  float* a      = qkv + BB * NN * 192;        // B*N*F      = 1048576
  float* scores = a + BB * NN * FF;           // B*N        = 16384
  int*   idxb   = (int*)(scores + BB * NN);   // B*TOPK     = 128
  float* r2g    = (float*)(idxb + BB * TOPK); // B*8192     = 65536
  float* h1g    = r2g + BB * 8192;            // B*1024     = 8192
  unsigned* wpk1 = (unsigned*)(h1g + BB * 1024);   // 2*2048*64 = 262144
  unsigned* wpk2 = wpk1 + NLAYER * 2048 * 64;      // 2*64*2048 = 262144
  float* part   = qkv;  // FFN split-K partials reuse qkv+a (4*16384*64 floats)

  float* out = (float*)d_out;  // fp32: h at [0,4096), idx-as-float at [4096,4224)

  k_transpose<<<(BB * NN * FF) / 256, 256, 0, stream>>>(sv, x);
  k_wpack<<<(NLAYER * 2048 * 64) / 256, 256, 0, stream>>>(tl_w1, wpk1, NLAYER * 2048 * 64);
  k_wpack<<<(NLAYER * 2048 * 64) / 256, 256, 0, stream>>>(tl_w2, wpk2, NLAYER * 2048 * 64);

  for (int l = 0; l < NLAYER; ++l) {
    k_qkv2<<<dim3(BB * NN / 64, 3), 256, 0, stream>>>(x, tl_win + l * 192 * FF,
                                                      tl_bin + l * 192, qkv);
    k_attn3<<<dim3(NN / 256, NHEAD, BB), 1024, 0, stream>>>(qkv, a);
    k_proj2<<<BB * NN / 64, 256, 0, stream>>>(a, tl_wout + l * FF * FF, tl_bout + l * FF,
                                              tl_ln1g + l * FF, tl_ln1b + l * FF, x);
    k_ffn4<<<dim3(BB * NN / 64, 4), 256, 0, stream>>>(x, wpk1 + l * 2048 * 64,
                                                      tl_b1 + l * 2048,
                                                      wpk2 + l * 2048 * 64, part);
    k_ffn_ln<<<BB * NN / 4, 256, 0, stream>>>(part, tl_b2 + l * FF,
                                              tl_ln2g + l * FF, tl_ln2b + l * FF, x);
  }

  k_fg2<<<BB * NN / 64, 256, 0, stream>>>(x, fg_w0, fg_b0, fbn0, fg_w1, fg_b1, fbn1,
                                          fg_w2, fg_b2, fbn2, scores);
  k_topk2<<<BB, 256, 0, stream>>>(scores, idxb, out + BB * 512);
  k_group<<<dim3(TOPK, BB), 64, 0, stream>>>(inp, idxb, rc_w0, rc_b0, rbn0,
                                             rc_w1, rc_b1, rbn1, rc_w2, rc_b2, rbn2, r2g);
  k_fl<<<BB * 1024, 64, 0, stream>>>(r2g, fl_w0, fl_b0, lbn0, h1g, 8192, 1024);
  k_fl<<<BB * 512, 64, 0, stream>>>(h1g, fl_w1, fl_b1, lbn1, out, 1024, 512);
}

// Round 7
// 877.182 us; speedup vs baseline: 5.5536x; 1.0776x over previous
//
#include <hip/hip_runtime.h>
#include <hip/hip_bf16.h>
#include <math.h>

#define BB 8
#define NN 2048
#define FF 64
#define DD 6
#define NSAMP 64
#define TOPK 16
#define NHEAD 8
#define HD 8
#define NLAYER 2
#define EPSF 1e-5f
#define R2 0.09f

typedef short short8 __attribute__((ext_vector_type(8)));
typedef float f32x4 __attribute__((ext_vector_type(4)));

// split-pack: u32 = (bf16_hi << 16) | bf16_lo, both RNE. x ≈ hi + lo, err ~2^-16 rel.
__device__ inline unsigned pk2(float x) {
  unsigned b = __float_as_uint(x);
  unsigned hi = (b + 0x7fffu + ((b >> 16) & 1u)) >> 16;
  float r = x - __uint_as_float(hi << 16);
  unsigned c = __float_as_uint(r);
  unsigned lo = (c + 0x7fffu + ((c >> 16) & 1u)) >> 16;
  return (hi << 16) | lo;
}

__device__ inline void unpk(const unsigned* p, short8& hi, short8& lo) {
  #pragma unroll
  for (int i = 0; i < 8; ++i) {
    hi[i] = (short)(p[i] >> 16);
    lo[i] = (short)(p[i] & 0xffffu);
  }
}

// ---------------- transpose sortvec (B,1,F,N) -> x (B,N,F) ----------------
__global__ void k_transpose(const float* __restrict__ sv, float* __restrict__ x) {
  int i = blockIdx.x * 256 + threadIdx.x;
  if (i >= BB * NN * FF) return;
  int f = i % FF;
  int n = (i / FF) % NN;
  int b = i / (FF * NN);
  x[i] = sv[(b * FF + f) * NN + n];
}

// ---------------- pack fp32 weights -> split-bf16 u32 ----------------
__global__ void k_wpack(const float* __restrict__ w, unsigned* __restrict__ o, int n) {
  int i = blockIdx.x * 256 + threadIdx.x;
  if (i < n) o[i] = pk2(w[i]);
}

// ---------------- tiled GEMM: qkv[row][192] = x[row][64] @ win^T + bin ----------
__global__ void k_qkv2(const float* __restrict__ x, const float* __restrict__ win,
                       const float* __restrict__ bin, float* __restrict__ qkv) {
  __shared__ float xs[64 * 68];
  __shared__ float ws[64 * 68];
  int row0 = blockIdx.x * 64, col0 = blockIdx.y * 64;
  int t = threadIdx.x;
  #pragma unroll
  for (int i = 0; i < 4; ++i) {
    int q = t + i * 256, r = q >> 4, c = (q & 15) * 4;
    *(float4*)(xs + r * 68 + c) = *(const float4*)(x + (size_t)(row0 + r) * 64 + c);
    *(float4*)(ws + r * 68 + c) = *(const float4*)(win + (size_t)(col0 + r) * 64 + c);
  }
  __syncthreads();
  int tx = t & 15, ty = t >> 4;
  float acc[4][4] = {};
  for (int f = 0; f < 64; f += 4) {
    float4 xv[4], wv[4];
    #pragma unroll
    for (int ri = 0; ri < 4; ++ri) xv[ri] = *(const float4*)(xs + (ty * 4 + ri) * 68 + f);
    #pragma unroll
    for (int ci = 0; ci < 4; ++ci) wv[ci] = *(const float4*)(ws + (tx + 16 * ci) * 68 + f);
    #pragma unroll
    for (int ri = 0; ri < 4; ++ri)
      #pragma unroll
      for (int ci = 0; ci < 4; ++ci)
        acc[ri][ci] += xv[ri].x * wv[ci].x + xv[ri].y * wv[ci].y +
                       xv[ri].z * wv[ci].z + xv[ri].w * wv[ci].w;
  }
  #pragma unroll
  for (int ri = 0; ri < 4; ++ri)
    #pragma unroll
    for (int ci = 0; ci < 4; ++ci) {
      int r = row0 + ty * 4 + ri, c = col0 + tx + 16 * ci;
      qkv[(size_t)r * 192 + c] = acc[ri][ci] + bin[c];
    }
}

// ---- attention v4: 512 threads, 4-query register blocking, 4 key-splits ----
// lt = t&127 owns queries {lt, lt+128, lt+256, lt+384} of the block's 512;
// ksp = t>>7 owns keys [ksp*512, ksp*512+512). Per staged key, 4 LDS broadcast
// reads + loop overhead amortize over 4 queries. Summation order per query is
// identical to v3 (128-key chunks, sequential; same combine tree).
#define ACHK 128
__global__ void __launch_bounds__(512, 2)
k_attn4(const float* __restrict__ qkv, float* __restrict__ a) {
  __shared__ float kv[4 * ACHK * 16];       // 32 KB
  __shared__ float cbuf[2 * 4 * 128 * 9];   // 36.9 KB, stride 9 (conflict-free)
  int t = threadIdx.x;
  int ksp = t >> 7, lt = t & 127;
  int h = blockIdx.y, b = blockIdx.z;
  int nbase = blockIdx.x * 512 + lt;
  const float kf = 0.35355339059327373f * 1.4426950408889634f;  // scale*log2e
  float4 q0[4], q1[4];
  #pragma unroll
  for (int j = 0; j < 4; ++j) {
    const float* qrow = qkv + ((size_t)(b * NN + nbase + 128 * j)) * 192 + h * HD;
    q0[j] = *(const float4*)(qrow);
    q1[j] = *(const float4*)(qrow + 4);
    q0[j].x *= kf; q0[j].y *= kf; q0[j].z *= kf; q0[j].w *= kf;
    q1[j].x *= kf; q1[j].y *= kf; q1[j].z *= kf; q1[j].w *= kf;
  }
  float l[4] = {0.f, 0.f, 0.f, 0.f};
  float4 a0[4], a1[4];
  #pragma unroll
  for (int j = 0; j < 4; ++j) {
    a0[j] = (float4){0, 0, 0, 0};
    a1[j] = (float4){0, 0, 0, 0};
  }
  const float* my_kv = kv + ksp * (ACHK * 16);
  for (int c = 0; c < 512 / ACHK; ++c) {
    #pragma unroll
    for (int u = 0; u < 16; ++u) {
      int i = t + u * 512;                  // < 8192
      int g = i >> 11, j2 = i & 2047;
      int m = j2 >> 4, d = j2 & 15;
      int key = g * 512 + c * ACHK + m;
      size_t off = ((size_t)(b * NN + key)) * 192;
      kv[i] = (d < 8) ? qkv[off + 64 + h * HD + d] : qkv[off + 128 + h * HD + (d - 8)];
    }
    __syncthreads();
    #pragma unroll 2
    for (int m = 0; m < ACHK; ++m) {
      const float4 k0 = *(const float4*)(my_kv + m * 16);
      const float4 k1 = *(const float4*)(my_kv + m * 16 + 4);
      const float4 v0 = *(const float4*)(my_kv + m * 16 + 8);
      const float4 v1 = *(const float4*)(my_kv + m * 16 + 12);
      #pragma unroll
      for (int j = 0; j < 4; ++j) {
        float s = q0[j].x * k0.x + q0[j].y * k0.y + q0[j].z * k0.z + q0[j].w * k0.w +
                  q1[j].x * k1.x + q1[j].y * k1.y + q1[j].z * k1.z + q1[j].w * k1.w;
        float p = __builtin_amdgcn_exp2f(s);
        l[j] += p;
        a0[j].x += p * v0.x; a0[j].y += p * v0.y; a0[j].z += p * v0.z; a0[j].w += p * v0.w;
        a1[j].x += p * v1.x; a1[j].y += p * v1.y; a1[j].z += p * v1.z; a1[j].w += p * v1.w;
      }
    }
    __syncthreads();
  }
  // combine: (0<-2, 1<-3), then (0<-1). Fixed order => deterministic.
  if (ksp >= 2) {
    #pragma unroll
    for (int j = 0; j < 4; ++j) {
      float* cb = cbuf + (((ksp - 2) * 4 + j) * 128 + lt) * 9;
      cb[0] = l[j];
      cb[1] = a0[j].x; cb[2] = a0[j].y; cb[3] = a0[j].z; cb[4] = a0[j].w;
      cb[5] = a1[j].x; cb[6] = a1[j].y; cb[7] = a1[j].z; cb[8] = a1[j].w;
    }
  }
  __syncthreads();
  if (ksp < 2) {
    #pragma unroll
    for (int j = 0; j < 4; ++j) {
      const float* cb = cbuf + ((ksp * 4 + j) * 128 + lt) * 9;
      l[j] += cb[0];
      a0[j].x += cb[1]; a0[j].y += cb[2]; a0[j].z += cb[3]; a0[j].w += cb[4];
      a1[j].x += cb[5]; a1[j].y += cb[6]; a1[j].z += cb[7]; a1[j].w += cb[8];
    }
  }
  __syncthreads();
  if (ksp == 1) {
    #pragma unroll
    for (int j = 0; j < 4; ++j) {
      float* cb = cbuf + ((j * 128 + lt) * 9);
      cb[0] = l[j];
      cb[1] = a0[j].x; cb[2] = a0[j].y; cb[3] = a0[j].z; cb[4] = a0[j].w;
      cb[5] = a1[j].x; cb[6] = a1[j].y; cb[7] = a1[j].z; cb[8] = a1[j].w;
    }
  }
  __syncthreads();
  if (ksp == 0) {
    #pragma unroll
    for (int j = 0; j < 4; ++j) {
      const float* cb = cbuf + ((j * 128 + lt) * 9);
      float lj = l[j] + cb[0];
      float4 o0 = a0[j], o1 = a1[j];
      o0.x += cb[1]; o0.y += cb[2]; o0.z += cb[3]; o0.w += cb[4];
      o1.x += cb[5]; o1.y += cb[6]; o1.z += cb[7]; o1.w += cb[8];
      float inv = 1.f / lj;
      o0.x *= inv; o0.y *= inv; o0.z *= inv; o0.w *= inv;
      o1.x *= inv; o1.y *= inv; o1.z *= inv; o1.w *= inv;
      float* out = a + ((size_t)(b * NN + nbase + 128 * j)) * FF + h * HD;
      *(float4*)(out) = o0;
      *(float4*)(out + 4) = o1;
    }
  }
}

// ------- proj + residual + LN, tiled GEMM ---------
__global__ void k_proj2(const float* __restrict__ a, const float* __restrict__ wout,
                        const float* __restrict__ bout, const float* __restrict__ g,
                        const float* __restrict__ be, float* __restrict__ x) {
  __shared__ float xs[64 * 68];
  __shared__ float ws[64 * 68];
  int row0 = blockIdx.x * 64;
  int t = threadIdx.x;
  #pragma unroll
  for (int i = 0; i < 4; ++i) {
    int q = t + i * 256, r = q >> 4, c = (q & 15) * 4;
    *(float4*)(xs + r * 68 + c) = *(const float4*)(a + (size_t)(row0 + r) * 64 + c);
    *(float4*)(ws + r * 68 + c) = *(const float4*)(wout + r * 64 + c);
  }
  __syncthreads();
  int tx = t & 15, ty = t >> 4;
  float acc[4][4] = {};
  for (int f = 0; f < 64; f += 4) {
    float4 xv[4], wv[4];
    #pragma unroll
    for (int ri = 0; ri < 4; ++ri) xv[ri] = *(const float4*)(xs + (ty * 4 + ri) * 68 + f);
    #pragma unroll
    for (int ci = 0; ci < 4; ++ci) wv[ci] = *(const float4*)(ws + (tx + 16 * ci) * 68 + f);
    #pragma unroll
    for (int ri = 0; ri < 4; ++ri)
      #pragma unroll
      for (int ci = 0; ci < 4; ++ci)
        acc[ri][ci] += xv[ri].x * wv[ci].x + xv[ri].y * wv[ci].y +
                       xv[ri].z * wv[ci].z + xv[ri].w * wv[ci].w;
  }
  #pragma unroll
  for (int ri = 0; ri < 4; ++ri) {
    int rl = ty * 4 + ri;
    float val[4], s = 0.f, sq = 0.f;
    #pragma unroll
    for (int ci = 0; ci < 4; ++ci) {
      int c = tx + 16 * ci;
      val[ci] = x[(size_t)(row0 + rl) * 64 + c] + bout[c] + acc[ri][ci];
      s += val[ci]; sq += val[ci] * val[ci];
    }
    #pragma unroll
    for (int off = 1; off < 16; off <<= 1) { s += __shfl_xor(s, off); sq += __shfl_xor(sq, off); }
    float mean = s * (1.f / 64.f);
    float var = sq * (1.f / 64.f) - mean * mean;
    float rstd = rsqrtf(var + EPSF);
    #pragma unroll
    for (int ci = 0; ci < 4; ++ci) {
      int c = tx + 16 * ci;
      x[(size_t)(row0 + rl) * 64 + c] = (val[ci] - mean) * rstd * g[c] + be[c];
    }
  }
}

// ------- FFN v4: MFMA split-bf16 (hi*hi + hi*lo + lo*hi), split-K grid (256,4) ----
__global__ void __launch_bounds__(256, 4)
k_ffn4(const float* __restrict__ x, const unsigned* __restrict__ w1p,
       const float* __restrict__ b1, const unsigned* __restrict__ w2p,
       float* __restrict__ part) {
  __shared__ unsigned xs[64 * 68];
  __shared__ unsigned ws[64 * 68];
  __shared__ unsigned hs[64 * 68];
  __shared__ float b1s[64];
  int row0 = blockIdx.x * 64;
  int ks = blockIdx.y;
  int t = threadIdx.x;
  int lane = t & 63, wv = t >> 6;
  int lm = lane & 15, lq = lane >> 4;
  #pragma unroll
  for (int i = 0; i < 4; ++i) {
    int q = t + i * 256, r = q >> 4, c = (q & 15) * 4;
    float4 v = *(const float4*)(x + (size_t)(row0 + r) * 64 + c);
    xs[r * 68 + c]     = pk2(v.x);
    xs[r * 68 + c + 1] = pk2(v.y);
    xs[r * 68 + c + 2] = pk2(v.z);
    xs[r * 68 + c + 3] = pk2(v.w);
  }
  f32x4 acc[4];
  #pragma unroll
  for (int tn = 0; tn < 4; ++tn) acc[tn] = (f32x4){0.f, 0.f, 0.f, 0.f};

  for (int ch = 0; ch < 8; ++ch) {
    int kc = (ks * 8 + ch) * 64;
    uint4 rw[4];
    #pragma unroll
    for (int i = 0; i < 4; ++i) {
      int q = t + i * 256, r = q >> 4, c = (q & 15) * 4;
      rw[i] = *(const uint4*)(w1p + (size_t)(kc + r) * 64 + c);
    }
    float rbv = 0.f;
    if (t < 64) rbv = b1[kc + t];
    __syncthreads();  // (A)
    #pragma unroll
    for (int i = 0; i < 4; ++i) {
      int q = t + i * 256, r = q >> 4, c = (q & 15) * 4;
      *(uint4*)(ws + r * 68 + c) = rw[i];
    }
    if (t < 64) b1s[t] = rbv;
    __syncthreads();  // (B)
    f32x4 h4[4];
    #pragma unroll
    for (int tn = 0; tn < 4; ++tn) h4[tn] = (f32x4){0.f, 0.f, 0.f, 0.f};
    #pragma unroll
    for (int kb = 0; kb < 64; kb += 32) {
      unsigned ap[8];
      const unsigned* abase = xs + (wv * 16 + lm) * 68 + kb + lq * 8;
      *(uint4*)(ap)     = *(const uint4*)(abase);
      *(uint4*)(ap + 4) = *(const uint4*)(abase + 4);
      short8 ahi, alo; unpk(ap, ahi, alo);
      #pragma unroll
      for (int tn = 0; tn < 4; ++tn) {
        unsigned bp[8];
        const unsigned* bbase = ws + (tn * 16 + lm) * 68 + kb + lq * 8;
        *(uint4*)(bp)     = *(const uint4*)(bbase);
        *(uint4*)(bp + 4) = *(const uint4*)(bbase + 4);
        short8 bhi, blo; unpk(bp, bhi, blo);
        h4[tn] = __builtin_amdgcn_mfma_f32_16x16x32_bf16(ahi, bhi, h4[tn], 0, 0, 0);
        h4[tn] = __builtin_amdgcn_mfma_f32_16x16x32_bf16(ahi, blo, h4[tn], 0, 0, 0);
        h4[tn] = __builtin_amdgcn_mfma_f32_16x16x32_bf16(alo, bhi, h4[tn], 0, 0, 0);
      }
    }
    #pragma unroll
    for (int tn = 0; tn < 4; ++tn)
      #pragma unroll
      for (int r = 0; r < 4; ++r) {
        float hv = fmaxf(h4[tn][r] + b1s[tn * 16 + lm], 0.f);
        hs[(wv * 16 + lq * 4 + r) * 68 + tn * 16 + lm] = pk2(hv);
      }
    #pragma unroll
    for (int i = 0; i < 4; ++i) {
      int q = t + i * 256, j = q >> 4, c = (q & 15) * 4;
      rw[i] = *(const uint4*)(w2p + (size_t)j * 2048 + kc + c);
    }
    __syncthreads();  // (C)
    #pragma unroll
    for (int i = 0; i < 4; ++i) {
      int q = t + i * 256, j = q >> 4, c = (q & 15) * 4;
      *(uint4*)(ws + j * 68 + c) = rw[i];
    }
    __syncthreads();  // (D)
    #pragma unroll
    for (int kb = 0; kb < 64; kb += 32) {
      unsigned ap[8];
      const unsigned* abase = hs + (wv * 16 + lm) * 68 + kb + lq * 8;
      *(uint4*)(ap)     = *(const uint4*)(abase);
      *(uint4*)(ap + 4) = *(const uint4*)(abase + 4);
      short8 ahi, alo; unpk(ap, ahi, alo);
      #pragma unroll
      for (int tn = 0; tn < 4; ++tn) {
        unsigned bp[8];
        const unsigned* bbase = ws + (tn * 16 + lm) * 68 + kb + lq * 8;
        *(uint4*)(bp)     = *(const uint4*)(bbase);
        *(uint4*)(bp + 4) = *(const uint4*)(bbase + 4);
        short8 bhi, blo; unpk(bp, bhi, blo);
        acc[tn] = __builtin_amdgcn_mfma_f32_16x16x32_bf16(ahi, bhi, acc[tn], 0, 0, 0);
        acc[tn] = __builtin_amdgcn_mfma_f32_16x16x32_bf16(ahi, blo, acc[tn], 0, 0, 0);
        acc[tn] = __builtin_amdgcn_mfma_f32_16x16x32_bf16(alo, bhi, acc[tn], 0, 0, 0);
      }
    }
  }
  float* pb = part + (size_t)ks * (BB * NN * 64);
  #pragma unroll
  for (int tn = 0; tn < 4; ++tn)
    #pragma unroll
    for (int r = 0; r < 4; ++r)
      pb[(size_t)(row0 + wv * 16 + lq * 4 + r) * 64 + tn * 16 + lm] = acc[tn][r];
}

// ------- combine 4 partials + residual + b2 + LN; one wave per row ---------
__global__ void k_ffn_ln(const float* __restrict__ part, const float* __restrict__ b2,
                         const float* __restrict__ g, const float* __restrict__ be,
                         float* __restrict__ x) {
  int row = blockIdx.x * 4 + (threadIdx.x >> 6);
  int j = threadIdx.x & 63;
  size_t o = (size_t)row * 64 + j;
  const size_t S = (size_t)BB * NN * 64;
  float val = x[o] + b2[j] + ((part[o] + part[o + S]) + (part[o + 2 * S] + part[o + 3 * S]));
  float s = val;
  for (int off = 32; off; off >>= 1) s += __shfl_xor(s, off);
  s *= (1.f / 64.f);
  float d = val - s;
  float v = d * d;
  for (int off = 32; off; off >>= 1) v += __shfl_xor(v, off);
  v *= (1.f / 64.f);
  x[o] = d * rsqrtf(v + EPSF) * g[j] + be[j];
}

// ------- score head tiled ----------
__global__ void k_fg2(const float* __restrict__ x,
                      const float* __restrict__ w0, const float* __restrict__ b0, const float* __restrict__ bn0,
                      const float* __restrict__ w1, const float* __restrict__ b1, const float* __restrict__ bn1,
                      const float* __restrict__ w2, const float* __restrict__ b2, const float* __restrict__ bn2,
                      float* __restrict__ scores) {
  __shared__ float xs[64 * 68];
  __shared__ float ws[64 * 68];
  __shared__ float s0s[64 * 68];
  __shared__ float s1s[64 * 20];
  int row0 = blockIdx.x * 64;
  int t = threadIdx.x;
  #pragma unroll
  for (int i = 0; i < 4; ++i) {
    int q = t + i * 256, r = q >> 4, c = (q & 15) * 4;
    *(float4*)(xs + r * 68 + c) = *(const float4*)(x + (size_t)(row0 + r) * 64 + c);
    *(float4*)(ws + r * 68 + c) = *(const float4*)(w0 + r * 64 + c);
  }
  __syncthreads();
  int tx = t & 15, ty = t >> 4;
  float acc[4][4] = {};
  for (int f = 0; f < 64; f += 4) {
    float4 xv[4], wv[4];
    #pragma unroll
    for (int ri = 0; ri < 4; ++ri) xv[ri] = *(const float4*)(xs + (ty * 4 + ri) * 68 + f);
    #pragma unroll
    for (int ci = 0; ci < 4; ++ci) wv[ci] = *(const float4*)(ws + (tx + 16 * ci) * 68 + f);
    #pragma unroll
    for (int ri = 0; ri < 4; ++ri)
      #pragma unroll
      for (int ci = 0; ci < 4; ++ci)
        acc[ri][ci] += xv[ri].x * wv[ci].x + xv[ri].y * wv[ci].y +
                       xv[ri].z * wv[ci].z + xv[ri].w * wv[ci].w;
  }
  #pragma unroll
  for (int ri = 0; ri < 4; ++ri)
    #pragma unroll
    for (int ci = 0; ci < 4; ++ci) {
      int c = tx + 16 * ci;
      float sc = bn0[c] * rsqrtf(bn0[192 + c] + EPSF);
      float v = (acc[ri][ci] + b0[c] - bn0[128 + c]) * sc + bn0[64 + c];
      s0s[(ty * 4 + ri) * 68 + c] = fmaxf(v, 0.f);
    }
  __syncthreads();
  {
    int rl = t & 63, j0 = t >> 6;
    #pragma unroll
    for (int i = 0; i < 4; ++i) {
      int j = j0 + 4 * i;
      float s = b1[j];
      const float* wr = w1 + j * 64;
      #pragma unroll 16
      for (int c = 0; c < 64; ++c) s += s0s[rl * 68 + c] * wr[c];
      float sc = bn1[j] * rsqrtf(bn1[48 + j] + EPSF);
      s = (s - bn1[32 + j]) * sc + bn1[16 + j];
      s1s[rl * 20 + j] = fmaxf(s, 0.f);
    }
  }
  __syncthreads();
  if (t < 64) {
    float s = b2[0];
    #pragma unroll
    for (int o = 0; o < 16; ++o) s += s1s[t * 20 + o] * w2[o];
    float sc = bn2[0] * rsqrtf(bn2[3] + EPSF);
    s = (s - bn2[2]) * sc + bn2[1];
    scores[row0 + t] = fmaxf(s, 0.f);
  }
}

// ---- top-k (k=16) ----
__global__ void k_topk2(const float* __restrict__ scores, int* __restrict__ idx,
                        float* __restrict__ out_idx) {
  int b = blockIdx.x, t = threadIdx.x;
  float v[8];
  int base = b * NN;
  #pragma unroll
  for (int u = 0; u < 8; ++u) v[u] = scores[base + t + 256 * u];
  __shared__ float wvs[4];
  __shared__ int wis[4];
  __shared__ int winner;
  unsigned taken = 0;
  for (int r = 0; r < TOPK; ++r) {
    float best = -1e30f; int bi = 1 << 30;
    #pragma unroll
    for (int u = 0; u < 8; ++u) {
      if (!((taken >> u) & 1)) {
        float vv = v[u]; int ii = t + 256 * u;
        if (vv > best || (vv == best && ii < bi)) { best = vv; bi = ii; }
      }
    }
    for (int off = 32; off; off >>= 1) {
      float ov = __shfl_xor(best, off);
      int oi = __shfl_xor(bi, off);
      if (ov > best || (ov == best && oi < bi)) { best = ov; bi = oi; }
    }
    if ((t & 63) == 0) { wvs[t >> 6] = best; wis[t >> 6] = bi; }
    __syncthreads();
    if (t == 0) {
      float B = wvs[0]; int I = wis[0];
      #pragma unroll
      for (int q = 1; q < 4; ++q)
        if (wvs[q] > B || (wvs[q] == B && wis[q] < I)) { B = wvs[q]; I = wis[q]; }
      winner = I;
      idx[b * TOPK + r] = I;
      out_idx[b * TOPK + r] = (float)I;
    }
    __syncthreads();
    int w = winner;
    if ((w & 255) == t) taken |= 1u << (w >> 8);
  }
}

// ---------------- ball query + 3 conv stages, block = 64 per (b,k) ----------------
__global__ void k_group(const float* __restrict__ inp, const int* __restrict__ idx,
                        const float* __restrict__ w0, const float* __restrict__ b0, const float* __restrict__ bn0,
                        const float* __restrict__ w1, const float* __restrict__ b1, const float* __restrict__ bn1,
                        const float* __restrict__ w2, const float* __restrict__ b2, const float* __restrict__ bn2,
                        float* __restrict__ r2g) {
  __shared__ int gidx[NSAMP];
  __shared__ float gsh[65 * DD];
  __shared__ float r0[128];
  __shared__ float r1[256];
  int k = blockIdx.x, b = blockIdx.y;
  int lane = threadIdx.x;
  int qn = idx[b * TOPK + k];
  const float* px = inp + (size_t)b * DD * NN;
  float qx = px[qn], qy = px[NN + qn], qz = px[2 * NN + qn];
  int cnt = 0;
  for (int base = 0; base < NN && cnt < NSAMP; base += 64) {
    int n = base + lane;
    float dx = px[n] - qx, dy = px[NN + n] - qy, dz = px[2 * NN + n] - qz;
    float d2 = dx * dx + dy * dy + dz * dz;
    bool flag = (d2 <= R2);
    unsigned long long m = __ballot(flag);
    int pos = cnt + __popcll(m & ((1ull << lane) - 1ull));
    if (flag && pos < NSAMP) gidx[pos] = n;
    cnt += (int)__popcll(m);
  }
  __syncthreads();
  int total = cnt < NSAMP ? cnt : NSAMP;
  if (lane >= total) gidx[lane] = gidx[0];
  __syncthreads();
  for (int i = lane; i < 65 * DD; i += 64) {
    int p = i / DD, d = i - p * DD;
    int n = (p == 0) ? qn : gidx[p - 1];
    gsh[i] = px[d * NN + n];
  }
  __syncthreads();
  for (int c = lane; c < 128; c += 64) {
    float s = b0[c];
    const float* w = w0 + c * 390;
    for (int i = 0; i < 390; ++i) s += gsh[i] * w[i];
    float sc = bn0[c] * rsqrtf(bn0[384 + c] + EPSF);
    s = (s - bn0[256 + c]) * sc + bn0[128 + c];
    r0[c] = fmaxf(s, 0.f);
  }
  __syncthreads();
  for (int c = lane; c < 256; c += 64) {
    float s = b1[c];
    const float* w = w1 + c * 128;
    for (int o = 0; o < 128; ++o) s += r0[o] * w[o];
    float sc = bn1[c] * rsqrtf(bn1[768 + c] + EPSF);
    s = (s - bn1[512 + c]) * sc + bn1[256 + c];
    r1[c] = fmaxf(s, 0.f);
  }
  __syncthreads();
  for (int c = lane; c < 512; c += 64) {
    float s = b2[c];
    const float* w = w2 + c * 256;
    for (int o = 0; o < 256; ++o) s += r1[o] * w[o];
    float sc = bn2[c] * rsqrtf(bn2[1536 + c] + EPSF);
    s = (s - bn2[1024 + c]) * sc + bn2[512 + c];
    r2g[b * 8192 + c * TOPK + k] = fmaxf(s, 0.f);
  }
}

// ---------------- FC + BN + ReLU (wave-reduced dot), block=64 ----------------
__global__ void k_fl(const float* __restrict__ hin, const float* __restrict__ w,
                     const float* __restrict__ bias, const float* __restrict__ bn,
                     float* __restrict__ hout, int IN, int OUT) {
  int blk = blockIdx.x;
  int b = blk / OUT, j = blk % OUT;
  int lane = threadIdx.x;
  const float* hr = hin + (size_t)b * IN;
  const float* wr = w + (size_t)j * IN;
  float s = 0.f;
  for (int i = lane; i < IN; i += 64) s += hr[i] * wr[i];
  for (int o = 32; o; o >>= 1) s += __shfl_xor(s, o);
  if (lane == 0) {
    s += bias[j];
    float sc = bn[j] * rsqrtf(bn[3 * OUT + j] + EPSF);
    s = (s - bn[2 * OUT + j]) * sc + bn[OUT + j];
    hout[b * OUT + j] = fmaxf(s, 0.f);
  }
}

extern "C" void kernel_launch(void* const* d_in, const int* in_sizes, int n_in,
                              void* d_out, int out_size, void* d_ws, size_t ws_size,
                              hipStream_t stream) {
  const float* sv      = (const float*)d_in[0];
  const float* inp     = (const float*)d_in[1];
  const float* tl_win  = (const float*)d_in[2];
  const float* tl_bin  = (const float*)d_in[3];
  const float* tl_wout = (const float*)d_in[4];
  const float* tl_bout = (const float*)d_in[5];
  const float* tl_w1   = (const float*)d_in[6];
  const float* tl_b1   = (const float*)d_in[7];
  const float* tl_w2   = (const float*)d_in[8];
  const float* tl_b2   = (const float*)d_in[9];
  const float* tl_ln1g = (const float*)d_in[10];
  const float* tl_ln1b = (const float*)d_in[11];
  const float* tl_ln2g = (const float*)d_in[12];
  const float* tl_ln2b = (const float*)d_in[13];
  const float* fg_w0   = (const float*)d_in[14];
  const float* fg_b0   = (const float*)d_in[15];
  const float* fg_w1   = (const float*)d_in[16];
  const float* fg_b1   = (const float*)d_in[17];
  const float* fg_w2   = (const float*)d_in[18];
  const float* fg_b2   = (const float*)d_in[19];
  const float* fbn0    = (const float*)d_in[20];
  const float* fbn1    = (const float*)d_in[21];
  const float* fbn2    = (const float*)d_in[22];
  const float* rc_w0   = (const float*)d_in[23];
  const float* rc_b0   = (const float*)d_in[24];
  const float* rc_w1   = (const float*)d_in[25];
  const float* rc_b1   = (const float*)d_in[26];
  const float* rc_w2   = (const float*)d_in[27];
  const float* rc_b2   = (const float*)d_in[28];
  const float* rbn0    = (const float*)d_in[29];
  const float* rbn1    = (const float*)d_in[30];
  const float* rbn2    = (const float*)d_in[31];
  const float* fl_w0   = (const float*)d_in[32];
  const float* fl_b0   = (const float*)d_in[33];
  const float* fl_w1   = (const float*)d_in[34];
  const float* fl_b1   = (const float*)d_in[35];
  const float* lbn0    = (const float*)d_in[36];
  const float* lbn1    = (const float*)d_in[37];
  (void)in_sizes; (void)n_in; (void)out_size; (void)ws_size;

  float* wsp = (float*)d_ws;
  float* x      = wsp;                        // B*N*F      = 1048576
  float* qkv    = x + BB * NN * FF;           // B*N*192    = 3145728
  float* a      = qkv + BB * NN * 192;        // B*N*F      = 1048576
  float* scores = a + BB * NN * FF;           // B*N        = 16384
  int*   idxb   = (int*)(scores + BB * NN);   // B*TOPK     = 128
  float* r2g    = (float*)(idxb + BB * TOPK); // B*8192     = 65536
  float* h1g    = r2g + BB * 8192;            // B*1024     = 8192
  unsigned* wpk1 = (unsigned*)(h1g + BB * 1024);   // 2*2048*64 = 262144
  unsigned* wpk2 = wpk1 + NLAYER * 2048 * 64;      // 2*64*2048 = 262144
  float* part   = qkv;  // FFN split-K partials reuse qkv+a (4*16384*64 floats)

  float* out = (float*)d_out;  // fp32: h at [0,4096), idx-as-float at [4096,4224)

  k_transpose<<<(BB * NN * FF) / 256, 256, 0, stream>>>(sv, x);
  k_wpack<<<(NLAYER * 2048 * 64) / 256, 256, 0, stream>>>(tl_w1, wpk1, NLAYER * 2048 * 64);
  k_wpack<<<(NLAYER * 2048 * 64) / 256, 256, 0, stream>>>(tl_w2, wpk2, NLAYER * 2048 * 64);

  for (int l = 0; l < NLAYER; ++l) {
    k_qkv2<<<dim3(BB * NN / 64, 3), 256, 0, stream>>>(x, tl_win + l * 192 * FF,
                                                      tl_bin + l * 192, qkv);
    k_attn4<<<dim3(NN / 512, NHEAD, BB), 512, 0, stream>>>(qkv, a);
    k_proj2<<<BB * NN / 64, 256, 0, stream>>>(a, tl_wout + l * FF * FF, tl_bout + l * FF,
                                              tl_ln1g + l * FF, tl_ln1b + l * FF, x);
    k_ffn4<<<dim3(BB * NN / 64, 4), 256, 0, stream>>>(x, wpk1 + l * 2048 * 64,
                                                      tl_b1 + l * 2048,
                                                      wpk2 + l * 2048 * 64, part);
    k_ffn_ln<<<BB * NN / 4, 256, 0, stream>>>(part, tl_b2 + l * FF,
                                              tl_ln2g + l * FF, tl_ln2b + l * FF, x);
  }

  k_fg2<<<BB * NN / 64, 256, 0, stream>>>(x, fg_w0, fg_b0, fbn0, fg_w1, fg_b1, fbn1,
                                          fg_w2, fg_b2, fbn2, scores);
  k_topk2<<<BB, 256, 0, stream>>>(scores, idxb, out + BB * 512);
  k_group<<<dim3(TOPK, BB), 64, 0, stream>>>(inp, idxb, rc_w0, rc_b0, rbn0,
                                             rc_w1, rc_b1, rbn1, rc_w2, rc_b2, rbn2, r2g);
  k_fl<<<BB * 1024, 64, 0, stream>>>(r2g, fl_w0, fl_b0, lbn0, h1g, 8192, 1024);
  k_fl<<<BB * 512, 64, 0, stream>>>(h1g, fl_w1, fl_b1, lbn1, out, 1024, 512);
}

// Round 8
// 835.483 us; speedup vs baseline: 5.8308x; 1.0499x over previous
//
#include <hip/hip_runtime.h>
#include <hip/hip_bf16.h>
#include <math.h>

#define BB 8
#define NN 2048
#define FF 64
#define DD 6
#define NSAMP 64
#define TOPK 16
#define NHEAD 8
#define HD 8
#define NLAYER 2
#define EPSF 1e-5f
#define R2 0.09f

typedef short short8 __attribute__((ext_vector_type(8)));
typedef float f32x4 __attribute__((ext_vector_type(4)));

// split-pack: u32 = (bf16_hi << 16) | bf16_lo, both RNE. x ≈ hi + lo, err ~2^-16 rel.
__device__ inline unsigned pk2(float x) {
  unsigned b = __float_as_uint(x);
  unsigned hi = (b + 0x7fffu + ((b >> 16) & 1u)) >> 16;
  float r = x - __uint_as_float(hi << 16);
  unsigned c = __float_as_uint(r);
  unsigned lo = (c + 0x7fffu + ((c >> 16) & 1u)) >> 16;
  return (hi << 16) | lo;
}

__device__ inline void unpk(const unsigned* p, short8& hi, short8& lo) {
  #pragma unroll
  for (int i = 0; i < 8; ++i) {
    hi[i] = (short)(p[i] >> 16);
    lo[i] = (short)(p[i] & 0xffffu);
  }
}

// ---------------- transpose sortvec (B,1,F,N) -> x (B,N,F) ----------------
__global__ void k_transpose(const float* __restrict__ sv, float* __restrict__ x) {
  int i = blockIdx.x * 256 + threadIdx.x;
  if (i >= BB * NN * FF) return;
  int f = i % FF;
  int n = (i / FF) % NN;
  int b = i / (FF * NN);
  x[i] = sv[(b * FF + f) * NN + n];
}

// ---------------- pack fp32 weights -> split-bf16 u32 ----------------
__global__ void k_wpack(const float* __restrict__ w, unsigned* __restrict__ o, int n) {
  int i = blockIdx.x * 256 + threadIdx.x;
  if (i < n) o[i] = pk2(w[i]);
}

// ---------------- tiled GEMM: qkv[row][192] = x[row][64] @ win^T + bin ----------
__global__ void k_qkv2(const float* __restrict__ x, const float* __restrict__ win,
                       const float* __restrict__ bin, float* __restrict__ qkv) {
  __shared__ float xs[64 * 68];
  __shared__ float ws[64 * 68];
  int row0 = blockIdx.x * 64, col0 = blockIdx.y * 64;
  int t = threadIdx.x;
  #pragma unroll
  for (int i = 0; i < 4; ++i) {
    int q = t + i * 256, r = q >> 4, c = (q & 15) * 4;
    *(float4*)(xs + r * 68 + c) = *(const float4*)(x + (size_t)(row0 + r) * 64 + c);
    *(float4*)(ws + r * 68 + c) = *(const float4*)(win + (size_t)(col0 + r) * 64 + c);
  }
  __syncthreads();
  int tx = t & 15, ty = t >> 4;
  float acc[4][4] = {};
  for (int f = 0; f < 64; f += 4) {
    float4 xv[4], wv[4];
    #pragma unroll
    for (int ri = 0; ri < 4; ++ri) xv[ri] = *(const float4*)(xs + (ty * 4 + ri) * 68 + f);
    #pragma unroll
    for (int ci = 0; ci < 4; ++ci) wv[ci] = *(const float4*)(ws + (tx + 16 * ci) * 68 + f);
    #pragma unroll
    for (int ri = 0; ri < 4; ++ri)
      #pragma unroll
      for (int ci = 0; ci < 4; ++ci)
        acc[ri][ci] += xv[ri].x * wv[ci].x + xv[ri].y * wv[ci].y +
                       xv[ri].z * wv[ci].z + xv[ri].w * wv[ci].w;
  }
  #pragma unroll
  for (int ri = 0; ri < 4; ++ri)
    #pragma unroll
    for (int ci = 0; ci < 4; ++ci) {
      int r = row0 + ty * 4 + ri, c = col0 + tx + 16 * ci;
      qkv[(size_t)r * 192 + c] = acc[ri][ci] + bin[c];
    }
}

// ---- attention v5: MFMA flash. Block 256 thr = 4 waves; wave owns 16 queries
// x all 2048 keys. QK^T: 16x16x32 bf16 MFMA, K=8 zero-padded, split-bf16 Q/K
// (3 mfma). P=exp2(S) from C-layout regs, split-packed through per-wave LDS
// (C->A transform), PV: 3 mfma vs split V^T planes; ones-row gives l in col 8.
__global__ void __launch_bounds__(256, 4)
k_attn5(const float* __restrict__ qkv, float* __restrict__ a) {
  __shared__ __attribute__((aligned(16))) unsigned short khi[256 * 8];
  __shared__ __attribute__((aligned(16))) unsigned short klo[256 * 8];
  __shared__ __attribute__((aligned(16))) unsigned short vhi[9 * 264];
  __shared__ __attribute__((aligned(16))) unsigned short vlo[9 * 264];
  __shared__ __attribute__((aligned(16))) unsigned short pbh[4 * 16 * 40];
  __shared__ __attribute__((aligned(16))) unsigned short pbl[4 * 16 * 40];
  int t = threadIdx.x;
  int lane = t & 63, w = t >> 6;
  int nIdx = lane & 15, lq = lane >> 4;
  int h = blockIdx.y, b = blockIdx.z;
  int qwb = blockIdx.x * 64 + w * 16;  // wave's first query row
  const float kf = 0.35355339059327373f * 1.4426950408889634f;  // scale*log2e
  // Q A-fragment (split, trunc): quad0 lanes hold k=0..7, others zero
  short8 qhiF = {0, 0, 0, 0, 0, 0, 0, 0};
  short8 qloF = {0, 0, 0, 0, 0, 0, 0, 0};
  if (lq == 0) {
    const float* qr = qkv + ((size_t)(b * NN + qwb + nIdx)) * 192 + h * HD;
    #pragma unroll
    for (int j = 0; j < 8; ++j) {
      float v = qr[j] * kf;
      unsigned bb = __float_as_uint(v);
      float r = v - __uint_as_float(bb & 0xffff0000u);
      qhiF[j] = (short)(bb >> 16);
      qloF[j] = (short)(__float_as_uint(r) >> 16);
    }
  }
  f32x4 acc = {0.f, 0.f, 0.f, 0.f};
  unsigned short* mypbh = pbh + w * 640;
  unsigned short* mypbl = pbl + w * 640;
  for (int kc = 0; kc < NN; kc += 256) {
    __syncthreads();
    #pragma unroll
    for (int i = 0; i < 8; ++i) {  // stage K chunk (split)
      int e = t + i * 256;
      int key = e >> 3, d = e & 7;
      float f = qkv[((size_t)(b * NN + kc + key)) * 192 + 64 + h * HD + d];
      unsigned bb = __float_as_uint(f);
      float r = f - __uint_as_float(bb & 0xffff0000u);
      khi[key * 8 + d] = (unsigned short)(bb >> 16);
      klo[key * 8 + d] = (unsigned short)(__float_as_uint(r) >> 16);
    }
    #pragma unroll
    for (int i = 0; i < 8; ++i) {  // stage V^T chunk (split)
      int e = t + i * 256;
      int key = e >> 3, d = e & 7;
      float f = qkv[((size_t)(b * NN + kc + key)) * 192 + 128 + h * HD + d];
      unsigned bb = __float_as_uint(f);
      float r = f - __uint_as_float(bb & 0xffff0000u);
      vhi[d * 264 + key] = (unsigned short)(bb >> 16);
      vlo[d * 264 + key] = (unsigned short)(__float_as_uint(r) >> 16);
    }
    vhi[8 * 264 + t] = 0x3f80;  // ones row -> l in C col 8
    vlo[8 * 264 + t] = 0;
    __syncthreads();
    for (int s = 0; s < 8; ++s) {
      int kb = s * 32;
      #pragma unroll
      for (int half = 0; half < 2; ++half) {
        int key = kb + half * 16 + nIdx;
        short8 bh = *(const short8*)(khi + key * 8);
        short8 bl = *(const short8*)(klo + key * 8);
        if (lq != 0) {
          bh = (short8){0, 0, 0, 0, 0, 0, 0, 0};
          bl = (short8){0, 0, 0, 0, 0, 0, 0, 0};
        }
        f32x4 c = {0.f, 0.f, 0.f, 0.f};
        c = __builtin_amdgcn_mfma_f32_16x16x32_bf16(qhiF, bh, c, 0, 0, 0);
        c = __builtin_amdgcn_mfma_f32_16x16x32_bf16(qhiF, bl, c, 0, 0, 0);
        c = __builtin_amdgcn_mfma_f32_16x16x32_bf16(qloF, bh, c, 0, 0, 0);
        #pragma unroll
        for (int r = 0; r < 4; ++r) {
          float p = __builtin_amdgcn_exp2f(c[r]);
          unsigned bb = __float_as_uint(p);
          float rr = p - __uint_as_float(bb & 0xffff0000u);
          int row = lq * 4 + r;
          mypbh[row * 40 + half * 16 + nIdx] = (unsigned short)(bb >> 16);
          mypbl[row * 40 + half * 16 + nIdx] = (unsigned short)(__float_as_uint(rr) >> 16);
        }
      }
      // C->A transform readback (same-wave LDS, compiler inserts lgkm wait)
      short8 pah = *(const short8*)(mypbh + nIdx * 40 + lq * 8);
      short8 pal = *(const short8*)(mypbl + nIdx * 40 + lq * 8);
      int vn = nIdx < 9 ? nIdx : 8;
      short8 vbh = *(const short8*)(vhi + vn * 264 + kb + lq * 8);
      short8 vbl = *(const short8*)(vlo + vn * 264 + kb + lq * 8);
      acc = __builtin_amdgcn_mfma_f32_16x16x32_bf16(pah, vbh, acc, 0, 0, 0);
      acc = __builtin_amdgcn_mfma_f32_16x16x32_bf16(pah, vbl, acc, 0, 0, 0);
      acc = __builtin_amdgcn_mfma_f32_16x16x32_bf16(pal, vbh, acc, 0, 0, 0);
    }
  }
  // epilogue: col 8 holds l; divide and scatter (cols 0..7 are the 8 dims)
  #pragma unroll
  for (int r = 0; r < 4; ++r) {
    float lr = __shfl(acc[r], (lane & 48) | 8);
    if (nIdx < 8) {
      int row = qwb + lq * 4 + r;
      a[((size_t)(b * NN + row)) * 64 + h * HD + nIdx] = acc[r] / lr;
    }
  }
}

// ------- proj + residual + LN, tiled GEMM ---------
__global__ void k_proj2(const float* __restrict__ a, const float* __restrict__ wout,
                        const float* __restrict__ bout, const float* __restrict__ g,
                        const float* __restrict__ be, float* __restrict__ x) {
  __shared__ float xs[64 * 68];
  __shared__ float ws[64 * 68];
  int row0 = blockIdx.x * 64;
  int t = threadIdx.x;
  #pragma unroll
  for (int i = 0; i < 4; ++i) {
    int q = t + i * 256, r = q >> 4, c = (q & 15) * 4;
    *(float4*)(xs + r * 68 + c) = *(const float4*)(a + (size_t)(row0 + r) * 64 + c);
    *(float4*)(ws + r * 68 + c) = *(const float4*)(wout + r * 64 + c);
  }
  __syncthreads();
  int tx = t & 15, ty = t >> 4;
  float acc[4][4] = {};
  for (int f = 0; f < 64; f += 4) {
    float4 xv[4], wv[4];
    #pragma unroll
    for (int ri = 0; ri < 4; ++ri) xv[ri] = *(const float4*)(xs + (ty * 4 + ri) * 68 + f);
    #pragma unroll
    for (int ci = 0; ci < 4; ++ci) wv[ci] = *(const float4*)(ws + (tx + 16 * ci) * 68 + f);
    #pragma unroll
    for (int ri = 0; ri < 4; ++ri)
      #pragma unroll
      for (int ci = 0; ci < 4; ++ci)
        acc[ri][ci] += xv[ri].x * wv[ci].x + xv[ri].y * wv[ci].y +
                       xv[ri].z * wv[ci].z + xv[ri].w * wv[ci].w;
  }
  #pragma unroll
  for (int ri = 0; ri < 4; ++ri) {
    int rl = ty * 4 + ri;
    float val[4], s = 0.f, sq = 0.f;
    #pragma unroll
    for (int ci = 0; ci < 4; ++ci) {
      int c = tx + 16 * ci;
      val[ci] = x[(size_t)(row0 + rl) * 64 + c] + bout[c] + acc[ri][ci];
      s += val[ci]; sq += val[ci] * val[ci];
    }
    #pragma unroll
    for (int off = 1; off < 16; off <<= 1) { s += __shfl_xor(s, off); sq += __shfl_xor(sq, off); }
    float mean = s * (1.f / 64.f);
    float var = sq * (1.f / 64.f) - mean * mean;
    float rstd = rsqrtf(var + EPSF);
    #pragma unroll
    for (int ci = 0; ci < 4; ++ci) {
      int c = tx + 16 * ci;
      x[(size_t)(row0 + rl) * 64 + c] = (val[ci] - mean) * rstd * g[c] + be[c];
    }
  }
}

// ------- FFN v4: MFMA split-bf16 (hi*hi + hi*lo + lo*hi), split-K grid (256,4) ----
__global__ void __launch_bounds__(256, 4)
k_ffn4(const float* __restrict__ x, const unsigned* __restrict__ w1p,
       const float* __restrict__ b1, const unsigned* __restrict__ w2p,
       float* __restrict__ part) {
  __shared__ unsigned xs[64 * 68];
  __shared__ unsigned ws[64 * 68];
  __shared__ unsigned hs[64 * 68];
  __shared__ float b1s[64];
  int row0 = blockIdx.x * 64;
  int ks = blockIdx.y;
  int t = threadIdx.x;
  int lane = t & 63, wv = t >> 6;
  int lm = lane & 15, lq = lane >> 4;
  #pragma unroll
  for (int i = 0; i < 4; ++i) {
    int q = t + i * 256, r = q >> 4, c = (q & 15) * 4;
    float4 v = *(const float4*)(x + (size_t)(row0 + r) * 64 + c);
    xs[r * 68 + c]     = pk2(v.x);
    xs[r * 68 + c + 1] = pk2(v.y);
    xs[r * 68 + c + 2] = pk2(v.z);
    xs[r * 68 + c + 3] = pk2(v.w);
  }
  f32x4 acc[4];
  #pragma unroll
  for (int tn = 0; tn < 4; ++tn) acc[tn] = (f32x4){0.f, 0.f, 0.f, 0.f};

  for (int ch = 0; ch < 8; ++ch) {
    int kc = (ks * 8 + ch) * 64;
    uint4 rw[4];
    #pragma unroll
    for (int i = 0; i < 4; ++i) {
      int q = t + i * 256, r = q >> 4, c = (q & 15) * 4;
      rw[i] = *(const uint4*)(w1p + (size_t)(kc + r) * 64 + c);
    }
    float rbv = 0.f;
    if (t < 64) rbv = b1[kc + t];
    __syncthreads();  // (A)
    #pragma unroll
    for (int i = 0; i < 4; ++i) {
      int q = t + i * 256, r = q >> 4, c = (q & 15) * 4;
      *(uint4*)(ws + r * 68 + c) = rw[i];
    }
    if (t < 64) b1s[t] = rbv;
    __syncthreads();  // (B)
    f32x4 h4[4];
    #pragma unroll
    for (int tn = 0; tn < 4; ++tn) h4[tn] = (f32x4){0.f, 0.f, 0.f, 0.f};
    #pragma unroll
    for (int kb = 0; kb < 64; kb += 32) {
      unsigned ap[8];
      const unsigned* abase = xs + (wv * 16 + lm) * 68 + kb + lq * 8;
      *(uint4*)(ap)     = *(const uint4*)(abase);
      *(uint4*)(ap + 4) = *(const uint4*)(abase + 4);
      short8 ahi, alo; unpk(ap, ahi, alo);
      #pragma unroll
      for (int tn = 0; tn < 4; ++tn) {
        unsigned bp[8];
        const unsigned* bbase = ws + (tn * 16 + lm) * 68 + kb + lq * 8;
        *(uint4*)(bp)     = *(const uint4*)(bbase);
        *(uint4*)(bp + 4) = *(const uint4*)(bbase + 4);
        short8 bhi, blo; unpk(bp, bhi, blo);
        h4[tn] = __builtin_amdgcn_mfma_f32_16x16x32_bf16(ahi, bhi, h4[tn], 0, 0, 0);
        h4[tn] = __builtin_amdgcn_mfma_f32_16x16x32_bf16(ahi, blo, h4[tn], 0, 0, 0);
        h4[tn] = __builtin_amdgcn_mfma_f32_16x16x32_bf16(alo, bhi, h4[tn], 0, 0, 0);
      }
    }
    #pragma unroll
    for (int tn = 0; tn < 4; ++tn)
      #pragma unroll
      for (int r = 0; r < 4; ++r) {
        float hv = fmaxf(h4[tn][r] + b1s[tn * 16 + lm], 0.f);
        hs[(wv * 16 + lq * 4 + r) * 68 + tn * 16 + lm] = pk2(hv);
      }
    #pragma unroll
    for (int i = 0; i < 4; ++i) {
      int q = t + i * 256, j = q >> 4, c = (q & 15) * 4;
      rw[i] = *(const uint4*)(w2p + (size_t)j * 2048 + kc + c);
    }
    __syncthreads();  // (C)
    #pragma unroll
    for (int i = 0; i < 4; ++i) {
      int q = t + i * 256, j = q >> 4, c = (q & 15) * 4;
      *(uint4*)(ws + j * 68 + c) = rw[i];
    }
    __syncthreads();  // (D)
    #pragma unroll
    for (int kb = 0; kb < 64; kb += 32) {
      unsigned ap[8];
      const unsigned* abase = hs + (wv * 16 + lm) * 68 + kb + lq * 8;
      *(uint4*)(ap)     = *(const uint4*)(abase);
      *(uint4*)(ap + 4) = *(const uint4*)(abase + 4);
      short8 ahi, alo; unpk(ap, ahi, alo);
      #pragma unroll
      for (int tn = 0; tn < 4; ++tn) {
        unsigned bp[8];
        const unsigned* bbase = ws + (tn * 16 + lm) * 68 + kb + lq * 8;
        *(uint4*)(bp)     = *(const uint4*)(bbase);
        *(uint4*)(bp + 4) = *(const uint4*)(bbase + 4);
        short8 bhi, blo; unpk(bp, bhi, blo);
        acc[tn] = __builtin_amdgcn_mfma_f32_16x16x32_bf16(ahi, bhi, acc[tn], 0, 0, 0);
        acc[tn] = __builtin_amdgcn_mfma_f32_16x16x32_bf16(ahi, blo, acc[tn], 0, 0, 0);
        acc[tn] = __builtin_amdgcn_mfma_f32_16x16x32_bf16(alo, bhi, acc[tn], 0, 0, 0);
      }
    }
  }
  float* pb = part + (size_t)ks * (BB * NN * 64);
  #pragma unroll
  for (int tn = 0; tn < 4; ++tn)
    #pragma unroll
    for (int r = 0; r < 4; ++r)
      pb[(size_t)(row0 + wv * 16 + lq * 4 + r) * 64 + tn * 16 + lm] = acc[tn][r];
}

// ------- combine 4 partials + residual + b2 + LN; one wave per row ---------
__global__ void k_ffn_ln(const float* __restrict__ part, const float* __restrict__ b2,
                         const float* __restrict__ g, const float* __restrict__ be,
                         float* __restrict__ x) {
  int row = blockIdx.x * 4 + (threadIdx.x >> 6);
  int j = threadIdx.x & 63;
  size_t o = (size_t)row * 64 + j;
  const size_t S = (size_t)BB * NN * 64;
  float val = x[o] + b2[j] + ((part[o] + part[o + S]) + (part[o + 2 * S] + part[o + 3 * S]));
  float s = val;
  for (int off = 32; off; off >>= 1) s += __shfl_xor(s, off);
  s *= (1.f / 64.f);
  float d = val - s;
  float v = d * d;
  for (int off = 32; off; off >>= 1) v += __shfl_xor(v, off);
  v *= (1.f / 64.f);
  x[o] = d * rsqrtf(v + EPSF) * g[j] + be[j];
}

// ------- score head tiled ----------
__global__ void k_fg2(const float* __restrict__ x,
                      const float* __restrict__ w0, const float* __restrict__ b0, const float* __restrict__ bn0,
                      const float* __restrict__ w1, const float* __restrict__ b1, const float* __restrict__ bn1,
                      const float* __restrict__ w2, const float* __restrict__ b2, const float* __restrict__ bn2,
                      float* __restrict__ scores) {
  __shared__ float xs[64 * 68];
  __shared__ float ws[64 * 68];
  __shared__ float s0s[64 * 68];
  __shared__ float s1s[64 * 20];
  int row0 = blockIdx.x * 64;
  int t = threadIdx.x;
  #pragma unroll
  for (int i = 0; i < 4; ++i) {
    int q = t + i * 256, r = q >> 4, c = (q & 15) * 4;
    *(float4*)(xs + r * 68 + c) = *(const float4*)(x + (size_t)(row0 + r) * 64 + c);
    *(float4*)(ws + r * 68 + c) = *(const float4*)(w0 + r * 64 + c);
  }
  __syncthreads();
  int tx = t & 15, ty = t >> 4;
  float acc[4][4] = {};
  for (int f = 0; f < 64; f += 4) {
    float4 xv[4], wv[4];
    #pragma unroll
    for (int ri = 0; ri < 4; ++ri) xv[ri] = *(const float4*)(xs + (ty * 4 + ri) * 68 + f);
    #pragma unroll
    for (int ci = 0; ci < 4; ++ci) wv[ci] = *(const float4*)(ws + (tx + 16 * ci) * 68 + f);
    #pragma unroll
    for (int ri = 0; ri < 4; ++ri)
      #pragma unroll
      for (int ci = 0; ci < 4; ++ci)
        acc[ri][ci] += xv[ri].x * wv[ci].x + xv[ri].y * wv[ci].y +
                       xv[ri].z * wv[ci].z + xv[ri].w * wv[ci].w;
  }
  #pragma unroll
  for (int ri = 0; ri < 4; ++ri)
    #pragma unroll
    for (int ci = 0; ci < 4; ++ci) {
      int c = tx + 16 * ci;
      float sc = bn0[c] * rsqrtf(bn0[192 + c] + EPSF);
      float v = (acc[ri][ci] + b0[c] - bn0[128 + c]) * sc + bn0[64 + c];
      s0s[(ty * 4 + ri) * 68 + c] = fmaxf(v, 0.f);
    }
  __syncthreads();
  {
    int rl = t & 63, j0 = t >> 6;
    #pragma unroll
    for (int i = 0; i < 4; ++i) {
      int j = j0 + 4 * i;
      float s = b1[j];
      const float* wr = w1 + j * 64;
      #pragma unroll 16
      for (int c = 0; c < 64; ++c) s += s0s[rl * 68 + c] * wr[c];
      float sc = bn1[j] * rsqrtf(bn1[48 + j] + EPSF);
      s = (s - bn1[32 + j]) * sc + bn1[16 + j];
      s1s[rl * 20 + j] = fmaxf(s, 0.f);
    }
  }
  __syncthreads();
  if (t < 64) {
    float s = b2[0];
    #pragma unroll
    for (int o = 0; o < 16; ++o) s += s1s[t * 20 + o] * w2[o];
    float sc = bn2[0] * rsqrtf(bn2[3] + EPSF);
    s = (s - bn2[2]) * sc + bn2[1];
    scores[row0 + t] = fmaxf(s, 0.f);
  }
}

// ---- top-k (k=16) ----
__global__ void k_topk2(const float* __restrict__ scores, int* __restrict__ idx,
                        float* __restrict__ out_idx) {
  int b = blockIdx.x, t = threadIdx.x;
  float v[8];
  int base = b * NN;
  #pragma unroll
  for (int u = 0; u < 8; ++u) v[u] = scores[base + t + 256 * u];
  __shared__ float wvs[4];
  __shared__ int wis[4];
  __shared__ int winner;
  unsigned taken = 0;
  for (int r = 0; r < TOPK; ++r) {
    float best = -1e30f; int bi = 1 << 30;
    #pragma unroll
    for (int u = 0; u < 8; ++u) {
      if (!((taken >> u) & 1)) {
        float vv = v[u]; int ii = t + 256 * u;
        if (vv > best || (vv == best && ii < bi)) { best = vv; bi = ii; }
      }
    }
    for (int off = 32; off; off >>= 1) {
      float ov = __shfl_xor(best, off);
      int oi = __shfl_xor(bi, off);
      if (ov > best || (ov == best && oi < bi)) { best = ov; bi = oi; }
    }
    if ((t & 63) == 0) { wvs[t >> 6] = best; wis[t >> 6] = bi; }
    __syncthreads();
    if (t == 0) {
      float B = wvs[0]; int I = wis[0];
      #pragma unroll
      for (int q = 1; q < 4; ++q)
        if (wvs[q] > B || (wvs[q] == B && wis[q] < I)) { B = wvs[q]; I = wis[q]; }
      winner = I;
      idx[b * TOPK + r] = I;
      out_idx[b * TOPK + r] = (float)I;
    }
    __syncthreads();
    int w = winner;
    if ((w & 255) == t) taken |= 1u << (w >> 8);
  }
}

// ---------------- ball query + 3 conv stages, block = 64 per (b,k) ----------------
__global__ void k_group(const float* __restrict__ inp, const int* __restrict__ idx,
                        const float* __restrict__ w0, const float* __restrict__ b0, const float* __restrict__ bn0,
                        const float* __restrict__ w1, const float* __restrict__ b1, const float* __restrict__ bn1,
                        const float* __restrict__ w2, const float* __restrict__ b2, const float* __restrict__ bn2,
                        float* __restrict__ r2g) {
  __shared__ int gidx[NSAMP];
  __shared__ float gsh[65 * DD];
  __shared__ float r0[128];
  __shared__ float r1[256];
  int k = blockIdx.x, b = blockIdx.y;
  int lane = threadIdx.x;
  int qn = idx[b * TOPK + k];
  const float* px = inp + (size_t)b * DD * NN;
  float qx = px[qn], qy = px[NN + qn], qz = px[2 * NN + qn];
  int cnt = 0;
  for (int base = 0; base < NN && cnt < NSAMP; base += 64) {
    int n = base + lane;
    float dx = px[n] - qx, dy = px[NN + n] - qy, dz = px[2 * NN + n] - qz;
    float d2 = dx * dx + dy * dy + dz * dz;
    bool flag = (d2 <= R2);
    unsigned long long m = __ballot(flag);
    int pos = cnt + __popcll(m & ((1ull << lane) - 1ull));
    if (flag && pos < NSAMP) gidx[pos] = n;
    cnt += (int)__popcll(m);
  }
  __syncthreads();
  int total = cnt < NSAMP ? cnt : NSAMP;
  if (lane >= total) gidx[lane] = gidx[0];
  __syncthreads();
  for (int i = lane; i < 65 * DD; i += 64) {
    int p = i / DD, d = i - p * DD;
    int n = (p == 0) ? qn : gidx[p - 1];
    gsh[i] = px[d * NN + n];
  }
  __syncthreads();
  for (int c = lane; c < 128; c += 64) {
    float s = b0[c];
    const float* w = w0 + c * 390;
    for (int i = 0; i < 390; ++i) s += gsh[i] * w[i];
    float sc = bn0[c] * rsqrtf(bn0[384 + c] + EPSF);
    s = (s - bn0[256 + c]) * sc + bn0[128 + c];
    r0[c] = fmaxf(s, 0.f);
  }
  __syncthreads();
  for (int c = lane; c < 256; c += 64) {
    float s = b1[c];
    const float* w = w1 + c * 128;
    for (int o = 0; o < 128; ++o) s += r0[o] * w[o];
    float sc = bn1[c] * rsqrtf(bn1[768 + c] + EPSF);
    s = (s - bn1[512 + c]) * sc + bn1[256 + c];
    r1[c] = fmaxf(s, 0.f);
  }
  __syncthreads();
  for (int c = lane; c < 512; c += 64) {
    float s = b2[c];
    const float* w = w2 + c * 256;
    for (int o = 0; o < 256; ++o) s += r1[o] * w[o];
    float sc = bn2[c] * rsqrtf(bn2[1536 + c] + EPSF);
    s = (s - bn2[1024 + c]) * sc + bn2[512 + c];
    r2g[b * 8192 + c * TOPK + k] = fmaxf(s, 0.f);
  }
}

// ---------------- FC + BN + ReLU (wave-reduced dot), block=64 ----------------
__global__ void k_fl(const float* __restrict__ hin, const float* __restrict__ w,
                     const float* __restrict__ bias, const float* __restrict__ bn,
                     float* __restrict__ hout, int IN, int OUT) {
  int blk = blockIdx.x;
  int b = blk / OUT, j = blk % OUT;
  int lane = threadIdx.x;
  const float* hr = hin + (size_t)b * IN;
  const float* wr = w + (size_t)j * IN;
  float s = 0.f;
  for (int i = lane; i < IN; i += 64) s += hr[i] * wr[i];
  for (int o = 32; o; o >>= 1) s += __shfl_xor(s, o);
  if (lane == 0) {
    s += bias[j];
    float sc = bn[j] * rsqrtf(bn[3 * OUT + j] + EPSF);
    s = (s - bn[2 * OUT + j]) * sc + bn[OUT + j];
    hout[b * OUT + j] = fmaxf(s, 0.f);
  }
}

extern "C" void kernel_launch(void* const* d_in, const int* in_sizes, int n_in,
                              void* d_out, int out_size, void* d_ws, size_t ws_size,
                              hipStream_t stream) {
  const float* sv      = (const float*)d_in[0];
  const float* inp     = (const float*)d_in[1];
  const float* tl_win  = (const float*)d_in[2];
  const float* tl_bin  = (const float*)d_in[3];
  const float* tl_wout = (const float*)d_in[4];
  const float* tl_bout = (const float*)d_in[5];
  const float* tl_w1   = (const float*)d_in[6];
  const float* tl_b1   = (const float*)d_in[7];
  const float* tl_w2   = (const float*)d_in[8];
  const float* tl_b2   = (const float*)d_in[9];
  const float* tl_ln1g = (const float*)d_in[10];
  const float* tl_ln1b = (const float*)d_in[11];
  const float* tl_ln2g = (const float*)d_in[12];
  const float* tl_ln2b = (const float*)d_in[13];
  const float* fg_w0   = (const float*)d_in[14];
  const float* fg_b0   = (const float*)d_in[15];
  const float* fg_w1   = (const float*)d_in[16];
  const float* fg_b1   = (const float*)d_in[17];
  const float* fg_w2   = (const float*)d_in[18];
  const float* fg_b2   = (const float*)d_in[19];
  const float* fbn0    = (const float*)d_in[20];
  const float* fbn1    = (const float*)d_in[21];
  const float* fbn2    = (const float*)d_in[22];
  const float* rc_w0   = (const float*)d_in[23];
  const float* rc_b0   = (const float*)d_in[24];
  const float* rc_w1   = (const float*)d_in[25];
  const float* rc_b1   = (const float*)d_in[26];
  const float* rc_w2   = (const float*)d_in[27];
  const float* rc_b2   = (const float*)d_in[28];
  const float* rbn0    = (const float*)d_in[29];
  const float* rbn1    = (const float*)d_in[30];
  const float* rbn2    = (const float*)d_in[31];
  const float* fl_w0   = (const float*)d_in[32];
  const float* fl_b0   = (const float*)d_in[33];
  const float* fl_w1   = (const float*)d_in[34];
  const float* fl_b1   = (const float*)d_in[35];
  const float* lbn0    = (const float*)d_in[36];
  const float* lbn1    = (const float*)d_in[37];
  (void)in_sizes; (void)n_in; (void)out_size; (void)ws_size;

  float* wsp = (float*)d_ws;
  float* x      = wsp;                        // B*N*F      = 1048576
  float* qkv    = x + BB * NN * FF;           // B*N*192    = 3145728
  float* a      = qkv + BB * NN * 192;        // B*N*F      = 1048576
  float* scores = a + BB * NN * FF;           // B*N        = 16384
  int*   idxb   = (int*)(scores + BB * NN);   // B*TOPK     = 128
  float* r2g    = (float*)(idxb + BB * TOPK); // B*8192     = 65536
  float* h1g    = r2g + BB * 8192;            // B*1024     = 8192
  unsigned* wpk1 = (unsigned*)(h1g + BB * 1024);   // 2*2048*64 = 262144
  unsigned* wpk2 = wpk1 + NLAYER * 2048 * 64;      // 2*64*2048 = 262144
  float* part   = qkv;  // FFN split-K partials reuse qkv+a (4*16384*64 floats)

  float* out = (float*)d_out;  // fp32: h at [0,4096), idx-as-float at [4096,4224)

  k_transpose<<<(BB * NN * FF) / 256, 256, 0, stream>>>(sv, x);
  k_wpack<<<(NLAYER * 2048 * 64) / 256, 256, 0, stream>>>(tl_w1, wpk1, NLAYER * 2048 * 64);
  k_wpack<<<(NLAYER * 2048 * 64) / 256, 256, 0, stream>>>(tl_w2, wpk2, NLAYER * 2048 * 64);

  for (int l = 0; l < NLAYER; ++l) {
    k_qkv2<<<dim3(BB * NN / 64, 3), 256, 0, stream>>>(x, tl_win + l * 192 * FF,
                                                      tl_bin + l * 192, qkv);
    k_attn5<<<dim3(NN / 64, NHEAD, BB), 256, 0, stream>>>(qkv, a);
    k_proj2<<<BB * NN / 64, 256, 0, stream>>>(a, tl_wout + l * FF * FF, tl_bout + l * FF,
                                              tl_ln1g + l * FF, tl_ln1b + l * FF, x);
    k_ffn4<<<dim3(BB * NN / 64, 4), 256, 0, stream>>>(x, wpk1 + l * 2048 * 64,
                                                      tl_b1 + l * 2048,
                                                      wpk2 + l * 2048 * 64, part);
    k_ffn_ln<<<BB * NN / 4, 256, 0, stream>>>(part, tl_b2 + l * FF,
                                              tl_ln2g + l * FF, tl_ln2b + l * FF, x);
  }

  k_fg2<<<BB * NN / 64, 256, 0, stream>>>(x, fg_w0, fg_b0, fbn0, fg_w1, fg_b1, fbn1,
                                          fg_w2, fg_b2, fbn2, scores);
  k_topk2<<<BB, 256, 0, stream>>>(scores, idxb, out + BB * 512);
  k_group<<<dim3(TOPK, BB), 64, 0, stream>>>(inp, idxb, rc_w0, rc_b0, rbn0,
                                             rc_w1, rc_b1, rbn1, rc_w2, rc_b2, rbn2, r2g);
  k_fl<<<BB * 1024, 64, 0, stream>>>(r2g, fl_w0, fl_b0, lbn0, h1g, 8192, 1024);
  k_fl<<<BB * 512, 64, 0, stream>>>(h1g, fl_w1, fl_b1, lbn1, out, 1024, 512);
}

// Round 9
// 744.570 us; speedup vs baseline: 6.5428x; 1.1221x over previous
//
#include <hip/hip_runtime.h>
#include <hip/hip_bf16.h>
#include <math.h>

#define BB 8
#define NN 2048
#define FF 64
#define DD 6
#define NSAMP 64
#define TOPK 16
#define NHEAD 8
#define HD 8
#define NLAYER 2
#define EPSF 1e-5f
#define R2 0.09f

typedef short short8 __attribute__((ext_vector_type(8)));
typedef float f32x4 __attribute__((ext_vector_type(4)));

// split-pack: u32 = (bf16_hi << 16) | bf16_lo, both RNE. x ≈ hi + lo, err ~2^-16 rel.
__device__ inline unsigned pk2(float x) {
  unsigned b = __float_as_uint(x);
  unsigned hi = (b + 0x7fffu + ((b >> 16) & 1u)) >> 16;
  float r = x - __uint_as_float(hi << 16);
  unsigned c = __float_as_uint(r);
  unsigned lo = (c + 0x7fffu + ((c >> 16) & 1u)) >> 16;
  return (hi << 16) | lo;
}

__device__ inline void unpk(const unsigned* p, short8& hi, short8& lo) {
  #pragma unroll
  for (int i = 0; i < 8; ++i) {
    hi[i] = (short)(p[i] >> 16);
    lo[i] = (short)(p[i] & 0xffffu);
  }
}

// ---------------- transpose sortvec (B,1,F,N) -> x (B,N,F) ----------------
__global__ void k_transpose(const float* __restrict__ sv, float* __restrict__ x) {
  int i = blockIdx.x * 256 + threadIdx.x;
  if (i >= BB * NN * FF) return;
  int f = i % FF;
  int n = (i / FF) % NN;
  int b = i / (FF * NN);
  x[i] = sv[(b * FF + f) * NN + n];
}

// ---------------- pack fp32 weights -> split-bf16 u32 ----------------
__global__ void k_wpack(const float* __restrict__ w, unsigned* __restrict__ o, int n) {
  int i = blockIdx.x * 256 + threadIdx.x;
  if (i < n) o[i] = pk2(w[i]);
}

// ---------------- tiled GEMM: qkv[row][192] = x[row][64] @ win^T + bin ----------
__global__ void k_qkv2(const float* __restrict__ x, const float* __restrict__ win,
                       const float* __restrict__ bin, float* __restrict__ qkv) {
  __shared__ float xs[64 * 68];
  __shared__ float ws[64 * 68];
  int row0 = blockIdx.x * 64, col0 = blockIdx.y * 64;
  int t = threadIdx.x;
  #pragma unroll
  for (int i = 0; i < 4; ++i) {
    int q = t + i * 256, r = q >> 4, c = (q & 15) * 4;
    *(float4*)(xs + r * 68 + c) = *(const float4*)(x + (size_t)(row0 + r) * 64 + c);
    *(float4*)(ws + r * 68 + c) = *(const float4*)(win + (size_t)(col0 + r) * 64 + c);
  }
  __syncthreads();
  int tx = t & 15, ty = t >> 4;
  float acc[4][4] = {};
  for (int f = 0; f < 64; f += 4) {
    float4 xv[4], wv[4];
    #pragma unroll
    for (int ri = 0; ri < 4; ++ri) xv[ri] = *(const float4*)(xs + (ty * 4 + ri) * 68 + f);
    #pragma unroll
    for (int ci = 0; ci < 4; ++ci) wv[ci] = *(const float4*)(ws + (tx + 16 * ci) * 68 + f);
    #pragma unroll
    for (int ri = 0; ri < 4; ++ri)
      #pragma unroll
      for (int ci = 0; ci < 4; ++ci)
        acc[ri][ci] += xv[ri].x * wv[ci].x + xv[ri].y * wv[ci].y +
                       xv[ri].z * wv[ci].z + xv[ri].w * wv[ci].w;
  }
  #pragma unroll
  for (int ri = 0; ri < 4; ++ri)
    #pragma unroll
    for (int ci = 0; ci < 4; ++ci) {
      int r = row0 + ty * 4 + ri, c = col0 + tx + 16 * ci;
      qkv[(size_t)r * 192 + c] = acc[ri][ci] + bin[c];
    }
}

// ---- attention v6: single-plane bf16 MFMA flash. Wave = 16 queries x 2048
// keys. bf16 rounding of K/V/P is statistically safe here (near-uniform
// softmax over 2048 keys averages independent roundings to ~1e-5; ones-row
// makes num/denom use the same p-tilde). K staged in 40-u16 rows zero-padded
// to k=32 so the B-frag needs no masking. 1 mfma per QK half, 1 per PV.
__global__ void __launch_bounds__(256, 5)
k_attn6(const float* __restrict__ qkv, float* __restrict__ a) {
  __shared__ __attribute__((aligned(16))) unsigned short kb16[256 * 40];  // 20 KB
  __shared__ __attribute__((aligned(16))) unsigned short vb16[9 * 264];   // 4.6 KB
  __shared__ __attribute__((aligned(16))) unsigned short pb16[4 * 16 * 40]; // 5 KB
  int t = threadIdx.x;
  int lane = t & 63, w = t >> 6;
  int nIdx = lane & 15, lq = lane >> 4;
  int h = blockIdx.y, b = blockIdx.z;
  int qwb = blockIdx.x * 64 + w * 16;
  const float kf = 0.35355339059327373f * 1.4426950408889634f;  // scale*log2e
  // zero K pad (d=8..31 stays zero; staging writes only d<8)
  {
    unsigned* kz = (unsigned*)kb16;
    #pragma unroll
    for (int i = 0; i < 20; ++i) kz[t + i * 256] = 0u;
  }
  // Q A-fragment: quad0 lanes hold k=0..7 (RNE bf16), others zero
  short8 qF = {0, 0, 0, 0, 0, 0, 0, 0};
  if (lq == 0) {
    const float* qr = qkv + ((size_t)(b * NN + qwb + nIdx)) * 192 + h * HD;
    #pragma unroll
    for (int j = 0; j < 8; ++j) {
      float v = qr[j] * kf;
      unsigned bb = __float_as_uint(v);
      qF[j] = (short)((bb + 0x7fffu + ((bb >> 16) & 1u)) >> 16);
    }
  }
  f32x4 acc = {0.f, 0.f, 0.f, 0.f};
  unsigned short* mypb = pb16 + w * 640;
  for (int kc = 0; kc < NN; kc += 256) {
    __syncthreads();
    // stage K chunk: pairs (d0,d0+1) -> one u32 (trunc bf16)
    #pragma unroll
    for (int i = 0; i < 4; ++i) {
      int p = t + i * 256;               // 0..1023
      int key = p >> 2, d0 = (p & 3) * 2;
      const float* src = qkv + ((size_t)(b * NN + kc + key)) * 192 + 64 + h * HD + d0;
      float2 f = *(const float2*)(src);
      unsigned u = (__float_as_uint(f.x) >> 16) | (__float_as_uint(f.y) & 0xffff0000u);
      *(unsigned*)(kb16 + key * 40 + d0) = u;
    }
    // stage V^T chunk: pairs of keys -> one u32
    #pragma unroll
    for (int i = 0; i < 4; ++i) {
      int p = t + i * 256;
      int d = p >> 7, kp = p & 127;
      int key0 = 2 * kp;
      float f0 = qkv[((size_t)(b * NN + kc + key0)) * 192 + 128 + h * HD + d];
      float f1 = qkv[((size_t)(b * NN + kc + key0 + 1)) * 192 + 128 + h * HD + d];
      unsigned u = (__float_as_uint(f0) >> 16) | (__float_as_uint(f1) & 0xffff0000u);
      *(unsigned*)(vb16 + d * 264 + key0) = u;
    }
    if (t < 132) ((unsigned*)(vb16 + 8 * 264))[t] = 0x3f803f80u;  // ones row
    __syncthreads();
    for (int s = 0; s < 8; ++s) {
      int kb = s * 32;
      #pragma unroll
      for (int half = 0; half < 2; ++half) {
        int key = kb + half * 16 + nIdx;
        short8 bF = *(const short8*)(kb16 + key * 40 + lq * 8);  // zeros for k>=8
        f32x4 c = {0.f, 0.f, 0.f, 0.f};
        c = __builtin_amdgcn_mfma_f32_16x16x32_bf16(qF, bF, c, 0, 0, 0);
        #pragma unroll
        for (int r = 0; r < 4; ++r) {
          float p = __builtin_amdgcn_exp2f(c[r]);
          int row = lq * 4 + r;
          mypb[row * 40 + half * 16 + nIdx] = (unsigned short)(__float_as_uint(p) >> 16);
        }
      }
      // C->A readback (same-wave LDS)
      short8 pa = *(const short8*)(mypb + nIdx * 40 + lq * 8);
      int vn = nIdx < 9 ? nIdx : 8;
      short8 vb = *(const short8*)(vb16 + vn * 264 + kb + lq * 8);
      acc = __builtin_amdgcn_mfma_f32_16x16x32_bf16(pa, vb, acc, 0, 0, 0);
    }
  }
  // epilogue: col 8 holds l = sum(p); divide, scatter cols 0..7
  #pragma unroll
  for (int r = 0; r < 4; ++r) {
    float lr = __shfl(acc[r], (lane & 48) | 8);
    if (nIdx < 8) {
      int row = qwb + lq * 4 + r;
      a[((size_t)(b * NN + row)) * 64 + h * HD + nIdx] = acc[r] / lr;
    }
  }
}

// ------- proj + residual + LN, tiled GEMM ---------
__global__ void k_proj2(const float* __restrict__ a, const float* __restrict__ wout,
                        const float* __restrict__ bout, const float* __restrict__ g,
                        const float* __restrict__ be, float* __restrict__ x) {
  __shared__ float xs[64 * 68];
  __shared__ float ws[64 * 68];
  int row0 = blockIdx.x * 64;
  int t = threadIdx.x;
  #pragma unroll
  for (int i = 0; i < 4; ++i) {
    int q = t + i * 256, r = q >> 4, c = (q & 15) * 4;
    *(float4*)(xs + r * 68 + c) = *(const float4*)(a + (size_t)(row0 + r) * 64 + c);
    *(float4*)(ws + r * 68 + c) = *(const float4*)(wout + r * 64 + c);
  }
  __syncthreads();
  int tx = t & 15, ty = t >> 4;
  float acc[4][4] = {};
  for (int f = 0; f < 64; f += 4) {
    float4 xv[4], wv[4];
    #pragma unroll
    for (int ri = 0; ri < 4; ++ri) xv[ri] = *(const float4*)(xs + (ty * 4 + ri) * 68 + f);
    #pragma unroll
    for (int ci = 0; ci < 4; ++ci) wv[ci] = *(const float4*)(ws + (tx + 16 * ci) * 68 + f);
    #pragma unroll
    for (int ri = 0; ri < 4; ++ri)
      #pragma unroll
      for (int ci = 0; ci < 4; ++ci)
        acc[ri][ci] += xv[ri].x * wv[ci].x + xv[ri].y * wv[ci].y +
                       xv[ri].z * wv[ci].z + xv[ri].w * wv[ci].w;
  }
  #pragma unroll
  for (int ri = 0; ri < 4; ++ri) {
    int rl = ty * 4 + ri;
    float val[4], s = 0.f, sq = 0.f;
    #pragma unroll
    for (int ci = 0; ci < 4; ++ci) {
      int c = tx + 16 * ci;
      val[ci] = x[(size_t)(row0 + rl) * 64 + c] + bout[c] + acc[ri][ci];
      s += val[ci]; sq += val[ci] * val[ci];
    }
    #pragma unroll
    for (int off = 1; off < 16; off <<= 1) { s += __shfl_xor(s, off); sq += __shfl_xor(sq, off); }
    float mean = s * (1.f / 64.f);
    float var = sq * (1.f / 64.f) - mean * mean;
    float rstd = rsqrtf(var + EPSF);
    #pragma unroll
    for (int ci = 0; ci < 4; ++ci) {
      int c = tx + 16 * ci;
      x[(size_t)(row0 + rl) * 64 + c] = (val[ci] - mean) * rstd * g[c] + be[c];
    }
  }
}

// ------- FFN v4: MFMA split-bf16 (hi*hi + hi*lo + lo*hi), split-K grid (256,4) ----
__global__ void __launch_bounds__(256, 4)
k_ffn4(const float* __restrict__ x, const unsigned* __restrict__ w1p,
       const float* __restrict__ b1, const unsigned* __restrict__ w2p,
       float* __restrict__ part) {
  __shared__ unsigned xs[64 * 68];
  __shared__ unsigned ws[64 * 68];
  __shared__ unsigned hs[64 * 68];
  __shared__ float b1s[64];
  int row0 = blockIdx.x * 64;
  int ks = blockIdx.y;
  int t = threadIdx.x;
  int lane = t & 63, wv = t >> 6;
  int lm = lane & 15, lq = lane >> 4;
  #pragma unroll
  for (int i = 0; i < 4; ++i) {
    int q = t + i * 256, r = q >> 4, c = (q & 15) * 4;
    float4 v = *(const float4*)(x + (size_t)(row0 + r) * 64 + c);
    xs[r * 68 + c]     = pk2(v.x);
    xs[r * 68 + c + 1] = pk2(v.y);
    xs[r * 68 + c + 2] = pk2(v.z);
    xs[r * 68 + c + 3] = pk2(v.w);
  }
  f32x4 acc[4];
  #pragma unroll
  for (int tn = 0; tn < 4; ++tn) acc[tn] = (f32x4){0.f, 0.f, 0.f, 0.f};

  for (int ch = 0; ch < 8; ++ch) {
    int kc = (ks * 8 + ch) * 64;
    uint4 rw[4];
    #pragma unroll
    for (int i = 0; i < 4; ++i) {
      int q = t + i * 256, r = q >> 4, c = (q & 15) * 4;
      rw[i] = *(const uint4*)(w1p + (size_t)(kc + r) * 64 + c);
    }
    float rbv = 0.f;
    if (t < 64) rbv = b1[kc + t];
    __syncthreads();  // (A)
    #pragma unroll
    for (int i = 0; i < 4; ++i) {
      int q = t + i * 256, r = q >> 4, c = (q & 15) * 4;
      *(uint4*)(ws + r * 68 + c) = rw[i];
    }
    if (t < 64) b1s[t] = rbv;
    __syncthreads();  // (B)
    f32x4 h4[4];
    #pragma unroll
    for (int tn = 0; tn < 4; ++tn) h4[tn] = (f32x4){0.f, 0.f, 0.f, 0.f};
    #pragma unroll
    for (int kb = 0; kb < 64; kb += 32) {
      unsigned ap[8];
      const unsigned* abase = xs + (wv * 16 + lm) * 68 + kb + lq * 8;
      *(uint4*)(ap)     = *(const uint4*)(abase);
      *(uint4*)(ap + 4) = *(const uint4*)(abase + 4);
      short8 ahi, alo; unpk(ap, ahi, alo);
      #pragma unroll
      for (int tn = 0; tn < 4; ++tn) {
        unsigned bp[8];
        const unsigned* bbase = ws + (tn * 16 + lm) * 68 + kb + lq * 8;
        *(uint4*)(bp)     = *(const uint4*)(bbase);
        *(uint4*)(bp + 4) = *(const uint4*)(bbase + 4);
        short8 bhi, blo; unpk(bp, bhi, blo);
        h4[tn] = __builtin_amdgcn_mfma_f32_16x16x32_bf16(ahi, bhi, h4[tn], 0, 0, 0);
        h4[tn] = __builtin_amdgcn_mfma_f32_16x16x32_bf16(ahi, blo, h4[tn], 0, 0, 0);
        h4[tn] = __builtin_amdgcn_mfma_f32_16x16x32_bf16(alo, bhi, h4[tn], 0, 0, 0);
      }
    }
    #pragma unroll
    for (int tn = 0; tn < 4; ++tn)
      #pragma unroll
      for (int r = 0; r < 4; ++r) {
        float hv = fmaxf(h4[tn][r] + b1s[tn * 16 + lm], 0.f);
        hs[(wv * 16 + lq * 4 + r) * 68 + tn * 16 + lm] = pk2(hv);
      }
    #pragma unroll
    for (int i = 0; i < 4; ++i) {
      int q = t + i * 256, j = q >> 4, c = (q & 15) * 4;
      rw[i] = *(const uint4*)(w2p + (size_t)j * 2048 + kc + c);
    }
    __syncthreads();  // (C)
    #pragma unroll
    for (int i = 0; i < 4; ++i) {
      int q = t + i * 256, j = q >> 4, c = (q & 15) * 4;
      *(uint4*)(ws + j * 68 + c) = rw[i];
    }
    __syncthreads();  // (D)
    #pragma unroll
    for (int kb = 0; kb < 64; kb += 32) {
      unsigned ap[8];
      const unsigned* abase = hs + (wv * 16 + lm) * 68 + kb + lq * 8;
      *(uint4*)(ap)     = *(const uint4*)(abase);
      *(uint4*)(ap + 4) = *(const uint4*)(abase + 4);
      short8 ahi, alo; unpk(ap, ahi, alo);
      #pragma unroll
      for (int tn = 0; tn < 4; ++tn) {
        unsigned bp[8];
        const unsigned* bbase = ws + (tn * 16 + lm) * 68 + kb + lq * 8;
        *(uint4*)(bp)     = *(const uint4*)(bbase);
        *(uint4*)(bp + 4) = *(const uint4*)(bbase + 4);
        short8 bhi, blo; unpk(bp, bhi, blo);
        acc[tn] = __builtin_amdgcn_mfma_f32_16x16x32_bf16(ahi, bhi, acc[tn], 0, 0, 0);
        acc[tn] = __builtin_amdgcn_mfma_f32_16x16x32_bf16(ahi, blo, acc[tn], 0, 0, 0);
        acc[tn] = __builtin_amdgcn_mfma_f32_16x16x32_bf16(alo, bhi, acc[tn], 0, 0, 0);
      }
    }
  }
  float* pb = part + (size_t)ks * (BB * NN * 64);
  #pragma unroll
  for (int tn = 0; tn < 4; ++tn)
    #pragma unroll
    for (int r = 0; r < 4; ++r)
      pb[(size_t)(row0 + wv * 16 + lq * 4 + r) * 64 + tn * 16 + lm] = acc[tn][r];
}

// ------- combine 4 partials + residual + b2 + LN; one wave per row ---------
__global__ void k_ffn_ln(const float* __restrict__ part, const float* __restrict__ b2,
                         const float* __restrict__ g, const float* __restrict__ be,
                         float* __restrict__ x) {
  int row = blockIdx.x * 4 + (threadIdx.x >> 6);
  int j = threadIdx.x & 63;
  size_t o = (size_t)row * 64 + j;
  const size_t S = (size_t)BB * NN * 64;
  float val = x[o] + b2[j] + ((part[o] + part[o + S]) + (part[o + 2 * S] + part[o + 3 * S]));
  float s = val;
  for (int off = 32; off; off >>= 1) s += __shfl_xor(s, off);
  s *= (1.f / 64.f);
  float d = val - s;
  float v = d * d;
  for (int off = 32; off; off >>= 1) v += __shfl_xor(v, off);
  v *= (1.f / 64.f);
  x[o] = d * rsqrtf(v + EPSF) * g[j] + be[j];
}

// ------- score head tiled ----------
__global__ void k_fg2(const float* __restrict__ x,
                      const float* __restrict__ w0, const float* __restrict__ b0, const float* __restrict__ bn0,
                      const float* __restrict__ w1, const float* __restrict__ b1, const float* __restrict__ bn1,
                      const float* __restrict__ w2, const float* __restrict__ b2, const float* __restrict__ bn2,
                      float* __restrict__ scores) {
  __shared__ float xs[64 * 68];
  __shared__ float ws[64 * 68];
  __shared__ float s0s[64 * 68];
  __shared__ float s1s[64 * 20];
  int row0 = blockIdx.x * 64;
  int t = threadIdx.x;
  #pragma unroll
  for (int i = 0; i < 4; ++i) {
    int q = t + i * 256, r = q >> 4, c = (q & 15) * 4;
    *(float4*)(xs + r * 68 + c) = *(const float4*)(x + (size_t)(row0 + r) * 64 + c);
    *(float4*)(ws + r * 68 + c) = *(const float4*)(w0 + r * 64 + c);
  }
  __syncthreads();
  int tx = t & 15, ty = t >> 4;
  float acc[4][4] = {};
  for (int f = 0; f < 64; f += 4) {
    float4 xv[4], wv[4];
    #pragma unroll
    for (int ri = 0; ri < 4; ++ri) xv[ri] = *(const float4*)(xs + (ty * 4 + ri) * 68 + f);
    #pragma unroll
    for (int ci = 0; ci < 4; ++ci) wv[ci] = *(const float4*)(ws + (tx + 16 * ci) * 68 + f);
    #pragma unroll
    for (int ri = 0; ri < 4; ++ri)
      #pragma unroll
      for (int ci = 0; ci < 4; ++ci)
        acc[ri][ci] += xv[ri].x * wv[ci].x + xv[ri].y * wv[ci].y +
                       xv[ri].z * wv[ci].z + xv[ri].w * wv[ci].w;
  }
  #pragma unroll
  for (int ri = 0; ri < 4; ++ri)
    #pragma unroll
    for (int ci = 0; ci < 4; ++ci) {
      int c = tx + 16 * ci;
      float sc = bn0[c] * rsqrtf(bn0[192 + c] + EPSF);
      float v = (acc[ri][ci] + b0[c] - bn0[128 + c]) * sc + bn0[64 + c];
      s0s[(ty * 4 + ri) * 68 + c] = fmaxf(v, 0.f);
    }
  __syncthreads();
  {
    int rl = t & 63, j0 = t >> 6;
    #pragma unroll
    for (int i = 0; i < 4; ++i) {
      int j = j0 + 4 * i;
      float s = b1[j];
      const float* wr = w1 + j * 64;
      #pragma unroll 16
      for (int c = 0; c < 64; ++c) s += s0s[rl * 68 + c] * wr[c];
      float sc = bn1[j] * rsqrtf(bn1[48 + j] + EPSF);
      s = (s - bn1[32 + j]) * sc + bn1[16 + j];
      s1s[rl * 20 + j] = fmaxf(s, 0.f);
    }
  }
  __syncthreads();
  if (t < 64) {
    float s = b2[0];
    #pragma unroll
    for (int o = 0; o < 16; ++o) s += s1s[t * 20 + o] * w2[o];
    float sc = bn2[0] * rsqrtf(bn2[3] + EPSF);
    s = (s - bn2[2]) * sc + bn2[1];
    scores[row0 + t] = fmaxf(s, 0.f);
  }
}

// ---- top-k (k=16) ----
__global__ void k_topk2(const float* __restrict__ scores, int* __restrict__ idx,
                        float* __restrict__ out_idx) {
  int b = blockIdx.x, t = threadIdx.x;
  float v[8];
  int base = b * NN;
  #pragma unroll
  for (int u = 0; u < 8; ++u) v[u] = scores[base + t + 256 * u];
  __shared__ float wvs[4];
  __shared__ int wis[4];
  __shared__ int winner;
  unsigned taken = 0;
  for (int r = 0; r < TOPK; ++r) {
    float best = -1e30f; int bi = 1 << 30;
    #pragma unroll
    for (int u = 0; u < 8; ++u) {
      if (!((taken >> u) & 1)) {
        float vv = v[u]; int ii = t + 256 * u;
        if (vv > best || (vv == best && ii < bi)) { best = vv; bi = ii; }
      }
    }
    for (int off = 32; off; off >>= 1) {
      float ov = __shfl_xor(best, off);
      int oi = __shfl_xor(bi, off);
      if (ov > best || (ov == best && oi < bi)) { best = ov; bi = oi; }
    }
    if ((t & 63) == 0) { wvs[t >> 6] = best; wis[t >> 6] = bi; }
    __syncthreads();
    if (t == 0) {
      float B = wvs[0]; int I = wis[0];
      #pragma unroll
      for (int q = 1; q < 4; ++q)
        if (wvs[q] > B || (wvs[q] == B && wis[q] < I)) { B = wvs[q]; I = wis[q]; }
      winner = I;
      idx[b * TOPK + r] = I;
      out_idx[b * TOPK + r] = (float)I;
    }
    __syncthreads();
    int w = winner;
    if ((w & 255) == t) taken |= 1u << (w >> 8);
  }
}

// ---------------- ball query + 3 conv stages, block = 64 per (b,k) ----------------
__global__ void k_group(const float* __restrict__ inp, const int* __restrict__ idx,
                        const float* __restrict__ w0, const float* __restrict__ b0, const float* __restrict__ bn0,
                        const float* __restrict__ w1, const float* __restrict__ b1, const float* __restrict__ bn1,
                        const float* __restrict__ w2, const float* __restrict__ b2, const float* __restrict__ bn2,
                        float* __restrict__ r2g) {
  __shared__ int gidx[NSAMP];
  __shared__ float gsh[65 * DD];
  __shared__ float r0[128];
  __shared__ float r1[256];
  int k = blockIdx.x, b = blockIdx.y;
  int lane = threadIdx.x;
  int qn = idx[b * TOPK + k];
  const float* px = inp + (size_t)b * DD * NN;
  float qx = px[qn], qy = px[NN + qn], qz = px[2 * NN + qn];
  int cnt = 0;
  for (int base = 0; base < NN && cnt < NSAMP; base += 64) {
    int n = base + lane;
    float dx = px[n] - qx, dy = px[NN + n] - qy, dz = px[2 * NN + n] - qz;
    float d2 = dx * dx + dy * dy + dz * dz;
    bool flag = (d2 <= R2);
    unsigned long long m = __ballot(flag);
    int pos = cnt + __popcll(m & ((1ull << lane) - 1ull));
    if (flag && pos < NSAMP) gidx[pos] = n;
    cnt += (int)__popcll(m);
  }
  __syncthreads();
  int total = cnt < NSAMP ? cnt : NSAMP;
  if (lane >= total) gidx[lane] = gidx[0];
  __syncthreads();
  for (int i = lane; i < 65 * DD; i += 64) {
    int p = i / DD, d = i - p * DD;
    int n = (p == 0) ? qn : gidx[p - 1];
    gsh[i] = px[d * NN + n];
  }
  __syncthreads();
  for (int c = lane; c < 128; c += 64) {
    float s = b0[c];
    const float* w = w0 + c * 390;
    for (int i = 0; i < 390; ++i) s += gsh[i] * w[i];
    float sc = bn0[c] * rsqrtf(bn0[384 + c] + EPSF);
    s = (s - bn0[256 + c]) * sc + bn0[128 + c];
    r0[c] = fmaxf(s, 0.f);
  }
  __syncthreads();
  for (int c = lane; c < 256; c += 64) {
    float s = b1[c];
    const float* w = w1 + c * 128;
    for (int o = 0; o < 128; ++o) s += r0[o] * w[o];
    float sc = bn1[c] * rsqrtf(bn1[768 + c] + EPSF);
    s = (s - bn1[512 + c]) * sc + bn1[256 + c];
    r1[c] = fmaxf(s, 0.f);
  }
  __syncthreads();
  for (int c = lane; c < 512; c += 64) {
    float s = b2[c];
    const float* w = w2 + c * 256;
    for (int o = 0; o < 256; ++o) s += r1[o] * w[o];
    float sc = bn2[c] * rsqrtf(bn2[1536 + c] + EPSF);
    s = (s - bn2[1024 + c]) * sc + bn2[512 + c];
    r2g[b * 8192 + c * TOPK + k] = fmaxf(s, 0.f);
  }
}

// ---------------- FC + BN + ReLU (wave-reduced dot), block=64 ----------------
__global__ void k_fl(const float* __restrict__ hin, const float* __restrict__ w,
                     const float* __restrict__ bias, const float* __restrict__ bn,
                     float* __restrict__ hout, int IN, int OUT) {
  int blk = blockIdx.x;
  int b = blk / OUT, j = blk % OUT;
  int lane = threadIdx.x;
  const float* hr = hin + (size_t)b * IN;
  const float* wr = w + (size_t)j * IN;
  float s = 0.f;
  for (int i = lane; i < IN; i += 64) s += hr[i] * wr[i];
  for (int o = 32; o; o >>= 1) s += __shfl_xor(s, o);
  if (lane == 0) {
    s += bias[j];
    float sc = bn[j] * rsqrtf(bn[3 * OUT + j] + EPSF);
    s = (s - bn[2 * OUT + j]) * sc + bn[OUT + j];
    hout[b * OUT + j] = fmaxf(s, 0.f);
  }
}

extern "C" void kernel_launch(void* const* d_in, const int* in_sizes, int n_in,
                              void* d_out, int out_size, void* d_ws, size_t ws_size,
                              hipStream_t stream) {
  const float* sv      = (const float*)d_in[0];
  const float* inp     = (const float*)d_in[1];
  const float* tl_win  = (const float*)d_in[2];
  const float* tl_bin  = (const float*)d_in[3];
  const float* tl_wout = (const float*)d_in[4];
  const float* tl_bout = (const float*)d_in[5];
  const float* tl_w1   = (const float*)d_in[6];
  const float* tl_b1   = (const float*)d_in[7];
  const float* tl_w2   = (const float*)d_in[8];
  const float* tl_b2   = (const float*)d_in[9];
  const float* tl_ln1g = (const float*)d_in[10];
  const float* tl_ln1b = (const float*)d_in[11];
  const float* tl_ln2g = (const float*)d_in[12];
  const float* tl_ln2b = (const float*)d_in[13];
  const float* fg_w0   = (const float*)d_in[14];
  const float* fg_b0   = (const float*)d_in[15];
  const float* fg_w1   = (const float*)d_in[16];
  const float* fg_b1   = (const float*)d_in[17];
  const float* fg_w2   = (const float*)d_in[18];
  const float* fg_b2   = (const float*)d_in[19];
  const float* fbn0    = (const float*)d_in[20];
  const float* fbn1    = (const float*)d_in[21];
  const float* fbn2    = (const float*)d_in[22];
  const float* rc_w0   = (const float*)d_in[23];
  const float* rc_b0   = (const float*)d_in[24];
  const float* rc_w1   = (const float*)d_in[25];
  const float* rc_b1   = (const float*)d_in[26];
  const float* rc_w2   = (const float*)d_in[27];
  const float* rc_b2   = (const float*)d_in[28];
  const float* rbn0    = (const float*)d_in[29];
  const float* rbn1    = (const float*)d_in[30];
  const float* rbn2    = (const float*)d_in[31];
  const float* fl_w0   = (const float*)d_in[32];
  const float* fl_b0   = (const float*)d_in[33];
  const float* fl_w1   = (const float*)d_in[34];
  const float* fl_b1   = (const float*)d_in[35];
  const float* lbn0    = (const float*)d_in[36];
  const float* lbn1    = (const float*)d_in[37];
  (void)in_sizes; (void)n_in; (void)out_size; (void)ws_size;

  float* wsp = (float*)d_ws;
  float* x      = wsp;                        // B*N*F      = 1048576
  float* qkv    = x + BB * NN * FF;           // B*N*192    = 3145728
  float* a      = qkv + BB * NN * 192;        // B*N*F      = 1048576
  float* scores = a + BB * NN * FF;           // B*N        = 16384
  int*   idxb   = (int*)(scores + BB * NN);   // B*TOPK     = 128
  float* r2g    = (float*)(idxb + BB * TOPK); // B*8192     = 65536
  float* h1g    = r2g + BB * 8192;            // B*1024     = 8192
  unsigned* wpk1 = (unsigned*)(h1g + BB * 1024);   // 2*2048*64 = 262144
  unsigned* wpk2 = wpk1 + NLAYER * 2048 * 64;      // 2*64*2048 = 262144
  float* part   = qkv;  // FFN split-K partials reuse qkv+a (4*16384*64 floats)

  float* out = (float*)d_out;  // fp32: h at [0,4096), idx-as-float at [4096,4224)

  k_transpose<<<(BB * NN * FF) / 256, 256, 0, stream>>>(sv, x);
  k_wpack<<<(NLAYER * 2048 * 64) / 256, 256, 0, stream>>>(tl_w1, wpk1, NLAYER * 2048 * 64);
  k_wpack<<<(NLAYER * 2048 * 64) / 256, 256, 0, stream>>>(tl_w2, wpk2, NLAYER * 2048 * 64);

  for (int l = 0; l < NLAYER; ++l) {
    k_qkv2<<<dim3(BB * NN / 64, 3), 256, 0, stream>>>(x, tl_win + l * 192 * FF,
                                                      tl_bin + l * 192, qkv);
    k_attn6<<<dim3(NN / 64, NHEAD, BB), 256, 0, stream>>>(qkv, a);
    k_proj2<<<BB * NN / 64, 256, 0, stream>>>(a, tl_wout + l * FF * FF, tl_bout + l * FF,
                                              tl_ln1g + l * FF, tl_ln1b + l * FF, x);
    k_ffn4<<<dim3(BB * NN / 64, 4), 256, 0, stream>>>(x, wpk1 + l * 2048 * 64,
                                                      tl_b1 + l * 2048,
                                                      wpk2 + l * 2048 * 64, part);
    k_ffn_ln<<<BB * NN / 4, 256, 0, stream>>>(part, tl_b2 + l * FF,
                                              tl_ln2g + l * FF, tl_ln2b + l * FF, x);
  }

  k_fg2<<<BB * NN / 64, 256, 0, stream>>>(x, fg_w0, fg_b0, fbn0, fg_w1, fg_b1, fbn1,
                                          fg_w2, fg_b2, fbn2, scores);
  k_topk2<<<BB, 256, 0, stream>>>(scores, idxb, out + BB * 512);
  k_group<<<dim3(TOPK, BB), 64, 0, stream>>>(inp, idxb, rc_w0, rc_b0, rbn0,
                                             rc_w1, rc_b1, rbn1, rc_w2, rc_b2, rbn2, r2g);
  k_fl<<<BB * 1024, 64, 0, stream>>>(r2g, fl_w0, fl_b0, lbn0, h1g, 8192, 1024);
  k_fl<<<BB * 512, 64, 0, stream>>>(h1g, fl_w1, fl_b1, lbn1, out, 1024, 512);
}